// Round 4
// baseline (5793.810 us; speedup 1.0000x reference)
//
#include <hip/hip_runtime.h>
#include <hip/hip_bf16.h>
#include <math.h>

#define NL 6
#define DM 272
#define DS 64
#define DI 544
#define DTR 17
#define NSC 4
#define BB 4
#define LL 2048
#define MTOK (BB*LL)

__device__ __forceinline__ float sigmoidf_(float x){ return 1.0f/(1.0f+__expf(-x)); }
__device__ __forceinline__ float rlf(float x, int s){ return __int_as_float(__builtin_amdgcn_readlane(__float_as_int(x), s)); }

#define DPPADD(x, ctrl) x += __int_as_float(__builtin_amdgcn_update_dpp(0, __float_as_int(x), ctrl, 0xf, 0xf, true))
// full-wave64 sum; result valid in lane 63
__device__ __forceinline__ float wsum64(float x){
    DPPADD(x, 0x111); // row_shr:1
    DPPADD(x, 0x112); // row_shr:2
    DPPADD(x, 0x114); // row_shr:4
    DPPADD(x, 0x118); // row_shr:8
    DPPADD(x, 0x142); // row_bcast:15
    DPPADD(x, 0x143); // row_bcast:31
    return x;
}

// ---------------- LayerNorm: one wave per token ----------------
__global__ __launch_bounds__(256) void ln_kernel(const float* __restrict__ X,
                          const float* __restrict__ w,
                          const float* __restrict__ b,
                          float* __restrict__ H)
{
    int wave = threadIdx.x >> 6;
    int lane = threadIdx.x & 63;
    int tok = blockIdx.x*4 + wave;
    const float* xr = X + (size_t)tok*DM;
    float v[5];
    float s=0.f, ss=0.f;
    #pragma unroll
    for (int j=0;j<5;++j){
        int idx = lane + j*64;
        float x = (idx < DM) ? xr[idx] : 0.f;
        v[j]=x; s+=x; ss+=x*x;
    }
    #pragma unroll
    for (int off=1; off<64; off<<=1){ s += __shfl_xor(s,off); ss += __shfl_xor(ss,off); }
    float mu  = s * (1.0f/DM);
    float var = ss*(1.0f/DM) - mu*mu;
    float inv = 1.0f/sqrtf(var + 1e-5f);
    float* hr = H + (size_t)tok*DM;
    #pragma unroll
    for (int j=0;j<5;++j){
        int idx = lane + j*64;
        if (idx<DM) hr[idx] = (v[j]-mu)*inv*w[idx] + b[idx];
    }
}

// ---------------- f32 GEMM (A row-major): C[M,N] = A[M,K] @ W[N,K]^T ----------------
template<bool RESID>
__global__ __launch_bounds__(256) void gemm_tn(const float* __restrict__ A, int lda,
                        const float* __restrict__ W,
                        float* __restrict__ C, int ldc,
                        const float* __restrict__ R, int ldr,
                        int N, int K)
{
    __shared__ float As[16][68];
    __shared__ float Bs[16][68];
    int bm = blockIdx.x*64, bn = blockIdx.y*64;
    int tid = threadIdx.x;
    int tn = tid & 15, tm = tid >> 4;
    int lrow = tid >> 2, lkq = (tid & 3)*4;
    float acc[4][4] = {};
    for (int k0=0; k0<K; k0+=16){
        float4 va = *(const float4*)(A + (size_t)(bm+lrow)*lda + k0 + lkq);
        As[lkq+0][lrow]=va.x; As[lkq+1][lrow]=va.y; As[lkq+2][lrow]=va.z; As[lkq+3][lrow]=va.w;
        int wr = bn + lrow;
        float4 vb = make_float4(0.f,0.f,0.f,0.f);
        if (wr < N) vb = *(const float4*)(W + (size_t)wr*K + k0 + lkq);
        Bs[lkq+0][lrow]=vb.x; Bs[lkq+1][lrow]=vb.y; Bs[lkq+2][lrow]=vb.z; Bs[lkq+3][lrow]=vb.w;
        __syncthreads();
        #pragma unroll
        for (int k=0;k<16;++k){
            float4 av = *(const float4*)&As[k][tm*4];
            float4 bv = *(const float4*)&Bs[k][tn*4];
            float a[4]={av.x,av.y,av.z,av.w};
            float bb[4]={bv.x,bv.y,bv.z,bv.w};
            #pragma unroll
            for (int i=0;i<4;++i)
                #pragma unroll
                for (int j=0;j<4;++j)
                    acc[i][j] = fmaf(a[i], bb[j], acc[i][j]);
        }
        __syncthreads();
    }
    #pragma unroll
    for (int i=0;i<4;++i){
        int row = bm + tm*4 + i;
        #pragma unroll
        for (int j=0;j<4;++j){
            int col = bn + tn*4 + j;
            if (col < N){
                float v = acc[i][j];
                if (RESID) v += R[(size_t)row*ldr + col];
                C[(size_t)row*ldc + col] = v;
            }
        }
    }
}

// ---------------- f32 GEMM (A K-major / transposed): C[M,N] = A^T @ W^T ----------------
// At layout: [BB][K][LL] (row base (b*K+k)*LL + t). M-tiles never cross b (LL%64==0).
template<bool RESID>
__global__ __launch_bounds__(256) void gemm_nt(const float* __restrict__ At,
                        const float* __restrict__ W,
                        float* __restrict__ C, int ldc,
                        const float* __restrict__ R, int ldr,
                        int N, int K)
{
    __shared__ float As[16][68];
    __shared__ float Bs[16][68];
    int bm = blockIdx.x*64, bn = blockIdx.y*64;
    int b  = bm >> 11;            // /LL
    int t0 = bm & (LL-1);
    int tid = threadIdx.x;
    int tn = tid & 15, tm = tid >> 4;
    int lrow = tid >> 2, lkq = (tid & 3)*4;   // for W staging
    int akk = tid & 15, amq = tid >> 4;       // for A^T staging: k row, m quad
    float acc[4][4] = {};
    for (int k0=0; k0<K; k0+=16){
        float4 va = *(const float4*)(At + ((size_t)b*K + k0 + akk)*LL + t0 + amq*4);
        As[akk][amq*4+0]=va.x; As[akk][amq*4+1]=va.y; As[akk][amq*4+2]=va.z; As[akk][amq*4+3]=va.w;
        int wr = bn + lrow;
        float4 vb = make_float4(0.f,0.f,0.f,0.f);
        if (wr < N) vb = *(const float4*)(W + (size_t)wr*K + k0 + lkq);
        Bs[lkq+0][lrow]=vb.x; Bs[lkq+1][lrow]=vb.y; Bs[lkq+2][lrow]=vb.z; Bs[lkq+3][lrow]=vb.w;
        __syncthreads();
        #pragma unroll
        for (int k=0;k<16;++k){
            float4 av = *(const float4*)&As[k][tm*4];
            float4 bv = *(const float4*)&Bs[k][tn*4];
            float a[4]={av.x,av.y,av.z,av.w};
            float bb[4]={bv.x,bv.y,bv.z,bv.w};
            #pragma unroll
            for (int i=0;i<4;++i)
                #pragma unroll
                for (int j=0;j<4;++j)
                    acc[i][j] = fmaf(a[i], bb[j], acc[i][j]);
        }
        __syncthreads();
    }
    #pragma unroll
    for (int i=0;i<4;++i){
        int row = bm + tm*4 + i;
        #pragma unroll
        for (int j=0;j<4;++j){
            int col = bn + tn*4 + j;
            if (col < N){
                float v = acc[i][j];
                if (RESID) v += R[(size_t)row*ldr + col];
                C[(size_t)row*ldc + col] = v;
            }
        }
    }
}

// ------- depthwise causal conv (k=4) + SiLU + gate prep, t-fast, transposed outputs -------
// XCt[b][d][t] = silu(conv(xi)), Gt[b][d][t] = z*sigmoid(z)
__global__ __launch_bounds__(256) void conv_t_kernel(const float* __restrict__ XZ,
                                 const float* __restrict__ cw,
                                 const float* __restrict__ cb,
                                 float* __restrict__ XCt,
                                 float* __restrict__ Gt)
{
    int idx = blockIdx.x*256 + threadIdx.x;   // (b, d, t) with t fastest
    int t = idx & (LL-1);
    int d = (idx >> 11) % DI;
    int b = idx / (LL*DI);
    size_t rowb = (size_t)b*LL;
    float acc = cb[d];
    const float* cwd = cw + d*4;
    #pragma unroll
    for (int k=0;k<4;++k){
        int tt = t - 3 + k;
        if (tt >= 0)
            acc = fmaf(XZ[(rowb + tt)*(2*DI) + d], cwd[k], acc);
    }
    float z = XZ[(rowb + t)*(2*DI) + DI + d];
    size_t o = ((size_t)b*DI + d)*LL + t;
    XCt[o] = acc * sigmoidf_(acc);
    Gt[o]  = z * sigmoidf_(z);
}

// ---------------- dt_proj (K=17) + softplus, t-fast, transposed output ----------------
__global__ __launch_bounds__(256) void dt_t_kernel(const float* __restrict__ DBLb,
                          const float* __restrict__ Wdt,
                          const float* __restrict__ bdt,
                          float* __restrict__ DELt)
{
    int idx = blockIdx.x*256 + threadIdx.x;   // (b, d, t) with t fastest
    int t = idx & (LL-1);
    int d = (idx >> 11) % DI;
    int b = idx / (LL*DI);
    const float* dtv = DBLb + ((size_t)b*LL + t)*145;
    const float* wr  = Wdt + d*DTR;
    float s = bdt[d];
    #pragma unroll
    for (int r=0;r<DTR;++r) s = fmaf(dtv[r], wr[r], s);
    DELt[((size_t)b*DI + d)*LL + t] = (s > 20.f) ? s : log1pf(__expf(s));
}

// ---------------- single-pass selective scan: one wave per (b,d) ----------------
// Per 64-step block: coalesced loads of delta/u/g, precompute e[64], then
// per-step: h = e*h + (du)*B; y_t = wsum(h*C). Output (y+u*Dd)*g overwrites XCt.
__global__ __launch_bounds__(256) void scan1_kernel(const float* __restrict__ DELt,
                             float* __restrict__ XCt,      // in: u ; out: y (overlay)
                             const float* __restrict__ Gt,
                             const float* __restrict__ DBLb,
                             const float* __restrict__ A_log,
                             const float* __restrict__ Dskip)
{
    int wave = threadIdx.x >> 6, lane = threadIdx.x & 63;
    int wid = blockIdx.x*4 + wave;            // 0..BB*DI-1
    int b = wid / DI, d = wid - b*DI;
    float Aval = -__expf(A_log[d*DS + lane]);
    float Dd = Dskip[d];
    float h = 0.f;
    size_t rbase = ((size_t)b*DI + d)*LL;
    const float* pB = DBLb + (size_t)b*LL*145;
    for (int blk=0; blk<LL/64; ++blk){
        size_t o = rbase + blk*64 + lane;
        float dl = DELt[o];
        float ul = XCt[o];
        float gl = Gt[o];
        float du = dl*ul;
        float e[64];
        #pragma unroll
        for (int s=0;s<64;++s) e[s] = __expf(rlf(dl,s)*Aval);
        float y = 0.f;
        const float* p = pB + (size_t)blk*64*145;
        #pragma unroll
        for (int s=0;s<64;++s){
            float Bv = p[17+lane];
            float Cv = p[81+lane];
            h = fmaf(e[s], h, rlf(du,s)*Bv);
            float pp = wsum64(h*Cv);
            float pb = rlf(pp, 63);
            if (lane == s) y = pb;
            p += 145;
        }
        XCt[o] = (y + ul*Dd)*gl;
    }
}

// ---------------- mean-pool + regression head ----------------
__global__ __launch_bounds__(256) void head_kernel(const float* __restrict__ X,
                            const float* __restrict__ reg_w,
                            const float* __restrict__ reg_b,
                            float* __restrict__ out)
{
    __shared__ float feat[DM];
    int b = blockIdx.x, tid = threadIdx.x;
    for (int dm = tid; dm < DM; dm += 256){
        float s = 0.f;
        const float* base = X + ((size_t)b*LL)*DM + dm;
        #pragma unroll 8
        for (int l=0;l<LL;++l) s += base[(size_t)l*DM];
        float f = s * (1.0f/LL);
        feat[dm] = f;
        out[16 + b*DM + dm] = f;
    }
    __syncthreads();
    if (tid < NSC){
        float s = reg_b[tid];
        const float* wr = reg_w + tid*DM;
        for (int k=0;k<DM;++k) s = fmaf(feat[k], wr[k], s);
        out[b*NSC + tid] = s;
    }
}

extern "C" void kernel_launch(void* const* d_in, const int* in_sizes, int n_in,
                              void* d_out, int out_size, void* d_ws, size_t ws_size,
                              hipStream_t stream)
{
    const float* x_in  = (const float*)d_in[0];
    const float* ln_w  = (const float*)d_in[1];
    const float* ln_b  = (const float*)d_in[2];
    const float* Wi    = (const float*)d_in[3];
    const float* cw    = (const float*)d_in[4];
    const float* cb    = (const float*)d_in[5];
    const float* Wx    = (const float*)d_in[6];
    const float* Wdt   = (const float*)d_in[7];
    const float* bdt   = (const float*)d_in[8];
    const float* A_log = (const float*)d_in[9];
    const float* Dd    = (const float*)d_in[10];
    const float* Wo    = (const float*)d_in[11];
    const float* regw  = (const float*)d_in[12];
    const float* regb  = (const float*)d_in[13];
    float* out = (float*)d_out;

    float* ws   = (float*)d_ws;
    float* H    = ws;                          // 8192*272
    float* XZ   = H    + (size_t)MTOK*DM;      // 8192*1088 (dead after conv; DELt overlays)
    float* XCt  = XZ   + (size_t)MTOK*2*DI;    // [BB][DI][LL] u; y overlays after scan
    float* Gt   = XCt  + (size_t)MTOK*DI;      // [BB][DI][LL]
    float* DBLb = Gt   + (size_t)MTOK*DI;      // 8192*145
    float* Xb   = DBLb + (size_t)MTOK*145;     // 8192*272 residual stream
    float* DELt = XZ;                          // overlays dead XZ (needs 8192*544 < 8192*1088)

    (void)hipMemcpyAsync(Xb, x_in, sizeof(float)*(size_t)MTOK*DM, hipMemcpyDeviceToDevice, stream);

    for (int l=0; l<NL; ++l){
        ln_kernel<<<MTOK/4, 256, 0, stream>>>(Xb, ln_w + l*DM, ln_b + l*DM, H);
        gemm_tn<false><<<dim3(MTOK/64, (2*DI+63)/64), 256, 0, stream>>>(
            H, DM, Wi + (size_t)l*2*DI*DM, XZ, 2*DI, nullptr, 0, 2*DI, DM);
        conv_t_kernel<<<(MTOK*DI)/256, 256, 0, stream>>>(XZ, cw + l*DI*4, cb + l*DI, XCt, Gt);
        gemm_nt<false><<<dim3(MTOK/64, (145+63)/64), 256, 0, stream>>>(
            XCt, Wx + (size_t)l*145*DI, DBLb, 145, nullptr, 0, 145, DI);
        dt_t_kernel<<<(MTOK*DI)/256, 256, 0, stream>>>(DBLb, Wdt + (size_t)l*DI*DTR, bdt + l*DI, DELt);
        scan1_kernel<<<(BB*DI)/4, 256, 0, stream>>>(DELt, XCt, Gt, DBLb,
                                                    A_log + (size_t)l*DI*DS, Dd + l*DI);
        gemm_nt<true><<<dim3(MTOK/64, (DM+63)/64), 256, 0, stream>>>(
            XCt, Wo + (size_t)l*DM*DI, Xb, DM, Xb, DM, DM, DI);
    }
    head_kernel<<<BB, 256, 0, stream>>>(Xb, regw, regb, out);
}

// Round 5
// 3384.830 us; speedup vs baseline: 1.7117x; 1.7117x over previous
//
#include <hip/hip_runtime.h>
#include <hip/hip_bf16.h>
#include <math.h>

#define NL 6
#define DM 272
#define DS 64
#define DI 544
#define DTR 17
#define NSC 4
#define BB 4
#define LL 2048
#define MTOK (BB*LL)

__device__ __forceinline__ float sigmoidf_(float x){ return 1.0f/(1.0f+__expf(-x)); }
__device__ __forceinline__ float rlf(float x, int s){ return __int_as_float(__builtin_amdgcn_readlane(__float_as_int(x), s)); }

#define DPPADD(x, ctrl) x += __int_as_float(__builtin_amdgcn_update_dpp(0, __float_as_int(x), ctrl, 0xf, 0xf, true))
// full-wave64 sum; result valid in lane 63
__device__ __forceinline__ float wsum64(float x){
    DPPADD(x, 0x111); // row_shr:1
    DPPADD(x, 0x112); // row_shr:2
    DPPADD(x, 0x114); // row_shr:4
    DPPADD(x, 0x118); // row_shr:8
    DPPADD(x, 0x142); // row_bcast:15
    DPPADD(x, 0x143); // row_bcast:31
    return x;
}

// ---------------- LayerNorm: one wave per token ----------------
__global__ __launch_bounds__(256) void ln_kernel(const float* __restrict__ X,
                          const float* __restrict__ w,
                          const float* __restrict__ b,
                          float* __restrict__ H)
{
    int wave = threadIdx.x >> 6;
    int lane = threadIdx.x & 63;
    int tok = blockIdx.x*4 + wave;
    const float* xr = X + (size_t)tok*DM;
    float v[5];
    float s=0.f, ss=0.f;
    #pragma unroll
    for (int j=0;j<5;++j){
        int idx = lane + j*64;
        float x = (idx < DM) ? xr[idx] : 0.f;
        v[j]=x; s+=x; ss+=x*x;
    }
    #pragma unroll
    for (int off=1; off<64; off<<=1){ s += __shfl_xor(s,off); ss += __shfl_xor(ss,off); }
    float mu  = s * (1.0f/DM);
    float var = ss*(1.0f/DM) - mu*mu;
    float inv = 1.0f/sqrtf(var + 1e-5f);
    float* hr = H + (size_t)tok*DM;
    #pragma unroll
    for (int j=0;j<5;++j){
        int idx = lane + j*64;
        if (idx<DM) hr[idx] = (v[j]-mu)*inv*w[idx] + b[idx];
    }
}

// ---------------- f32 GEMM (A row-major): C[M,N] = A[M,K] @ W[N,K]^T ----------------
template<bool RESID>
__global__ __launch_bounds__(256) void gemm_tn(const float* __restrict__ A, int lda,
                        const float* __restrict__ W,
                        float* __restrict__ C, int ldc,
                        const float* __restrict__ R, int ldr,
                        int N, int K)
{
    __shared__ float As[16][68];
    __shared__ float Bs[16][68];
    int bm = blockIdx.x*64, bn = blockIdx.y*64;
    int tid = threadIdx.x;
    int tn = tid & 15, tm = tid >> 4;
    int lrow = tid >> 2, lkq = (tid & 3)*4;
    float acc[4][4] = {};
    for (int k0=0; k0<K; k0+=16){
        float4 va = *(const float4*)(A + (size_t)(bm+lrow)*lda + k0 + lkq);
        As[lkq+0][lrow]=va.x; As[lkq+1][lrow]=va.y; As[lkq+2][lrow]=va.z; As[lkq+3][lrow]=va.w;
        int wr = bn + lrow;
        float4 vb = make_float4(0.f,0.f,0.f,0.f);
        if (wr < N) vb = *(const float4*)(W + (size_t)wr*K + k0 + lkq);
        Bs[lkq+0][lrow]=vb.x; Bs[lkq+1][lrow]=vb.y; Bs[lkq+2][lrow]=vb.z; Bs[lkq+3][lrow]=vb.w;
        __syncthreads();
        #pragma unroll
        for (int k=0;k<16;++k){
            float4 av = *(const float4*)&As[k][tm*4];
            float4 bv = *(const float4*)&Bs[k][tn*4];
            float a[4]={av.x,av.y,av.z,av.w};
            float bb[4]={bv.x,bv.y,bv.z,bv.w};
            #pragma unroll
            for (int i=0;i<4;++i)
                #pragma unroll
                for (int j=0;j<4;++j)
                    acc[i][j] = fmaf(a[i], bb[j], acc[i][j]);
        }
        __syncthreads();
    }
    #pragma unroll
    for (int i=0;i<4;++i){
        int row = bm + tm*4 + i;
        #pragma unroll
        for (int j=0;j<4;++j){
            int col = bn + tn*4 + j;
            if (col < N){
                float v = acc[i][j];
                if (RESID) v += R[(size_t)row*ldr + col];
                C[(size_t)row*ldc + col] = v;
            }
        }
    }
}

// ---------------- f32 GEMM (A K-major / transposed): C[M,N] = A^T @ W^T ----------------
// At layout: [BB][K][LL] (row base (b*K+k)*LL + t). M-tiles never cross b (LL%64==0).
template<bool RESID>
__global__ __launch_bounds__(256) void gemm_nt(const float* __restrict__ At,
                        const float* __restrict__ W,
                        float* __restrict__ C, int ldc,
                        const float* __restrict__ R, int ldr,
                        int N, int K)
{
    __shared__ float As[16][68];
    __shared__ float Bs[16][68];
    int bm = blockIdx.x*64, bn = blockIdx.y*64;
    int b  = bm >> 11;            // /LL
    int t0 = bm & (LL-1);
    int tid = threadIdx.x;
    int tn = tid & 15, tm = tid >> 4;
    int lrow = tid >> 2, lkq = (tid & 3)*4;   // for W staging
    int akk = tid & 15, amq = tid >> 4;       // for A^T staging: k row, m quad
    float acc[4][4] = {};
    for (int k0=0; k0<K; k0+=16){
        float4 va = *(const float4*)(At + ((size_t)b*K + k0 + akk)*LL + t0 + amq*4);
        As[akk][amq*4+0]=va.x; As[akk][amq*4+1]=va.y; As[akk][amq*4+2]=va.z; As[akk][amq*4+3]=va.w;
        int wr = bn + lrow;
        float4 vb = make_float4(0.f,0.f,0.f,0.f);
        if (wr < N) vb = *(const float4*)(W + (size_t)wr*K + k0 + lkq);
        Bs[lkq+0][lrow]=vb.x; Bs[lkq+1][lrow]=vb.y; Bs[lkq+2][lrow]=vb.z; Bs[lkq+3][lrow]=vb.w;
        __syncthreads();
        #pragma unroll
        for (int k=0;k<16;++k){
            float4 av = *(const float4*)&As[k][tm*4];
            float4 bv = *(const float4*)&Bs[k][tn*4];
            float a[4]={av.x,av.y,av.z,av.w};
            float bb[4]={bv.x,bv.y,bv.z,bv.w};
            #pragma unroll
            for (int i=0;i<4;++i)
                #pragma unroll
                for (int j=0;j<4;++j)
                    acc[i][j] = fmaf(a[i], bb[j], acc[i][j]);
        }
        __syncthreads();
    }
    #pragma unroll
    for (int i=0;i<4;++i){
        int row = bm + tm*4 + i;
        #pragma unroll
        for (int j=0;j<4;++j){
            int col = bn + tn*4 + j;
            if (col < N){
                float v = acc[i][j];
                if (RESID) v += R[(size_t)row*ldr + col];
                C[(size_t)row*ldc + col] = v;
            }
        }
    }
}

// ------- conv+SiLU+gate with LDS transpose: coalesced in (over d) and out (over t) -------
// tile: 64 t x 68 d for one b. xi halo 3 rows. Outputs XCt/Gt in [b][d][t].
__global__ __launch_bounds__(256) void conv_t2_kernel(const float* __restrict__ XZ,
                                 const float* __restrict__ cw,
                                 const float* __restrict__ cb,
                                 float* __restrict__ XCt,
                                 float* __restrict__ Gt)
{
    __shared__ float xi[67][69];
    __shared__ float zz[64][69];
    int bid = blockIdx.x;
    int b  = bid >> 8;            // 256 tiles per b
    int rem = bid & 255;
    int t0 = (rem >> 3)*64;
    int d0 = (rem & 7)*68;
    int tid = threadIdx.x;
    // stage xi tile rows t0-3 .. t0+63
    for (int li = tid; li < 67*17; li += 256){
        int row = li / 17, q = li - row*17;
        int tg = t0 - 3 + row;
        float4 v = make_float4(0.f,0.f,0.f,0.f);
        if (tg >= 0)
            v = *(const float4*)(XZ + ((size_t)b*LL + tg)*(2*DI) + d0 + q*4);
        xi[row][q*4+0]=v.x; xi[row][q*4+1]=v.y; xi[row][q*4+2]=v.z; xi[row][q*4+3]=v.w;
    }
    // stage z tile rows t0 .. t0+63
    for (int li = tid; li < 64*17; li += 256){
        int row = li / 17, q = li - row*17;
        float4 v = *(const float4*)(XZ + ((size_t)b*LL + t0 + row)*(2*DI) + DI + d0 + q*4);
        zz[row][q*4+0]=v.x; zz[row][q*4+1]=v.y; zz[row][q*4+2]=v.z; zz[row][q*4+3]=v.w;
    }
    __syncthreads();
    int t = tid & 63;
    #pragma unroll 1
    for (int dl = tid >> 6; dl < 68; dl += 4){
        int d = d0 + dl;
        const float* cwd = cw + d*4;
        float acc = cb[d];
        #pragma unroll
        for (int k=0;k<4;++k) acc = fmaf(xi[t+k][dl], cwd[k], acc);
        float xc = acc * sigmoidf_(acc);
        float z  = zz[t][dl];
        size_t o = ((size_t)b*DI + d)*LL + t0 + t;
        XCt[o] = xc;
        Gt[o]  = z * sigmoidf_(z);
    }
}

// ------- dt_proj (K=17) + softplus, LDS-staged, coalesced output over t -------
__global__ __launch_bounds__(256) void dt_t2_kernel(const float* __restrict__ DBLb,
                          const float* __restrict__ Wdt,
                          const float* __restrict__ bdt,
                          float* __restrict__ DELt)
{
    __shared__ float dtv[64*19];
    __shared__ float wl[68*17];
    int bid = blockIdx.x;
    int b  = bid >> 8;
    int rem = bid & 255;
    int t0 = (rem >> 3)*64;
    int d0 = (rem & 7)*68;
    int tid = threadIdx.x;
    for (int li = tid; li < 64*17; li += 256){
        int row = li / 17, col = li - row*17;
        dtv[row*19 + col] = DBLb[((size_t)b*LL + t0 + row)*145 + col];
    }
    for (int li = tid; li < 68*17; li += 256)
        wl[li] = Wdt[(size_t)d0*17 + li];
    __syncthreads();
    int t = tid & 63;
    #pragma unroll 1
    for (int dl = tid >> 6; dl < 68; dl += 4){
        float s = bdt[d0 + dl];
        #pragma unroll
        for (int r=0;r<DTR;++r) s = fmaf(dtv[t*19 + r], wl[dl*17 + r], s);
        float sp = (s > 20.f) ? s : log1pf(__expf(s));
        DELt[((size_t)b*DI + d0 + dl)*LL + t0 + t] = sp;
    }
}

// ---------------- single-pass selective scan: one wave per (b, {d, d+272}) ----------------
// B/C loads shared by the two d-states; exp hoisted in 16-step register blocks.
__global__ __launch_bounds__(256) void scan1_kernel(const float* __restrict__ DELt,
                             float* __restrict__ XCt,      // in: u ; out: y (overlay)
                             const float* __restrict__ Gt,
                             const float* __restrict__ DBLb,
                             const float* __restrict__ A_log,
                             const float* __restrict__ Dskip)
{
    int wave = threadIdx.x >> 6, lane = threadIdx.x & 63;
    int wid = blockIdx.x*4 + wave;            // 0..BB*DI/2-1
    int b = wid / (DI/2), dd = wid - b*(DI/2);
    int d0 = dd, d1 = dd + DI/2;
    float Av0 = -__expf(A_log[d0*DS + lane]);
    float Av1 = -__expf(A_log[d1*DS + lane]);
    float Dd0 = Dskip[d0], Dd1 = Dskip[d1];
    float h0 = 0.f, h1 = 0.f;
    size_t rb0 = ((size_t)b*DI + d0)*LL;
    size_t rb1 = ((size_t)b*DI + d1)*LL;
    const float* pB = DBLb + (size_t)b*LL*145;
    for (int blk=0; blk<LL/64; ++blk){
        size_t o0 = rb0 + blk*64 + lane;
        size_t o1 = rb1 + blk*64 + lane;
        float dl0 = DELt[o0], dl1 = DELt[o1];
        float ul0 = XCt[o0],  ul1 = XCt[o1];
        float gl0 = Gt[o0],   gl1 = Gt[o1];
        float du0 = dl0*ul0,  du1 = dl1*ul1;
        float y0 = 0.f, y1 = 0.f;
        const float* p = pB + (size_t)blk*64*145;
        #pragma unroll 1
        for (int sub=0; sub<4; ++sub){
            float e0[16], e1[16];
            #pragma unroll
            for (int i=0;i<16;++i){
                int s = sub*16 + i;
                e0[i] = __expf(rlf(dl0,s)*Av0);
                e1[i] = __expf(rlf(dl1,s)*Av1);
            }
            #pragma unroll
            for (int i=0;i<16;++i){
                int s = sub*16 + i;
                float Bv = p[17+lane];
                float Cv = p[81+lane];
                h0 = fmaf(e0[i], h0, rlf(du0,s)*Bv);
                h1 = fmaf(e1[i], h1, rlf(du1,s)*Bv);
                float pp0 = wsum64(h0*Cv);
                float pp1 = wsum64(h1*Cv);
                float pb0 = rlf(pp0, 63);
                float pb1 = rlf(pp1, 63);
                if (lane == s){ y0 = pb0; y1 = pb1; }
                p += 145;
            }
        }
        XCt[o0] = (y0 + ul0*Dd0)*gl0;
        XCt[o1] = (y1 + ul1*Dd1)*gl1;
    }
}

// ---------------- mean-pool + regression head ----------------
__global__ __launch_bounds__(256) void head_kernel(const float* __restrict__ X,
                            const float* __restrict__ reg_w,
                            const float* __restrict__ reg_b,
                            float* __restrict__ out)
{
    __shared__ float feat[DM];
    int b = blockIdx.x, tid = threadIdx.x;
    for (int dm = tid; dm < DM; dm += 256){
        float s = 0.f;
        const float* base = X + ((size_t)b*LL)*DM + dm;
        #pragma unroll 8
        for (int l=0;l<LL;++l) s += base[(size_t)l*DM];
        float f = s * (1.0f/LL);
        feat[dm] = f;
        out[16 + b*DM + dm] = f;
    }
    __syncthreads();
    if (tid < NSC){
        float s = reg_b[tid];
        const float* wr = reg_w + tid*DM;
        for (int k=0;k<DM;++k) s = fmaf(feat[k], wr[k], s);
        out[b*NSC + tid] = s;
    }
}

extern "C" void kernel_launch(void* const* d_in, const int* in_sizes, int n_in,
                              void* d_out, int out_size, void* d_ws, size_t ws_size,
                              hipStream_t stream)
{
    const float* x_in  = (const float*)d_in[0];
    const float* ln_w  = (const float*)d_in[1];
    const float* ln_b  = (const float*)d_in[2];
    const float* Wi    = (const float*)d_in[3];
    const float* cw    = (const float*)d_in[4];
    const float* cb    = (const float*)d_in[5];
    const float* Wx    = (const float*)d_in[6];
    const float* Wdt   = (const float*)d_in[7];
    const float* bdt   = (const float*)d_in[8];
    const float* A_log = (const float*)d_in[9];
    const float* Dd    = (const float*)d_in[10];
    const float* Wo    = (const float*)d_in[11];
    const float* regw  = (const float*)d_in[12];
    const float* regb  = (const float*)d_in[13];
    float* out = (float*)d_out;

    float* ws   = (float*)d_ws;
    float* H    = ws;                          // 8192*272
    float* XZ   = H    + (size_t)MTOK*DM;      // 8192*1088 (dead after conv; DELt overlays)
    float* XCt  = XZ   + (size_t)MTOK*2*DI;    // [BB][DI][LL] u; y overlays after scan
    float* Gt   = XCt  + (size_t)MTOK*DI;      // [BB][DI][LL]
    float* DBLb = Gt   + (size_t)MTOK*DI;      // 8192*145
    float* Xb   = DBLb + (size_t)MTOK*145;     // 8192*272 residual stream
    float* DELt = XZ;                          // overlays dead XZ

    (void)hipMemcpyAsync(Xb, x_in, sizeof(float)*(size_t)MTOK*DM, hipMemcpyDeviceToDevice, stream);

    for (int l=0; l<NL; ++l){
        ln_kernel<<<MTOK/4, 256, 0, stream>>>(Xb, ln_w + l*DM, ln_b + l*DM, H);
        gemm_tn<false><<<dim3(MTOK/64, (2*DI+63)/64), 256, 0, stream>>>(
            H, DM, Wi + (size_t)l*2*DI*DM, XZ, 2*DI, nullptr, 0, 2*DI, DM);
        conv_t2_kernel<<<BB*256, 256, 0, stream>>>(XZ, cw + l*DI*4, cb + l*DI, XCt, Gt);
        gemm_nt<false><<<dim3(MTOK/64, (145+63)/64), 256, 0, stream>>>(
            XCt, Wx + (size_t)l*145*DI, DBLb, 145, nullptr, 0, 145, DI);
        dt_t2_kernel<<<BB*256, 256, 0, stream>>>(DBLb, Wdt + (size_t)l*DI*DTR, bdt + l*DI, DELt);
        scan1_kernel<<<(BB*DI/2)/4, 256, 0, stream>>>(DELt, XCt, Gt, DBLb,
                                                      A_log + (size_t)l*DI*DS, Dd + l*DI);
        gemm_nt<true><<<dim3(MTOK/64, (DM+63)/64), 256, 0, stream>>>(
            XCt, Wo + (size_t)l*DM*DI, Xb, DM, Xb, DM, DM, DI);
    }
    head_kernel<<<BB, 256, 0, stream>>>(Xb, regw, regb, out);
}

// Round 6
// 3012.747 us; speedup vs baseline: 1.9231x; 1.1235x over previous
//
#include <hip/hip_runtime.h>
#include <hip/hip_bf16.h>
#include <math.h>

#define NL 6
#define DM 272
#define DS 64
#define DI 544
#define DTR 17
#define NSC 4
#define BB 4
#define LL 2048
#define MTOK (BB*LL)
#define TCH 512
#define CH  4

__device__ __forceinline__ float sigmoidf_(float x){ return 1.0f/(1.0f+__expf(-x)); }
__device__ __forceinline__ float rlf(float x, int s){ return __int_as_float(__builtin_amdgcn_readlane(__float_as_int(x), s)); }

#define DPPADD(x, ctrl) x += __int_as_float(__builtin_amdgcn_update_dpp(0, __float_as_int(x), ctrl, 0xf, 0xf, true))
// full-wave64 sum; result valid in lane 63
__device__ __forceinline__ float wsum64(float x){
    DPPADD(x, 0x111); // row_shr:1
    DPPADD(x, 0x112); // row_shr:2
    DPPADD(x, 0x114); // row_shr:4
    DPPADD(x, 0x118); // row_shr:8
    DPPADD(x, 0x142); // row_bcast:15
    DPPADD(x, 0x143); // row_bcast:31
    return x;
}

// ---------------- LayerNorm: one wave per token ----------------
__global__ __launch_bounds__(256) void ln_kernel(const float* __restrict__ X,
                          const float* __restrict__ w,
                          const float* __restrict__ b,
                          float* __restrict__ H)
{
    int wave = threadIdx.x >> 6;
    int lane = threadIdx.x & 63;
    int tok = blockIdx.x*4 + wave;
    const float* xr = X + (size_t)tok*DM;
    float v[5];
    float s=0.f, ss=0.f;
    #pragma unroll
    for (int j=0;j<5;++j){
        int idx = lane + j*64;
        float x = (idx < DM) ? xr[idx] : 0.f;
        v[j]=x; s+=x; ss+=x*x;
    }
    #pragma unroll
    for (int off=1; off<64; off<<=1){ s += __shfl_xor(s,off); ss += __shfl_xor(ss,off); }
    float mu  = s * (1.0f/DM);
    float var = ss*(1.0f/DM) - mu*mu;
    float inv = 1.0f/sqrtf(var + 1e-5f);
    float* hr = H + (size_t)tok*DM;
    #pragma unroll
    for (int j=0;j<5;++j){
        int idx = lane + j*64;
        if (idx<DM) hr[idx] = (v[j]-mu)*inv*w[idx] + b[idx];
    }
}

// ---------------- f32 GEMM (A row-major): C[M,N] = A[M,K] @ W[N,K]^T ----------------
template<bool RESID>
__global__ __launch_bounds__(256) void gemm_tn(const float* __restrict__ A, int lda,
                        const float* __restrict__ W,
                        float* __restrict__ C, int ldc,
                        const float* __restrict__ R, int ldr,
                        int N, int K)
{
    __shared__ float As[16][68];
    __shared__ float Bs[16][68];
    int bm = blockIdx.x*64, bn = blockIdx.y*64;
    int tid = threadIdx.x;
    int tn = tid & 15, tm = tid >> 4;
    int lrow = tid >> 2, lkq = (tid & 3)*4;
    float acc[4][4] = {};
    for (int k0=0; k0<K; k0+=16){
        float4 va = *(const float4*)(A + (size_t)(bm+lrow)*lda + k0 + lkq);
        As[lkq+0][lrow]=va.x; As[lkq+1][lrow]=va.y; As[lkq+2][lrow]=va.z; As[lkq+3][lrow]=va.w;
        int wr = bn + lrow;
        float4 vb = make_float4(0.f,0.f,0.f,0.f);
        if (wr < N) vb = *(const float4*)(W + (size_t)wr*K + k0 + lkq);
        Bs[lkq+0][lrow]=vb.x; Bs[lkq+1][lrow]=vb.y; Bs[lkq+2][lrow]=vb.z; Bs[lkq+3][lrow]=vb.w;
        __syncthreads();
        #pragma unroll
        for (int k=0;k<16;++k){
            float4 av = *(const float4*)&As[k][tm*4];
            float4 bv = *(const float4*)&Bs[k][tn*4];
            float a[4]={av.x,av.y,av.z,av.w};
            float bb[4]={bv.x,bv.y,bv.z,bv.w};
            #pragma unroll
            for (int i=0;i<4;++i)
                #pragma unroll
                for (int j=0;j<4;++j)
                    acc[i][j] = fmaf(a[i], bb[j], acc[i][j]);
        }
        __syncthreads();
    }
    #pragma unroll
    for (int i=0;i<4;++i){
        int row = bm + tm*4 + i;
        #pragma unroll
        for (int j=0;j<4;++j){
            int col = bn + tn*4 + j;
            if (col < N){
                float v = acc[i][j];
                if (RESID) v += R[(size_t)row*ldr + col];
                C[(size_t)row*ldc + col] = v;
            }
        }
    }
}

// ---------------- f32 GEMM (A K-major / transposed): C[M,N] = A^T @ W^T ----------------
// At layout: [BB][K][LL] (row base (b*K+k)*LL + t). M-tiles never cross b (LL%64==0).
template<bool RESID>
__global__ __launch_bounds__(256) void gemm_nt(const float* __restrict__ At,
                        const float* __restrict__ W,
                        float* __restrict__ C, int ldc,
                        const float* __restrict__ R, int ldr,
                        int N, int K)
{
    __shared__ float As[16][68];
    __shared__ float Bs[16][68];
    int bm = blockIdx.x*64, bn = blockIdx.y*64;
    int b  = bm >> 11;            // /LL
    int t0 = bm & (LL-1);
    int tid = threadIdx.x;
    int tn = tid & 15, tm = tid >> 4;
    int lrow = tid >> 2, lkq = (tid & 3)*4;   // for W staging
    int akk = tid & 15, amq = tid >> 4;       // for A^T staging: k row, m quad
    float acc[4][4] = {};
    for (int k0=0; k0<K; k0+=16){
        float4 va = *(const float4*)(At + ((size_t)b*K + k0 + akk)*LL + t0 + amq*4);
        As[akk][amq*4+0]=va.x; As[akk][amq*4+1]=va.y; As[akk][amq*4+2]=va.z; As[akk][amq*4+3]=va.w;
        int wr = bn + lrow;
        float4 vb = make_float4(0.f,0.f,0.f,0.f);
        if (wr < N) vb = *(const float4*)(W + (size_t)wr*K + k0 + lkq);
        Bs[lkq+0][lrow]=vb.x; Bs[lkq+1][lrow]=vb.y; Bs[lkq+2][lrow]=vb.z; Bs[lkq+3][lrow]=vb.w;
        __syncthreads();
        #pragma unroll
        for (int k=0;k<16;++k){
            float4 av = *(const float4*)&As[k][tm*4];
            float4 bv = *(const float4*)&Bs[k][tn*4];
            float a[4]={av.x,av.y,av.z,av.w};
            float bb[4]={bv.x,bv.y,bv.z,bv.w};
            #pragma unroll
            for (int i=0;i<4;++i)
                #pragma unroll
                for (int j=0;j<4;++j)
                    acc[i][j] = fmaf(a[i], bb[j], acc[i][j]);
        }
        __syncthreads();
    }
    #pragma unroll
    for (int i=0;i<4;++i){
        int row = bm + tm*4 + i;
        #pragma unroll
        for (int j=0;j<4;++j){
            int col = bn + tn*4 + j;
            if (col < N){
                float v = acc[i][j];
                if (RESID) v += R[(size_t)row*ldr + col];
                C[(size_t)row*ldc + col] = v;
            }
        }
    }
}

// ------- conv+SiLU+gate with LDS transpose: coalesced in (over d) and out (over t) -------
__global__ __launch_bounds__(256) void conv_t2_kernel(const float* __restrict__ XZ,
                                 const float* __restrict__ cw,
                                 const float* __restrict__ cb,
                                 float* __restrict__ XCt,
                                 float* __restrict__ Gt)
{
    __shared__ float xi[67][69];
    __shared__ float zz[64][69];
    int bid = blockIdx.x;
    int b  = bid >> 8;            // 256 tiles per b
    int rem = bid & 255;
    int t0 = (rem >> 3)*64;
    int d0 = (rem & 7)*68;
    int tid = threadIdx.x;
    for (int li = tid; li < 67*17; li += 256){
        int row = li / 17, q = li - row*17;
        int tg = t0 - 3 + row;
        float4 v = make_float4(0.f,0.f,0.f,0.f);
        if (tg >= 0)
            v = *(const float4*)(XZ + ((size_t)b*LL + tg)*(2*DI) + d0 + q*4);
        xi[row][q*4+0]=v.x; xi[row][q*4+1]=v.y; xi[row][q*4+2]=v.z; xi[row][q*4+3]=v.w;
    }
    for (int li = tid; li < 64*17; li += 256){
        int row = li / 17, q = li - row*17;
        float4 v = *(const float4*)(XZ + ((size_t)b*LL + t0 + row)*(2*DI) + DI + d0 + q*4);
        zz[row][q*4+0]=v.x; zz[row][q*4+1]=v.y; zz[row][q*4+2]=v.z; zz[row][q*4+3]=v.w;
    }
    __syncthreads();
    int t = tid & 63;
    #pragma unroll 1
    for (int dl = tid >> 6; dl < 68; dl += 4){
        int d = d0 + dl;
        const float* cwd = cw + d*4;
        float acc = cb[d];
        #pragma unroll
        for (int k=0;k<4;++k) acc = fmaf(xi[t+k][dl], cwd[k], acc);
        float xc = acc * sigmoidf_(acc);
        float z  = zz[t][dl];
        size_t o = ((size_t)b*DI + d)*LL + t0 + t;
        XCt[o] = xc;
        Gt[o]  = z * sigmoidf_(z);
    }
}

// ------- dt_proj (K=17) + softplus, LDS-staged, coalesced output over t -------
__global__ __launch_bounds__(256) void dt_t2_kernel(const float* __restrict__ DBLb,
                          const float* __restrict__ Wdt,
                          const float* __restrict__ bdt,
                          float* __restrict__ DELt)
{
    __shared__ float dtv[64*19];
    __shared__ float wl[68*17];
    int bid = blockIdx.x;
    int b  = bid >> 8;
    int rem = bid & 255;
    int t0 = (rem >> 3)*64;
    int d0 = (rem & 7)*68;
    int tid = threadIdx.x;
    for (int li = tid; li < 64*17; li += 256){
        int row = li / 17, col = li - row*17;
        dtv[row*19 + col] = DBLb[((size_t)b*LL + t0 + row)*145 + col];
    }
    for (int li = tid; li < 68*17; li += 256)
        wl[li] = Wdt[(size_t)d0*17 + li];
    __syncthreads();
    int t = tid & 63;
    #pragma unroll 1
    for (int dl = tid >> 6; dl < 68; dl += 4){
        float s = bdt[d0 + dl];
        #pragma unroll
        for (int r=0;r<DTR;++r) s = fmaf(dtv[t*19 + r], wl[dl*17 + r], s);
        float sp = (s > 20.f) ? s : log1pf(__expf(s));
        DELt[((size_t)b*DI + d0 + dl)*LL + t0 + t] = sp;
    }
}

// ======= chunked scan, pass A: local scan from h=0, emit h_out + sum(delta) =======
// wave handles pair (d, d+272) of chunk c of batch b. 8-step register e-batches.
#define EBATCH(i) float e0##i = __expf(rlf(dl0, base+i)*Av0); float e1##i = __expf(rlf(dl1, base+i)*Av1);
#define STEPA(i) { float Bv = p[17+lane]; \
    h0 = fmaf(e0##i, h0, rlf(du0, base+i)*Bv); \
    h1 = fmaf(e1##i, h1, rlf(du1, base+i)*Bv); \
    p += 145; }

__global__ __launch_bounds__(256) void scan_a(const float* __restrict__ DELt,
                       const float* __restrict__ XCt,
                       const float* __restrict__ DBLb,
                       const float* __restrict__ A_log,
                       float* __restrict__ Q,
                       float* __restrict__ S)
{
    int wave = threadIdx.x >> 6, lane = threadIdx.x & 63;
    int wid = blockIdx.x*4 + wave;            // (b, c, dd) dd fastest
    int dd = wid % (DI/2);
    int c  = (wid / (DI/2)) % CH;
    int b  = wid / ((DI/2)*CH);
    int d0 = dd, d1 = dd + DI/2;
    float Av0 = -__expf(A_log[d0*DS + lane]);
    float Av1 = -__expf(A_log[d1*DS + lane]);
    float h0 = 0.f, h1 = 0.f, ds0 = 0.f, ds1 = 0.f;
    size_t rb0 = ((size_t)b*DI + d0)*LL + c*TCH;
    size_t rb1 = ((size_t)b*DI + d1)*LL + c*TCH;
    const float* pB = DBLb + ((size_t)b*LL + c*TCH)*145;
    for (int blk=0; blk<TCH/64; ++blk){
        size_t o0 = rb0 + blk*64 + lane;
        size_t o1 = rb1 + blk*64 + lane;
        float dl0 = DELt[o0], dl1 = DELt[o1];
        float ul0 = XCt[o0],  ul1 = XCt[o1];
        float du0 = dl0*ul0,  du1 = dl1*ul1;
        ds0 += dl0; ds1 += dl1;
        const float* p = pB + (size_t)blk*64*145;
        #pragma unroll 1
        for (int sub=0; sub<8; ++sub){
            int base = sub*8;
            EBATCH(0) EBATCH(1) EBATCH(2) EBATCH(3)
            EBATCH(4) EBATCH(5) EBATCH(6) EBATCH(7)
            STEPA(0) STEPA(1) STEPA(2) STEPA(3)
            STEPA(4) STEPA(5) STEPA(6) STEPA(7)
        }
    }
    size_t q0 = ((size_t)b*DI + d0)*CH + c;
    size_t q1 = ((size_t)b*DI + d1)*CH + c;
    Q[q0*64 + lane] = h0;
    Q[q1*64 + lane] = h1;
    float s0 = wsum64(ds0);
    float s1 = wsum64(ds1);
    if (lane == 63){ S[q0] = s0; S[q1] = s1; }
}

// ======= chunked scan, pass B: sequential chunk combine, h_in written into Q =======
__global__ __launch_bounds__(256) void scan_b(float* __restrict__ Q,
                       const float* __restrict__ S,
                       const float* __restrict__ A_log)
{
    int tid = threadIdx.x;
    int n = tid & 63;
    int dq = tid >> 6;                        // 4 d per block
    int b = blockIdx.x / (DI/4);
    int d = (blockIdx.x % (DI/4))*4 + dq;
    float Aval = -__expf(A_log[d*DS + n]);
    float h = 0.f;
    size_t base = ((size_t)b*DI + d)*CH;
    for (int c=0; c<CH; ++c){
        size_t idx = base + c;
        float q  = Q[idx*64 + n];
        float Sv = S[idx];
        Q[idx*64 + n] = h;                    // h_in for chunk c
        h = fmaf(__expf(Aval*Sv), h, q);
    }
}

// ======= chunked scan, pass C: re-scan from h_in, emit gated y (overlays XCt) =======
#define STEPC(i) { float Bv = p[17+lane]; float Cv = p[81+lane]; \
    h0 = fmaf(e0##i, h0, rlf(du0, base+i)*Bv); \
    h1 = fmaf(e1##i, h1, rlf(du1, base+i)*Bv); \
    float pp0 = wsum64(h0*Cv); \
    float pp1 = wsum64(h1*Cv); \
    float pb0 = rlf(pp0, 63); \
    float pb1 = rlf(pp1, 63); \
    if (lane == base+i){ y0 = pb0; y1 = pb1; } \
    p += 145; }

__global__ __launch_bounds__(256) void scan_c(const float* __restrict__ DELt,
                       float* __restrict__ XCt,           // in: u ; out: y (overlay)
                       const float* __restrict__ Gt,
                       const float* __restrict__ DBLb,
                       const float* __restrict__ A_log,
                       const float* __restrict__ Dskip,
                       const float* __restrict__ Q)
{
    int wave = threadIdx.x >> 6, lane = threadIdx.x & 63;
    int wid = blockIdx.x*4 + wave;
    int dd = wid % (DI/2);
    int c  = (wid / (DI/2)) % CH;
    int b  = wid / ((DI/2)*CH);
    int d0 = dd, d1 = dd + DI/2;
    float Av0 = -__expf(A_log[d0*DS + lane]);
    float Av1 = -__expf(A_log[d1*DS + lane]);
    float Dd0 = Dskip[d0], Dd1 = Dskip[d1];
    size_t q0 = ((size_t)b*DI + d0)*CH + c;
    size_t q1 = ((size_t)b*DI + d1)*CH + c;
    float h0 = Q[q0*64 + lane];
    float h1 = Q[q1*64 + lane];
    size_t rb0 = ((size_t)b*DI + d0)*LL + c*TCH;
    size_t rb1 = ((size_t)b*DI + d1)*LL + c*TCH;
    const float* pB = DBLb + ((size_t)b*LL + c*TCH)*145;
    for (int blk=0; blk<TCH/64; ++blk){
        size_t o0 = rb0 + blk*64 + lane;
        size_t o1 = rb1 + blk*64 + lane;
        float dl0 = DELt[o0], dl1 = DELt[o1];
        float ul0 = XCt[o0],  ul1 = XCt[o1];
        float gl0 = Gt[o0],   gl1 = Gt[o1];
        float du0 = dl0*ul0,  du1 = dl1*ul1;
        float y0 = 0.f, y1 = 0.f;
        const float* p = pB + (size_t)blk*64*145;
        #pragma unroll 1
        for (int sub=0; sub<8; ++sub){
            int base = sub*8;
            EBATCH(0) EBATCH(1) EBATCH(2) EBATCH(3)
            EBATCH(4) EBATCH(5) EBATCH(6) EBATCH(7)
            STEPC(0) STEPC(1) STEPC(2) STEPC(3)
            STEPC(4) STEPC(5) STEPC(6) STEPC(7)
        }
        XCt[o0] = (y0 + ul0*Dd0)*gl0;
        XCt[o1] = (y1 + ul1*Dd1)*gl1;
    }
}

// ---------------- mean-pool + regression head ----------------
__global__ __launch_bounds__(256) void head_kernel(const float* __restrict__ X,
                            const float* __restrict__ reg_w,
                            const float* __restrict__ reg_b,
                            float* __restrict__ out)
{
    __shared__ float feat[DM];
    int b = blockIdx.x, tid = threadIdx.x;
    for (int dm = tid; dm < DM; dm += 256){
        float s = 0.f;
        const float* base = X + ((size_t)b*LL)*DM + dm;
        #pragma unroll 8
        for (int l=0;l<LL;++l) s += base[(size_t)l*DM];
        float f = s * (1.0f/LL);
        feat[dm] = f;
        out[16 + b*DM + dm] = f;
    }
    __syncthreads();
    if (tid < NSC){
        float s = reg_b[tid];
        const float* wr = reg_w + tid*DM;
        for (int k=0;k<DM;++k) s = fmaf(feat[k], wr[k], s);
        out[b*NSC + tid] = s;
    }
}

extern "C" void kernel_launch(void* const* d_in, const int* in_sizes, int n_in,
                              void* d_out, int out_size, void* d_ws, size_t ws_size,
                              hipStream_t stream)
{
    const float* x_in  = (const float*)d_in[0];
    const float* ln_w  = (const float*)d_in[1];
    const float* ln_b  = (const float*)d_in[2];
    const float* Wi    = (const float*)d_in[3];
    const float* cw    = (const float*)d_in[4];
    const float* cb    = (const float*)d_in[5];
    const float* Wx    = (const float*)d_in[6];
    const float* Wdt   = (const float*)d_in[7];
    const float* bdt   = (const float*)d_in[8];
    const float* A_log = (const float*)d_in[9];
    const float* Dd    = (const float*)d_in[10];
    const float* Wo    = (const float*)d_in[11];
    const float* regw  = (const float*)d_in[12];
    const float* regb  = (const float*)d_in[13];
    float* out = (float*)d_out;

    float* ws   = (float*)d_ws;
    float* H    = ws;                          // 8192*272 ; Q overlays (dead between gemm_in and next ln)
    float* XZ   = H    + (size_t)MTOK*DM;      // 8192*1088 (dead after conv; DELt overlays)
    float* XCt  = XZ   + (size_t)MTOK*2*DI;    // [BB][DI][LL] u; y overlays after scan
    float* Gt   = XCt  + (size_t)MTOK*DI;      // [BB][DI][LL]
    float* DBLb = Gt   + (size_t)MTOK*DI;      // 8192*145
    float* Xb   = DBLb + (size_t)MTOK*145;     // 8192*272 residual stream
    float* Sbuf = Xb   + (size_t)MTOK*DM;      // BB*DI*CH floats
    float* DELt = XZ;                          // overlays dead XZ
    float* Q    = H;                           // BB*DI*CH*64 = 557056 floats << MTOK*DM

    (void)hipMemcpyAsync(Xb, x_in, sizeof(float)*(size_t)MTOK*DM, hipMemcpyDeviceToDevice, stream);

    for (int l=0; l<NL; ++l){
        ln_kernel<<<MTOK/4, 256, 0, stream>>>(Xb, ln_w + l*DM, ln_b + l*DM, H);
        gemm_tn<false><<<dim3(MTOK/64, (2*DI+63)/64), 256, 0, stream>>>(
            H, DM, Wi + (size_t)l*2*DI*DM, XZ, 2*DI, nullptr, 0, 2*DI, DM);
        conv_t2_kernel<<<BB*256, 256, 0, stream>>>(XZ, cw + l*DI*4, cb + l*DI, XCt, Gt);
        gemm_nt<false><<<dim3(MTOK/64, (145+63)/64), 256, 0, stream>>>(
            XCt, Wx + (size_t)l*145*DI, DBLb, 145, nullptr, 0, 145, DI);
        dt_t2_kernel<<<BB*256, 256, 0, stream>>>(DBLb, Wdt + (size_t)l*DI*DTR, bdt + l*DI, DELt);
        scan_a<<<(BB*CH*(DI/2))/4, 256, 0, stream>>>(DELt, XCt, DBLb,
                                                     A_log + (size_t)l*DI*DS, Q, Sbuf);
        scan_b<<<BB*(DI/4), 256, 0, stream>>>(Q, Sbuf, A_log + (size_t)l*DI*DS);
        scan_c<<<(BB*CH*(DI/2))/4, 256, 0, stream>>>(DELt, XCt, Gt, DBLb,
                                                     A_log + (size_t)l*DI*DS, Dd + l*DI, Q);
        gemm_nt<true><<<dim3(MTOK/64, (DM+63)/64), 256, 0, stream>>>(
            XCt, Wo + (size_t)l*DM*DI, Xb, DM, Xb, DM, DM, DI);
    }
    head_kernel<<<BB, 256, 0, stream>>>(Xb, regw, regb, out);
}

// Round 7
// 2886.879 us; speedup vs baseline: 2.0069x; 1.0436x over previous
//
#include <hip/hip_runtime.h>
#include <hip/hip_bf16.h>
#include <math.h>

#define NL 6
#define DM 272
#define DS 64
#define DI 544
#define DTR 17
#define NSC 4
#define BB 4
#define LL 2048
#define MTOK (BB*LL)
#define TCH 256
#define CH  8

__device__ __forceinline__ float sigmoidf_(float x){ return 1.0f/(1.0f+__expf(-x)); }
__device__ __forceinline__ float rlf(float x, int s){ return __int_as_float(__builtin_amdgcn_readlane(__float_as_int(x), s)); }

#define DPPADD(x, ctrl) x += __int_as_float(__builtin_amdgcn_update_dpp(0, __float_as_int(x), ctrl, 0xf, 0xf, true))
// full-wave64 sum; result valid in lane 63
__device__ __forceinline__ float wsum64(float x){
    DPPADD(x, 0x111); DPPADD(x, 0x112); DPPADD(x, 0x114); DPPADD(x, 0x118);
    DPPADD(x, 0x142); DPPADD(x, 0x143);
    return x;
}

// ---------------- LayerNorm: one wave per token ----------------
__global__ __launch_bounds__(256) void ln_kernel(const float* __restrict__ X,
                          const float* __restrict__ w,
                          const float* __restrict__ b,
                          float* __restrict__ H)
{
    int wave = threadIdx.x >> 6;
    int lane = threadIdx.x & 63;
    int tok = blockIdx.x*4 + wave;
    const float* xr = X + (size_t)tok*DM;
    float v[5];
    float s=0.f, ss=0.f;
    #pragma unroll
    for (int j=0;j<5;++j){
        int idx = lane + j*64;
        float x = (idx < DM) ? xr[idx] : 0.f;
        v[j]=x; s+=x; ss+=x*x;
    }
    #pragma unroll
    for (int off=1; off<64; off<<=1){ s += __shfl_xor(s,off); ss += __shfl_xor(ss,off); }
    float mu  = s * (1.0f/DM);
    float var = ss*(1.0f/DM) - mu*mu;
    float inv = 1.0f/sqrtf(var + 1e-5f);
    float* hr = H + (size_t)tok*DM;
    #pragma unroll
    for (int j=0;j<5;++j){
        int idx = lane + j*64;
        if (idx<DM) hr[idx] = (v[j]-mu)*inv*w[idx] + b[idx];
    }
}

// ======= f32 GEMM 128x128 tile, 8x8 micro-tile, A row-major =======
template<bool RESID>
__global__ __launch_bounds__(256) void g128_tn(const float* __restrict__ A, int lda,
                        const float* __restrict__ W,
                        float* __restrict__ C, int ldc,
                        const float* __restrict__ R, int ldr,
                        int N, int K)
{
    __shared__ float As[16][132];
    __shared__ float Bs[16][132];
    int bm = blockIdx.x*128, bn = blockIdx.y*128;
    int tid = threadIdx.x;
    int tm = tid >> 4, tn = tid & 15;
    int lrow = tid >> 2, lkq = (tid & 3)*4;
    float acc[8][8] = {};
    for (int k0=0; k0<K; k0+=16){
        #pragma unroll
        for (int it=0; it<2; ++it){
            int row = lrow + it*64;
            float4 va = *(const float4*)(A + (size_t)(bm+row)*lda + k0 + lkq);
            As[lkq+0][row]=va.x; As[lkq+1][row]=va.y; As[lkq+2][row]=va.z; As[lkq+3][row]=va.w;
            int wr = bn + row;
            float4 vb = make_float4(0.f,0.f,0.f,0.f);
            if (wr < N) vb = *(const float4*)(W + (size_t)wr*K + k0 + lkq);
            Bs[lkq+0][row]=vb.x; Bs[lkq+1][row]=vb.y; Bs[lkq+2][row]=vb.z; Bs[lkq+3][row]=vb.w;
        }
        __syncthreads();
        #pragma unroll
        for (int k=0;k<16;++k){
            float4 a0 = *(const float4*)&As[k][tm*8];
            float4 a1 = *(const float4*)&As[k][tm*8+4];
            float4 b0 = *(const float4*)&Bs[k][tn*8];
            float4 b1 = *(const float4*)&Bs[k][tn*8+4];
            float av[8]={a0.x,a0.y,a0.z,a0.w,a1.x,a1.y,a1.z,a1.w};
            float bv[8]={b0.x,b0.y,b0.z,b0.w,b1.x,b1.y,b1.z,b1.w};
            #pragma unroll
            for (int i=0;i<8;++i)
                #pragma unroll
                for (int j=0;j<8;++j)
                    acc[i][j] = fmaf(av[i], bv[j], acc[i][j]);
        }
        __syncthreads();
    }
    #pragma unroll
    for (int i=0;i<8;++i){
        int row = bm + tm*8 + i;
        #pragma unroll
        for (int jq=0;jq<2;++jq){
            int col = bn + tn*8 + jq*4;
            if (col + 4 <= N){
                float4 v = make_float4(acc[i][jq*4], acc[i][jq*4+1], acc[i][jq*4+2], acc[i][jq*4+3]);
                if (RESID){
                    float4 r = *(const float4*)(R + (size_t)row*ldr + col);
                    v.x+=r.x; v.y+=r.y; v.z+=r.z; v.w+=r.w;
                }
                *(float4*)(C + (size_t)row*ldc + col) = v;
            } else {
                #pragma unroll
                for (int j=0;j<4;++j){
                    int cc = col + j;
                    if (cc < N){
                        float v = acc[i][jq*4+j];
                        if (RESID) v += R[(size_t)row*ldr + cc];
                        C[(size_t)row*ldc + cc] = v;
                    }
                }
            }
        }
    }
}

// ======= f32 GEMM 128x128, A K-major ([BB][K][LL]); M-tiles never cross b =======
template<bool RESID>
__global__ __launch_bounds__(256) void g128_nt(const float* __restrict__ At,
                        const float* __restrict__ W,
                        float* __restrict__ C, int ldc,
                        const float* __restrict__ R, int ldr,
                        int N, int K)
{
    __shared__ float As[16][132];
    __shared__ float Bs[16][132];
    int bm = blockIdx.x*128, bn = blockIdx.y*128;
    int b  = bm >> 11;
    int t0 = bm & (LL-1);
    int tid = threadIdx.x;
    int tm = tid >> 4, tn = tid & 15;
    int lrow = tid >> 2, lkq = (tid & 3)*4;
    int kk = tid >> 4, tq = (tid & 15)*4;
    float acc[8][8] = {};
    for (int k0=0; k0<K; k0+=16){
        #pragma unroll
        for (int it=0; it<2; ++it){
            float4 va = *(const float4*)(At + ((size_t)b*K + k0 + kk)*LL + t0 + tq + it*64);
            *(float4*)&As[kk][tq + it*64] = va;
            int row = lrow + it*64;
            int wr = bn + row;
            float4 vb = make_float4(0.f,0.f,0.f,0.f);
            if (wr < N) vb = *(const float4*)(W + (size_t)wr*K + k0 + lkq);
            Bs[lkq+0][row]=vb.x; Bs[lkq+1][row]=vb.y; Bs[lkq+2][row]=vb.z; Bs[lkq+3][row]=vb.w;
        }
        __syncthreads();
        #pragma unroll
        for (int k=0;k<16;++k){
            float4 a0 = *(const float4*)&As[k][tm*8];
            float4 a1 = *(const float4*)&As[k][tm*8+4];
            float4 b0 = *(const float4*)&Bs[k][tn*8];
            float4 b1 = *(const float4*)&Bs[k][tn*8+4];
            float av[8]={a0.x,a0.y,a0.z,a0.w,a1.x,a1.y,a1.z,a1.w};
            float bv[8]={b0.x,b0.y,b0.z,b0.w,b1.x,b1.y,b1.z,b1.w};
            #pragma unroll
            for (int i=0;i<8;++i)
                #pragma unroll
                for (int j=0;j<8;++j)
                    acc[i][j] = fmaf(av[i], bv[j], acc[i][j]);
        }
        __syncthreads();
    }
    #pragma unroll
    for (int i=0;i<8;++i){
        int row = bm + tm*8 + i;
        #pragma unroll
        for (int jq=0;jq<2;++jq){
            int col = bn + tn*8 + jq*4;
            if (col + 4 <= N){
                float4 v = make_float4(acc[i][jq*4], acc[i][jq*4+1], acc[i][jq*4+2], acc[i][jq*4+3]);
                if (RESID){
                    float4 r = *(const float4*)(R + (size_t)row*ldr + col);
                    v.x+=r.x; v.y+=r.y; v.z+=r.z; v.w+=r.w;
                }
                *(float4*)(C + (size_t)row*ldc + col) = v;
            } else {
                #pragma unroll
                for (int j=0;j<4;++j){
                    int cc = col + j;
                    if (cc < N){
                        float v = acc[i][jq*4+j];
                        if (RESID) v += R[(size_t)row*ldr + cc];
                        C[(size_t)row*ldc + cc] = v;
                    }
                }
            }
        }
    }
}

// ------- conv+SiLU+gate with LDS transpose: coalesced in (over d) and out (over t) -------
__global__ __launch_bounds__(256) void conv_t2_kernel(const float* __restrict__ XZ,
                                 const float* __restrict__ cw,
                                 const float* __restrict__ cb,
                                 float* __restrict__ XCt,
                                 float* __restrict__ Gt)
{
    __shared__ float xi[67][69];
    __shared__ float zz[64][69];
    int bid = blockIdx.x;
    int b  = bid >> 8;
    int rem = bid & 255;
    int t0 = (rem >> 3)*64;
    int d0 = (rem & 7)*68;
    int tid = threadIdx.x;
    for (int li = tid; li < 67*17; li += 256){
        int row = li / 17, q = li - row*17;
        int tg = t0 - 3 + row;
        float4 v = make_float4(0.f,0.f,0.f,0.f);
        if (tg >= 0)
            v = *(const float4*)(XZ + ((size_t)b*LL + tg)*(2*DI) + d0 + q*4);
        xi[row][q*4+0]=v.x; xi[row][q*4+1]=v.y; xi[row][q*4+2]=v.z; xi[row][q*4+3]=v.w;
    }
    for (int li = tid; li < 64*17; li += 256){
        int row = li / 17, q = li - row*17;
        float4 v = *(const float4*)(XZ + ((size_t)b*LL + t0 + row)*(2*DI) + DI + d0 + q*4);
        zz[row][q*4+0]=v.x; zz[row][q*4+1]=v.y; zz[row][q*4+2]=v.z; zz[row][q*4+3]=v.w;
    }
    __syncthreads();
    int t = tid & 63;
    #pragma unroll 1
    for (int dl = tid >> 6; dl < 68; dl += 4){
        int d = d0 + dl;
        const float* cwd = cw + d*4;
        float acc = cb[d];
        #pragma unroll
        for (int k=0;k<4;++k) acc = fmaf(xi[t+k][dl], cwd[k], acc);
        float xc = acc * sigmoidf_(acc);
        float z  = zz[t][dl];
        size_t o = ((size_t)b*DI + d)*LL + t0 + t;
        XCt[o] = xc;
        Gt[o]  = z * sigmoidf_(z);
    }
}

// ------- dt_proj (K=17) + softplus, LDS-staged, coalesced output over t -------
__global__ __launch_bounds__(256) void dt_t2_kernel(const float* __restrict__ DBLb,
                          const float* __restrict__ Wdt,
                          const float* __restrict__ bdt,
                          float* __restrict__ DELt)
{
    __shared__ float dtv[64*19];
    __shared__ float wl[68*17];
    int bid = blockIdx.x;
    int b  = bid >> 8;
    int rem = bid & 255;
    int t0 = (rem >> 3)*64;
    int d0 = (rem & 7)*68;
    int tid = threadIdx.x;
    for (int li = tid; li < 64*17; li += 256){
        int row = li / 17, col = li - row*17;
        dtv[row*19 + col] = DBLb[((size_t)b*LL + t0 + row)*145 + col];
    }
    for (int li = tid; li < 68*17; li += 256)
        wl[li] = Wdt[(size_t)d0*17 + li];
    __syncthreads();
    int t = tid & 63;
    #pragma unroll 1
    for (int dl = tid >> 6; dl < 68; dl += 4){
        float s = bdt[d0 + dl];
        #pragma unroll
        for (int r=0;r<DTR;++r) s = fmaf(dtv[t*19 + r], wl[dl*17 + r], s);
        float sp = (s > 20.f) ? s : log1pf(__expf(s));
        DELt[((size_t)b*DI + d0 + dl)*LL + t0 + t] = sp;
    }
}

// ======= chunked scan, pass A: local scan from h=0, emit h_out + sum(delta) =======
#define EBATCH(i) float e0##i = __expf(rlf(dl0, base+i)*Av0); float e1##i = __expf(rlf(dl1, base+i)*Av1);
#define STEPA(i) { float Bv = p[17+lane]; \
    h0 = fmaf(e0##i, h0, rlf(du0, base+i)*Bv); \
    h1 = fmaf(e1##i, h1, rlf(du1, base+i)*Bv); \
    p += 145; }

__global__ __launch_bounds__(256) void scan_a(const float* __restrict__ DELt,
                       const float* __restrict__ XCt,
                       const float* __restrict__ DBLb,
                       const float* __restrict__ A_log,
                       float* __restrict__ Q,
                       float* __restrict__ S)
{
    int wave = threadIdx.x >> 6, lane = threadIdx.x & 63;
    int wid = blockIdx.x*4 + wave;            // (b, c, dd) dd fastest
    int dd = wid % (DI/2);
    int c  = (wid / (DI/2)) % CH;
    int b  = wid / ((DI/2)*CH);
    int d0 = dd, d1 = dd + DI/2;
    float Av0 = -__expf(A_log[d0*DS + lane]);
    float Av1 = -__expf(A_log[d1*DS + lane]);
    float h0 = 0.f, h1 = 0.f, ds0 = 0.f, ds1 = 0.f;
    size_t rb0 = ((size_t)b*DI + d0)*LL + c*TCH;
    size_t rb1 = ((size_t)b*DI + d1)*LL + c*TCH;
    const float* pB = DBLb + ((size_t)b*LL + c*TCH)*145;
    for (int blk=0; blk<TCH/64; ++blk){
        size_t o0 = rb0 + blk*64 + lane;
        size_t o1 = rb1 + blk*64 + lane;
        float dl0 = DELt[o0], dl1 = DELt[o1];
        float ul0 = XCt[o0],  ul1 = XCt[o1];
        float du0 = dl0*ul0,  du1 = dl1*ul1;
        ds0 += dl0; ds1 += dl1;
        const float* p = pB + (size_t)blk*64*145;
        #pragma unroll 1
        for (int sub=0; sub<8; ++sub){
            int base = sub*8;
            EBATCH(0) EBATCH(1) EBATCH(2) EBATCH(3)
            EBATCH(4) EBATCH(5) EBATCH(6) EBATCH(7)
            STEPA(0) STEPA(1) STEPA(2) STEPA(3)
            STEPA(4) STEPA(5) STEPA(6) STEPA(7)
        }
    }
    size_t q0 = ((size_t)b*DI + d0)*CH + c;
    size_t q1 = ((size_t)b*DI + d1)*CH + c;
    Q[q0*64 + lane] = h0;
    Q[q1*64 + lane] = h1;
    float s0 = wsum64(ds0);
    float s1 = wsum64(ds1);
    if (lane == 63){ S[q0] = s0; S[q1] = s1; }
}

// ======= chunked scan, pass B: sequential chunk combine, h_in written into Q =======
__global__ __launch_bounds__(256) void scan_b(float* __restrict__ Q,
                       const float* __restrict__ S,
                       const float* __restrict__ A_log)
{
    int tid = threadIdx.x;
    int n = tid & 63;
    int dq = tid >> 6;
    int b = blockIdx.x / (DI/4);
    int d = (blockIdx.x % (DI/4))*4 + dq;
    float Aval = -__expf(A_log[d*DS + n]);
    float h = 0.f;
    size_t base = ((size_t)b*DI + d)*CH;
    for (int c=0; c<CH; ++c){
        size_t idx = base + c;
        float q  = Q[idx*64 + n];
        float Sv = S[idx];
        Q[idx*64 + n] = h;
        h = fmaf(__expf(Aval*Sv), h, q);
    }
}

// ======= chunked scan, pass C: re-scan from h_in, LDS-transpose y-reduction =======
// per step: write h*C into wave-private LDS; flush every 8 steps:
// per-lane 8-sum + 3-DPP 8-group combine + 1 bpermute to park y at lane==t.
#define CSTEP(i) { float Bv = p[17+lane]; float Cv = p[81+lane]; \
    h0 = fmaf(e0##i, h0, rlf(du0, base+i)*Bv); \
    h1 = fmaf(e1##i, h1, rlf(du1, base+i)*Bv); \
    P0[i][lane] = h0*Cv; \
    P1[i][lane] = h1*Cv; \
    p += 145; }

__global__ __launch_bounds__(256) void scan_c(const float* __restrict__ DELt,
                       float* __restrict__ XCt,           // in: u ; out: y (overlay)
                       const float* __restrict__ Gt,
                       const float* __restrict__ DBLb,
                       const float* __restrict__ A_log,
                       const float* __restrict__ Dskip,
                       const float* __restrict__ Q)
{
    __shared__ float P[4][2][8][76];
    int wave = threadIdx.x >> 6, lane = threadIdx.x & 63;
    float (*P0)[76] = P[wave][0];
    float (*P1)[76] = P[wave][1];
    int wid = blockIdx.x*4 + wave;
    int dd = wid % (DI/2);
    int c  = (wid / (DI/2)) % CH;
    int b  = wid / ((DI/2)*CH);
    int d0 = dd, d1 = dd + DI/2;
    float Av0 = -__expf(A_log[d0*DS + lane]);
    float Av1 = -__expf(A_log[d1*DS + lane]);
    float Dd0 = Dskip[d0], Dd1 = Dskip[d1];
    size_t q0 = ((size_t)b*DI + d0)*CH + c;
    size_t q1 = ((size_t)b*DI + d1)*CH + c;
    float h0 = Q[q0*64 + lane];
    float h1 = Q[q1*64 + lane];
    size_t rb0 = ((size_t)b*DI + d0)*LL + c*TCH;
    size_t rb1 = ((size_t)b*DI + d1)*LL + c*TCH;
    const float* pB = DBLb + ((size_t)b*LL + c*TCH)*145;
    int fr = lane >> 3, fq = lane & 7;
    int bidx = ((lane & 7)*8 + 7)*4;
    for (int blk=0; blk<TCH/64; ++blk){
        size_t o0 = rb0 + blk*64 + lane;
        size_t o1 = rb1 + blk*64 + lane;
        float dl0 = DELt[o0], dl1 = DELt[o1];
        float ul0 = XCt[o0],  ul1 = XCt[o1];
        float gl0 = Gt[o0],   gl1 = Gt[o1];
        float du0 = dl0*ul0,  du1 = dl1*ul1;
        float y0 = 0.f, y1 = 0.f;
        const float* p = pB + (size_t)blk*64*145;
        #pragma unroll 1
        for (int f=0; f<8; ++f){
            int base = f*8;
            EBATCH(0) EBATCH(1) EBATCH(2) EBATCH(3)
            EBATCH(4) EBATCH(5) EBATCH(6) EBATCH(7)
            CSTEP(0) CSTEP(1) CSTEP(2) CSTEP(3)
            CSTEP(4) CSTEP(5) CSTEP(6) CSTEP(7)
            float4 xa = *(const float4*)&P0[fr][fq*8];
            float4 xb = *(const float4*)&P0[fr][fq*8+4];
            float s0 = ((xa.x+xa.y)+(xa.z+xa.w)) + ((xb.x+xb.y)+(xb.z+xb.w));
            float4 ya = *(const float4*)&P1[fr][fq*8];
            float4 yb = *(const float4*)&P1[fr][fq*8+4];
            float s1 = ((ya.x+ya.y)+(ya.z+ya.w)) + ((yb.x+yb.y)+(yb.z+yb.w));
            DPPADD(s0,0x111); DPPADD(s0,0x112); DPPADD(s0,0x114);
            DPPADD(s1,0x111); DPPADD(s1,0x112); DPPADD(s1,0x114);
            float g0 = __int_as_float(__builtin_amdgcn_ds_bpermute(bidx, __float_as_int(s0)));
            float g1 = __int_as_float(__builtin_amdgcn_ds_bpermute(bidx, __float_as_int(s1)));
            if ((lane >> 3) == f){ y0 = g0; y1 = g1; }
        }
        XCt[o0] = (y0 + ul0*Dd0)*gl0;
        XCt[o1] = (y1 + ul1*Dd1)*gl1;
    }
}

// ---------------- mean-pool + regression head ----------------
__global__ __launch_bounds__(256) void head_kernel(const float* __restrict__ X,
                            const float* __restrict__ reg_w,
                            const float* __restrict__ reg_b,
                            float* __restrict__ out)
{
    __shared__ float feat[DM];
    int b = blockIdx.x, tid = threadIdx.x;
    for (int dm = tid; dm < DM; dm += 256){
        float s = 0.f;
        const float* base = X + ((size_t)b*LL)*DM + dm;
        #pragma unroll 8
        for (int l=0;l<LL;++l) s += base[(size_t)l*DM];
        float f = s * (1.0f/LL);
        feat[dm] = f;
        out[16 + b*DM + dm] = f;
    }
    __syncthreads();
    if (tid < NSC){
        float s = reg_b[tid];
        const float* wr = reg_w + tid*DM;
        for (int k=0;k<DM;++k) s = fmaf(feat[k], wr[k], s);
        out[b*NSC + tid] = s;
    }
}

extern "C" void kernel_launch(void* const* d_in, const int* in_sizes, int n_in,
                              void* d_out, int out_size, void* d_ws, size_t ws_size,
                              hipStream_t stream)
{
    const float* x_in  = (const float*)d_in[0];
    const float* ln_w  = (const float*)d_in[1];
    const float* ln_b  = (const float*)d_in[2];
    const float* Wi    = (const float*)d_in[3];
    const float* cw    = (const float*)d_in[4];
    const float* cb    = (const float*)d_in[5];
    const float* Wx    = (const float*)d_in[6];
    const float* Wdt   = (const float*)d_in[7];
    const float* bdt   = (const float*)d_in[8];
    const float* A_log = (const float*)d_in[9];
    const float* Dd    = (const float*)d_in[10];
    const float* Wo    = (const float*)d_in[11];
    const float* regw  = (const float*)d_in[12];
    const float* regb  = (const float*)d_in[13];
    float* out = (float*)d_out;

    float* ws   = (float*)d_ws;
    float* H    = ws;                          // 8192*272 ; Q overlays
    float* XZ   = H    + (size_t)MTOK*DM;      // 8192*1088 (dead after conv; DELt overlays)
    float* XCt  = XZ   + (size_t)MTOK*2*DI;    // [BB][DI][LL] u; y overlays after scan
    float* Gt   = XCt  + (size_t)MTOK*DI;      // [BB][DI][LL]
    float* DBLb = Gt   + (size_t)MTOK*DI;      // 8192*145
    float* Xb   = DBLb + (size_t)MTOK*145;     // 8192*272 residual stream
    float* Sbuf = Xb   + (size_t)MTOK*DM;      // BB*DI*CH floats
    float* DELt = XZ;                          // overlays dead XZ
    float* Q    = H;                           // BB*DI*CH*64 floats << MTOK*DM

    (void)hipMemcpyAsync(Xb, x_in, sizeof(float)*(size_t)MTOK*DM, hipMemcpyDeviceToDevice, stream);

    for (int l=0; l<NL; ++l){
        ln_kernel<<<MTOK/4, 256, 0, stream>>>(Xb, ln_w + l*DM, ln_b + l*DM, H);
        g128_tn<false><<<dim3(MTOK/128, (2*DI+127)/128), 256, 0, stream>>>(
            H, DM, Wi + (size_t)l*2*DI*DM, XZ, 2*DI, nullptr, 0, 2*DI, DM);
        conv_t2_kernel<<<BB*256, 256, 0, stream>>>(XZ, cw + l*DI*4, cb + l*DI, XCt, Gt);
        g128_nt<false><<<dim3(MTOK/128, (145+127)/128), 256, 0, stream>>>(
            XCt, Wx + (size_t)l*145*DI, DBLb, 145, nullptr, 0, 145, DI);
        dt_t2_kernel<<<BB*256, 256, 0, stream>>>(DBLb, Wdt + (size_t)l*DI*DTR, bdt + l*DI, DELt);
        scan_a<<<(BB*CH*(DI/2))/4, 256, 0, stream>>>(DELt, XCt, DBLb,
                                                     A_log + (size_t)l*DI*DS, Q, Sbuf);
        scan_b<<<BB*(DI/4), 256, 0, stream>>>(Q, Sbuf, A_log + (size_t)l*DI*DS);
        scan_c<<<(BB*CH*(DI/2))/4, 256, 0, stream>>>(DELt, XCt, Gt, DBLb,
                                                     A_log + (size_t)l*DI*DS, Dd + l*DI, Q);
        g128_nt<true><<<dim3(MTOK/128, (DM+127)/128), 256, 0, stream>>>(
            XCt, Wo + (size_t)l*DM*DI, Xb, DM, Xb, DM, DM, DI);
    }
    head_kernel<<<BB, 256, 0, stream>>>(Xb, regw, regb, out);
}

// Round 8
// 1868.442 us; speedup vs baseline: 3.1009x; 1.5451x over previous
//
#include <hip/hip_runtime.h>
#include <hip/hip_bf16.h>
#include <math.h>

#define NL 6
#define DM 272
#define DS 64
#define DI 544
#define DTR 17
#define NSC 4
#define BB 4
#define LL 2048
#define MTOK (BB*LL)
#define TCH 256
#define CH  8

typedef __attribute__((ext_vector_type(8))) short bf16x8;
typedef __attribute__((ext_vector_type(4))) float f32x4;

__device__ __forceinline__ float sigmoidf_(float x){ return 1.0f/(1.0f+__expf(-x)); }
__device__ __forceinline__ float rlf(float x, int s){ return __int_as_float(__builtin_amdgcn_readlane(__float_as_int(x), s)); }
__device__ __forceinline__ unsigned short f2bfu(float x){
    union { __hip_bfloat16 h; unsigned short u; } c; c.h = __float2bfloat16(x); return c.u;
}

#define DPPADD(x, ctrl) x += __int_as_float(__builtin_amdgcn_update_dpp(0, __float_as_int(x), ctrl, 0xf, 0xf, true))
__device__ __forceinline__ float wsum64(float x){
    DPPADD(x, 0x111); DPPADD(x, 0x112); DPPADD(x, 0x114); DPPADD(x, 0x118);
    DPPADD(x, 0x142); DPPADD(x, 0x143);
    return x;
}

// ---------------- LayerNorm: one wave per token, bf16 output ----------------
__global__ __launch_bounds__(256) void ln_kernel(const float* __restrict__ X,
                          const float* __restrict__ w,
                          const float* __restrict__ b,
                          unsigned short* __restrict__ Hb)
{
    int wave = threadIdx.x >> 6;
    int lane = threadIdx.x & 63;
    int tok = blockIdx.x*4 + wave;
    const float* xr = X + (size_t)tok*DM;
    float v[5];
    float s=0.f, ss=0.f;
    #pragma unroll
    for (int j=0;j<5;++j){
        int idx = lane + j*64;
        float x = (idx < DM) ? xr[idx] : 0.f;
        v[j]=x; s+=x; ss+=x*x;
    }
    #pragma unroll
    for (int off=1; off<64; off<<=1){ s += __shfl_xor(s,off); ss += __shfl_xor(ss,off); }
    float mu  = s * (1.0f/DM);
    float var = ss*(1.0f/DM) - mu*mu;
    float inv = 1.0f/sqrtf(var + 1e-5f);
    unsigned short* hr = Hb + (size_t)tok*DM;
    #pragma unroll
    for (int j=0;j<5;++j){
        int idx = lane + j*64;
        if (idx<DM) hr[idx] = f2bfu((v[j]-mu)*inv*w[idx] + b[idx]);
    }
}

// ======= bf16 MFMA GEMM: C[M,N] = A[M,K]bf16 @ W[N,K]bf16^T (+f32 residual) =======
// 128x128 tile, 4 waves, each wave 64x64 via 4x4 mfma_f32_16x16x32_bf16 frags.
// K need not be mult of 32 (must be mult of 8): staging zero-fills OOB chunks.
template<bool RESID>
__global__ __launch_bounds__(256) void gmfma(const unsigned short* __restrict__ A, int lda,
                     const unsigned short* __restrict__ W, int ldw,
                     float* __restrict__ C, int ldc,
                     const float* __restrict__ R, int ldr,
                     int N, int K)
{
    __shared__ unsigned short As[128*40];
    __shared__ unsigned short Bs[128*40];
    int bm = blockIdx.x*128, bn = blockIdx.y*128;
    int tid = threadIdx.x;
    int lane = tid & 63, wave = tid >> 6;
    int wm = wave >> 1, wn = wave & 1;
    f32x4 acc[4][4] = {};
    int r16 = lane & 15, kg = (lane >> 4) * 8;
    for (int k0=0; k0<K; k0+=32){
        #pragma unroll
        for (int it=0; it<2; ++it){
            int cid = tid + it*256;
            int row = cid >> 2, kq = (cid & 3)*8;
            int kk = k0 + kq;
            uint4 za = make_uint4(0,0,0,0);
            if (kk < K) za = *(const uint4*)(A + (size_t)(bm+row)*lda + kk);
            *(uint4*)&As[row*40 + kq] = za;
            uint4 zb = make_uint4(0,0,0,0);
            int wr = bn + row;
            if (wr < N && kk < K) zb = *(const uint4*)(W + (size_t)wr*ldw + kk);
            *(uint4*)&Bs[row*40 + kq] = zb;
        }
        __syncthreads();
        bf16x8 af[4], bfr[4];
        #pragma unroll
        for (int mi=0; mi<4; ++mi)
            af[mi] = *(bf16x8*)&As[(wm*64 + mi*16 + r16)*40 + kg];
        #pragma unroll
        for (int ni=0; ni<4; ++ni)
            bfr[ni] = *(bf16x8*)&Bs[(wn*64 + ni*16 + r16)*40 + kg];
        #pragma unroll
        for (int mi=0; mi<4; ++mi)
            #pragma unroll
            for (int ni=0; ni<4; ++ni)
                acc[mi][ni] = __builtin_amdgcn_mfma_f32_16x16x32_bf16(af[mi], bfr[ni], acc[mi][ni], 0, 0, 0);
        __syncthreads();
    }
    int rowt = (lane >> 4)*4, colt = lane & 15;
    #pragma unroll
    for (int mi=0; mi<4; ++mi){
        #pragma unroll
        for (int ni=0; ni<4; ++ni){
            int col = bn + wn*64 + ni*16 + colt;
            if (col < N){
                #pragma unroll
                for (int j=0; j<4; ++j){
                    int row = bm + wm*64 + mi*16 + rowt + j;
                    float v = acc[mi][ni][j];
                    if (RESID) v += R[(size_t)row*ldr + col];
                    C[(size_t)row*ldc + col] = v;
                }
            }
        }
    }
}

// ------- conv+SiLU+gate, LDS transpose; outputs XCt/Gt f32 [d][t] + XCb bf16 [tok][d] -------
__global__ __launch_bounds__(256) void conv_t2_kernel(const float* __restrict__ XZ,
                                 const float* __restrict__ cw,
                                 const float* __restrict__ cb,
                                 float* __restrict__ XCt,
                                 float* __restrict__ Gt,
                                 unsigned short* __restrict__ XCb)
{
    __shared__ float xi[67][69];
    __shared__ float zz[64][69];
    int bid = blockIdx.x;
    int b  = bid >> 8;
    int rem = bid & 255;
    int t0 = (rem >> 3)*64;
    int d0 = (rem & 7)*68;
    int tid = threadIdx.x;
    for (int li = tid; li < 67*17; li += 256){
        int row = li / 17, q = li - row*17;
        int tg = t0 - 3 + row;
        float4 v = make_float4(0.f,0.f,0.f,0.f);
        if (tg >= 0)
            v = *(const float4*)(XZ + ((size_t)b*LL + tg)*(2*DI) + d0 + q*4);
        xi[row][q*4+0]=v.x; xi[row][q*4+1]=v.y; xi[row][q*4+2]=v.z; xi[row][q*4+3]=v.w;
    }
    for (int li = tid; li < 64*17; li += 256){
        int row = li / 17, q = li - row*17;
        float4 v = *(const float4*)(XZ + ((size_t)b*LL + t0 + row)*(2*DI) + DI + d0 + q*4);
        zz[row][q*4+0]=v.x; zz[row][q*4+1]=v.y; zz[row][q*4+2]=v.z; zz[row][q*4+3]=v.w;
    }
    __syncthreads();
    int t = tid & 63;
    int dw = tid >> 6;
    float xcreg[17];
    #pragma unroll
    for (int i=0; i<17; ++i){
        int dl = dw + i*4;
        int d = d0 + dl;
        const float* cwd = cw + d*4;
        float acc = cb[d];
        #pragma unroll
        for (int k=0;k<4;++k) acc = fmaf(xi[t+k][dl], cwd[k], acc);
        float xc = acc * sigmoidf_(acc);
        float z  = zz[t][dl];
        size_t o = ((size_t)b*DI + d)*LL + t0 + t;
        XCt[o] = xc;
        Gt[o]  = z * sigmoidf_(z);
        xcreg[i] = xc;
    }
    __syncthreads();   // all zz reads done
    #pragma unroll
    for (int i=0; i<17; ++i) zz[t][dw + i*4] = xcreg[i];
    __syncthreads();
    for (int li = tid; li < 64*17; li += 256){
        int row = li / 17, q = li - row*17;
        ushort4 v;
        v.x = f2bfu(zz[row][q*4+0]); v.y = f2bfu(zz[row][q*4+1]);
        v.z = f2bfu(zz[row][q*4+2]); v.w = f2bfu(zz[row][q*4+3]);
        *(ushort4*)&XCb[((size_t)b*LL + t0 + row)*DI + d0 + q*4] = v;
    }
}

// ------- dt_proj (K=17) + softplus, LDS-staged, coalesced output over t -------
__global__ __launch_bounds__(256) void dt_t2_kernel(const float* __restrict__ DBLb,
                          const float* __restrict__ Wdt,
                          const float* __restrict__ bdt,
                          float* __restrict__ DELt)
{
    __shared__ float dtv[64*19];
    __shared__ float wl[68*17];
    int bid = blockIdx.x;
    int b  = bid >> 8;
    int rem = bid & 255;
    int t0 = (rem >> 3)*64;
    int d0 = (rem & 7)*68;
    int tid = threadIdx.x;
    for (int li = tid; li < 64*17; li += 256){
        int row = li / 17, col = li - row*17;
        dtv[row*19 + col] = DBLb[((size_t)b*LL + t0 + row)*145 + col];
    }
    for (int li = tid; li < 68*17; li += 256)
        wl[li] = Wdt[(size_t)d0*17 + li];
    __syncthreads();
    int t = tid & 63;
    #pragma unroll 1
    for (int dl = tid >> 6; dl < 68; dl += 4){
        float s = bdt[d0 + dl];
        #pragma unroll
        for (int r=0;r<DTR;++r) s = fmaf(dtv[t*19 + r], wl[dl*17 + r], s);
        float sp = (s > 20.f) ? s : log1pf(__expf(s));
        DELt[((size_t)b*DI + d0 + dl)*LL + t0 + t] = sp;
    }
}

// ======= chunked scan, pass A =======
#define EBATCH(i) float e0##i = __expf(rlf(dl0, base+i)*Av0); float e1##i = __expf(rlf(dl1, base+i)*Av1);
#define STEPA(i) { float Bv = p[17+lane]; \
    h0 = fmaf(e0##i, h0, rlf(du0, base+i)*Bv); \
    h1 = fmaf(e1##i, h1, rlf(du1, base+i)*Bv); \
    p += 145; }

__global__ __launch_bounds__(256) void scan_a(const float* __restrict__ DELt,
                       const float* __restrict__ XCt,
                       const float* __restrict__ DBLb,
                       const float* __restrict__ A_log,
                       float* __restrict__ Q,
                       float* __restrict__ S)
{
    int wave = threadIdx.x >> 6, lane = threadIdx.x & 63;
    int wid = blockIdx.x*4 + wave;
    int dd = wid % (DI/2);
    int c  = (wid / (DI/2)) % CH;
    int b  = wid / ((DI/2)*CH);
    int d0 = dd, d1 = dd + DI/2;
    float Av0 = -__expf(A_log[d0*DS + lane]);
    float Av1 = -__expf(A_log[d1*DS + lane]);
    float h0 = 0.f, h1 = 0.f, ds0 = 0.f, ds1 = 0.f;
    size_t rb0 = ((size_t)b*DI + d0)*LL + c*TCH;
    size_t rb1 = ((size_t)b*DI + d1)*LL + c*TCH;
    const float* pB = DBLb + ((size_t)b*LL + c*TCH)*145;
    for (int blk=0; blk<TCH/64; ++blk){
        size_t o0 = rb0 + blk*64 + lane;
        size_t o1 = rb1 + blk*64 + lane;
        float dl0 = DELt[o0], dl1 = DELt[o1];
        float ul0 = XCt[o0],  ul1 = XCt[o1];
        float du0 = dl0*ul0,  du1 = dl1*ul1;
        ds0 += dl0; ds1 += dl1;
        const float* p = pB + (size_t)blk*64*145;
        #pragma unroll 1
        for (int sub=0; sub<8; ++sub){
            int base = sub*8;
            EBATCH(0) EBATCH(1) EBATCH(2) EBATCH(3)
            EBATCH(4) EBATCH(5) EBATCH(6) EBATCH(7)
            STEPA(0) STEPA(1) STEPA(2) STEPA(3)
            STEPA(4) STEPA(5) STEPA(6) STEPA(7)
        }
    }
    size_t q0 = ((size_t)b*DI + d0)*CH + c;
    size_t q1 = ((size_t)b*DI + d1)*CH + c;
    Q[q0*64 + lane] = h0;
    Q[q1*64 + lane] = h1;
    float s0 = wsum64(ds0);
    float s1 = wsum64(ds1);
    if (lane == 63){ S[q0] = s0; S[q1] = s1; }
}

// ======= chunked scan, pass B =======
__global__ __launch_bounds__(256) void scan_b(float* __restrict__ Q,
                       const float* __restrict__ S,
                       const float* __restrict__ A_log)
{
    int tid = threadIdx.x;
    int n = tid & 63;
    int dq = tid >> 6;
    int b = blockIdx.x / (DI/4);
    int d = (blockIdx.x % (DI/4))*4 + dq;
    float Aval = -__expf(A_log[d*DS + n]);
    float h = 0.f;
    size_t base = ((size_t)b*DI + d)*CH;
    for (int c=0; c<CH; ++c){
        size_t idx = base + c;
        float q  = Q[idx*64 + n];
        float Sv = S[idx];
        Q[idx*64 + n] = h;
        h = fmaf(__expf(Aval*Sv), h, q);
    }
}

// ======= chunked scan, pass C: LDS-transpose y-reduction =======
#define CSTEP(i) { float Bv = p[17+lane]; float Cv = p[81+lane]; \
    h0 = fmaf(e0##i, h0, rlf(du0, base+i)*Bv); \
    h1 = fmaf(e1##i, h1, rlf(du1, base+i)*Bv); \
    P0[i][lane] = h0*Cv; \
    P1[i][lane] = h1*Cv; \
    p += 145; }

__global__ __launch_bounds__(256) void scan_c(const float* __restrict__ DELt,
                       float* __restrict__ XCt,
                       const float* __restrict__ Gt,
                       const float* __restrict__ DBLb,
                       const float* __restrict__ A_log,
                       const float* __restrict__ Dskip,
                       const float* __restrict__ Q)
{
    __shared__ float P[4][2][8][76];
    int wave = threadIdx.x >> 6, lane = threadIdx.x & 63;
    float (*P0)[76] = P[wave][0];
    float (*P1)[76] = P[wave][1];
    int wid = blockIdx.x*4 + wave;
    int dd = wid % (DI/2);
    int c  = (wid / (DI/2)) % CH;
    int b  = wid / ((DI/2)*CH);
    int d0 = dd, d1 = dd + DI/2;
    float Av0 = -__expf(A_log[d0*DS + lane]);
    float Av1 = -__expf(A_log[d1*DS + lane]);
    float Dd0 = Dskip[d0], Dd1 = Dskip[d1];
    size_t q0 = ((size_t)b*DI + d0)*CH + c;
    size_t q1 = ((size_t)b*DI + d1)*CH + c;
    float h0 = Q[q0*64 + lane];
    float h1 = Q[q1*64 + lane];
    size_t rb0 = ((size_t)b*DI + d0)*LL + c*TCH;
    size_t rb1 = ((size_t)b*DI + d1)*LL + c*TCH;
    const float* pB = DBLb + ((size_t)b*LL + c*TCH)*145;
    int fr = lane >> 3, fq = lane & 7;
    int bidx = ((lane & 7)*8 + 7)*4;
    for (int blk=0; blk<TCH/64; ++blk){
        size_t o0 = rb0 + blk*64 + lane;
        size_t o1 = rb1 + blk*64 + lane;
        float dl0 = DELt[o0], dl1 = DELt[o1];
        float ul0 = XCt[o0],  ul1 = XCt[o1];
        float gl0 = Gt[o0],   gl1 = Gt[o1];
        float du0 = dl0*ul0,  du1 = dl1*ul1;
        float y0 = 0.f, y1 = 0.f;
        const float* p = pB + (size_t)blk*64*145;
        #pragma unroll 1
        for (int f=0; f<8; ++f){
            int base = f*8;
            EBATCH(0) EBATCH(1) EBATCH(2) EBATCH(3)
            EBATCH(4) EBATCH(5) EBATCH(6) EBATCH(7)
            CSTEP(0) CSTEP(1) CSTEP(2) CSTEP(3)
            CSTEP(4) CSTEP(5) CSTEP(6) CSTEP(7)
            float4 xa = *(const float4*)&P0[fr][fq*8];
            float4 xb = *(const float4*)&P0[fr][fq*8+4];
            float s0 = ((xa.x+xa.y)+(xa.z+xa.w)) + ((xb.x+xb.y)+(xb.z+xb.w));
            float4 ya = *(const float4*)&P1[fr][fq*8];
            float4 yb = *(const float4*)&P1[fr][fq*8+4];
            float s1 = ((ya.x+ya.y)+(ya.z+ya.w)) + ((yb.x+yb.y)+(yb.z+yb.w));
            DPPADD(s0,0x111); DPPADD(s0,0x112); DPPADD(s0,0x114);
            DPPADD(s1,0x111); DPPADD(s1,0x112); DPPADD(s1,0x114);
            float g0 = __int_as_float(__builtin_amdgcn_ds_bpermute(bidx, __float_as_int(s0)));
            float g1 = __int_as_float(__builtin_amdgcn_ds_bpermute(bidx, __float_as_int(s1)));
            if ((lane >> 3) == f){ y0 = g0; y1 = g1; }
        }
        XCt[o0] = (y0 + ul0*Dd0)*gl0;
        XCt[o1] = (y1 + ul1*Dd1)*gl1;
    }
}

// ------- y transpose: XCt f32 [b][d][t] -> Yb bf16 [tok][DI] -------
__global__ __launch_bounds__(256) void yt2yb_kernel(const float* __restrict__ Yt,
                             unsigned short* __restrict__ Yb)
{
    __shared__ float yt[64][69];
    int bid = blockIdx.x;         // (b, dtile(8), ttile(32))
    int b = bid >> 8;
    int rem = bid & 255;
    int d0 = (rem >> 5)*68;
    int t0 = (rem & 31)*64;
    int tid = threadIdx.x;
    for (int li = tid; li < 68*16; li += 256){
        int dl = li >> 4, tq = (li & 15)*4;
        float4 v = *(const float4*)(Yt + ((size_t)b*DI + d0 + dl)*LL + t0 + tq);
        yt[tq+0][dl]=v.x; yt[tq+1][dl]=v.y; yt[tq+2][dl]=v.z; yt[tq+3][dl]=v.w;
    }
    __syncthreads();
    for (int li = tid; li < 64*17; li += 256){
        int row = li / 17, q = li - row*17;
        ushort4 v;
        v.x = f2bfu(yt[row][q*4+0]); v.y = f2bfu(yt[row][q*4+1]);
        v.z = f2bfu(yt[row][q*4+2]); v.w = f2bfu(yt[row][q*4+3]);
        *(ushort4*)&Yb[((size_t)b*LL + t0 + row)*DI + d0 + q*4] = v;
    }
}

// ------- weight f32 -> bf16 convert (optionally K-padded) -------
__global__ __launch_bounds__(256) void wconv_kernel(const float* __restrict__ src,
                            unsigned short* __restrict__ dst,
                            int total, int kin, int kout)
{
    int idx = blockIdx.x*256 + threadIdx.x;
    if (idx >= total) return;
    int r = idx / kout, c = idx - r*kout;
    float v = (c < kin) ? src[(size_t)r*kin + c] : 0.f;
    dst[idx] = f2bfu(v);
}

// ------- head: two-stage mean-pool + regression -------
__global__ __launch_bounds__(256) void head1_kernel(const float* __restrict__ X,
                             float* __restrict__ Pt)
{
    int b = blockIdx.x >> 6, c = blockIdx.x & 63;
    int tid = threadIdx.x;
    for (int dm = tid; dm < DM; dm += 256){
        float s = 0.f;
        const float* base = X + ((size_t)b*LL + c*32)*DM + dm;
        #pragma unroll 8
        for (int tt=0; tt<32; ++tt) s += base[(size_t)tt*DM];
        Pt[(size_t)(b*64 + c)*DM + dm] = s;
    }
}

__global__ __launch_bounds__(256) void head2_kernel(const float* __restrict__ Pt,
                             const float* __restrict__ reg_w,
                             const float* __restrict__ reg_b,
                             float* __restrict__ out)
{
    __shared__ float feat[DM];
    int b = blockIdx.x, tid = threadIdx.x;
    for (int dm = tid; dm < DM; dm += 256){
        float s = 0.f;
        for (int c=0; c<64; ++c) s += Pt[(size_t)(b*64 + c)*DM + dm];
        float f = s * (1.0f/LL);
        feat[dm] = f;
        out[16 + b*DM + dm] = f;
    }
    __syncthreads();
    if (tid < NSC){
        float s = reg_b[tid];
        const float* wr = reg_w + tid*DM;
        for (int k=0;k<DM;++k) s = fmaf(feat[k], wr[k], s);
        out[b*NSC + tid] = s;
    }
}

extern "C" void kernel_launch(void* const* d_in, const int* in_sizes, int n_in,
                              void* d_out, int out_size, void* d_ws, size_t ws_size,
                              hipStream_t stream)
{
    const float* x_in  = (const float*)d_in[0];
    const float* ln_w  = (const float*)d_in[1];
    const float* ln_b  = (const float*)d_in[2];
    const float* Wi    = (const float*)d_in[3];
    const float* cw    = (const float*)d_in[4];
    const float* cb    = (const float*)d_in[5];
    const float* Wx    = (const float*)d_in[6];
    const float* Wdt   = (const float*)d_in[7];
    const float* bdt   = (const float*)d_in[8];
    const float* A_log = (const float*)d_in[9];
    const float* Dd    = (const float*)d_in[10];
    const float* Wo    = (const float*)d_in[11];
    const float* regw  = (const float*)d_in[12];
    const float* regb  = (const float*)d_in[13];
    float* out = (float*)d_out;

    float* ws   = (float*)d_ws;
    float* XZ   = ws;                          // MTOK*1088 f32 (DELt + Yb overlay)
    float* XCt  = XZ   + (size_t)MTOK*1088;    // MTOK*544 f32 (u, then y)
    float* Gt   = XCt  + (size_t)MTOK*544;     // MTOK*544 f32
    float* DBLb = Gt   + (size_t)MTOK*544;     // MTOK*145 f32
    float* Xb   = DBLb + (size_t)MTOK*145;     // MTOK*272 f32 residual
    float* SCR  = Xb   + (size_t)MTOK*272;     // MTOK*272 f32 scratch: Hb/XCb/Q/Pt overlay
    float* Sbuf = SCR  + (size_t)MTOK*272;     // BB*DI*CH
    unsigned short* WiB = (unsigned short*)(Sbuf + BB*DI*CH);   // NL*1088*272 bf16
    unsigned short* WxB = WiB + (size_t)NL*1088*DM;             // NL*145*544 bf16
    unsigned short* WoB = WxB + (size_t)NL*145*DI;              // NL*272*544 bf16

    float* DELt = XZ;                                           // MTOK*544 f32
    unsigned short* Yb = (unsigned short*)(XZ + (size_t)MTOK*544); // MTOK*544 bf16
    unsigned short* Hb  = (unsigned short*)SCR;                 // MTOK*272 bf16
    unsigned short* XCb = (unsigned short*)SCR;                 // MTOK*544 bf16
    float* Q  = SCR;                                            // BB*DI*CH*64 f32
    float* Pt = SCR;                                            // BB*64*DM f32

    (void)hipMemcpyAsync(Xb, x_in, sizeof(float)*(size_t)MTOK*DM, hipMemcpyDeviceToDevice, stream);

    // one-shot weight conversion
    wconv_kernel<<<(NL*1088*DM + 255)/256, 256, 0, stream>>>(Wi, WiB, NL*1088*DM, DM, DM);
    wconv_kernel<<<(NL*145*DI + 255)/256, 256, 0, stream>>>(Wx, WxB, NL*145*DI, DI, DI);
    wconv_kernel<<<(NL*272*DI + 255)/256, 256, 0, stream>>>(Wo, WoB, NL*272*DI, DI, DI);

    for (int l=0; l<NL; ++l){
        ln_kernel<<<MTOK/4, 256, 0, stream>>>(Xb, ln_w + l*DM, ln_b + l*DM, Hb);
        gmfma<false><<<dim3(MTOK/128, (2*DI+127)/128), 256, 0, stream>>>(
            Hb, DM, WiB + (size_t)l*2*DI*DM, DM, XZ, 2*DI, nullptr, 0, 2*DI, DM);
        conv_t2_kernel<<<BB*256, 256, 0, stream>>>(XZ, cw + l*DI*4, cb + l*DI, XCt, Gt, XCb);
        gmfma<false><<<dim3(MTOK/128, 2), 256, 0, stream>>>(
            XCb, DI, WxB + (size_t)l*145*DI, DI, DBLb, 145, nullptr, 0, 145, DI);
        dt_t2_kernel<<<BB*256, 256, 0, stream>>>(DBLb, Wdt + (size_t)l*DI*DTR, bdt + l*DI, DELt);
        scan_a<<<(BB*CH*(DI/2))/4, 256, 0, stream>>>(DELt, XCt, DBLb,
                                                     A_log + (size_t)l*DI*DS, Q, Sbuf);
        scan_b<<<BB*(DI/4), 256, 0, stream>>>(Q, Sbuf, A_log + (size_t)l*DI*DS);
        scan_c<<<(BB*CH*(DI/2))/4, 256, 0, stream>>>(DELt, XCt, Gt, DBLb,
                                                     A_log + (size_t)l*DI*DS, Dd + l*DI, Q);
        yt2yb_kernel<<<BB*256, 256, 0, stream>>>(XCt, Yb);
        gmfma<true><<<dim3(MTOK/128, 3), 256, 0, stream>>>(
            Yb, DI, WoB + (size_t)l*DM*DI, DI, Xb, DM, Xb, DM, DM, DI);
    }
    head1_kernel<<<BB*64, 256, 0, stream>>>(Xb, Pt);
    head2_kernel<<<BB, 256, 0, stream>>>(Pt, regw, regb, out);
}

// Round 9
// 1862.929 us; speedup vs baseline: 3.1101x; 1.0030x over previous
//
#include <hip/hip_runtime.h>
#include <hip/hip_bf16.h>
#include <math.h>

#define NL 6
#define DM 272
#define DS 64
#define DI 544
#define DTR 17
#define NSC 4
#define BB 4
#define LL 2048
#define MTOK (BB*LL)
#define TCH 256
#define CH  8
#define DQ  (DI/4)   // 136 channels per quarter

typedef __attribute__((ext_vector_type(8))) short bf16x8;
typedef __attribute__((ext_vector_type(4))) float f32x4;

__device__ __forceinline__ float sigmoidf_(float x){ return 1.0f/(1.0f+__expf(-x)); }
__device__ __forceinline__ float rlf(float x, int s){ return __int_as_float(__builtin_amdgcn_readlane(__float_as_int(x), s)); }
__device__ __forceinline__ unsigned short f2bfu(float x){
    union { __hip_bfloat16 h; unsigned short u; } c; c.h = __float2bfloat16(x); return c.u;
}

#define DPPADD(x, ctrl) x += __int_as_float(__builtin_amdgcn_update_dpp(0, __float_as_int(x), ctrl, 0xf, 0xf, true))
__device__ __forceinline__ float wsum64(float x){
    DPPADD(x, 0x111); DPPADD(x, 0x112); DPPADD(x, 0x114); DPPADD(x, 0x118);
    DPPADD(x, 0x142); DPPADD(x, 0x143);
    return x;
}

// ---------------- LayerNorm: one wave per token, bf16 output ----------------
__global__ __launch_bounds__(256) void ln_kernel(const float* __restrict__ X,
                          const float* __restrict__ w,
                          const float* __restrict__ b,
                          unsigned short* __restrict__ Hb)
{
    int wave = threadIdx.x >> 6;
    int lane = threadIdx.x & 63;
    int tok = blockIdx.x*4 + wave;
    const float* xr = X + (size_t)tok*DM;
    float v[5];
    float s=0.f, ss=0.f;
    #pragma unroll
    for (int j=0;j<5;++j){
        int idx = lane + j*64;
        float x = (idx < DM) ? xr[idx] : 0.f;
        v[j]=x; s+=x; ss+=x*x;
    }
    #pragma unroll
    for (int off=1; off<64; off<<=1){ s += __shfl_xor(s,off); ss += __shfl_xor(ss,off); }
    float mu  = s * (1.0f/DM);
    float var = ss*(1.0f/DM) - mu*mu;
    float inv = 1.0f/sqrtf(var + 1e-5f);
    unsigned short* hr = Hb + (size_t)tok*DM;
    #pragma unroll
    for (int j=0;j<5;++j){
        int idx = lane + j*64;
        if (idx<DM) hr[idx] = f2bfu((v[j]-mu)*inv*w[idx] + b[idx]);
    }
}

// ======= bf16 MFMA GEMM: C[M,N] = A[M,K]bf16 @ W[N,K]bf16^T (+f32 residual) =======
template<bool RESID>
__global__ __launch_bounds__(256) void gmfma(const unsigned short* __restrict__ A, int lda,
                     const unsigned short* __restrict__ W, int ldw,
                     float* __restrict__ C, int ldc,
                     const float* __restrict__ R, int ldr,
                     int N, int K)
{
    __shared__ unsigned short As[128*40];
    __shared__ unsigned short Bs[128*40];
    int bm = blockIdx.x*128, bn = blockIdx.y*128;
    int tid = threadIdx.x;
    int lane = tid & 63, wave = tid >> 6;
    int wm = wave >> 1, wn = wave & 1;
    f32x4 acc[4][4] = {};
    int r16 = lane & 15, kg = (lane >> 4) * 8;
    for (int k0=0; k0<K; k0+=32){
        #pragma unroll
        for (int it=0; it<2; ++it){
            int cid = tid + it*256;
            int row = cid >> 2, kq = (cid & 3)*8;
            int kk = k0 + kq;
            uint4 za = make_uint4(0,0,0,0);
            if (kk < K) za = *(const uint4*)(A + (size_t)(bm+row)*lda + kk);
            *(uint4*)&As[row*40 + kq] = za;
            uint4 zb = make_uint4(0,0,0,0);
            int wr = bn + row;
            if (wr < N && kk < K) zb = *(const uint4*)(W + (size_t)wr*ldw + kk);
            *(uint4*)&Bs[row*40 + kq] = zb;
        }
        __syncthreads();
        bf16x8 af[4], bfr[4];
        #pragma unroll
        for (int mi=0; mi<4; ++mi)
            af[mi] = *(bf16x8*)&As[(wm*64 + mi*16 + r16)*40 + kg];
        #pragma unroll
        for (int ni=0; ni<4; ++ni)
            bfr[ni] = *(bf16x8*)&Bs[(wn*64 + ni*16 + r16)*40 + kg];
        #pragma unroll
        for (int mi=0; mi<4; ++mi)
            #pragma unroll
            for (int ni=0; ni<4; ++ni)
                acc[mi][ni] = __builtin_amdgcn_mfma_f32_16x16x32_bf16(af[mi], bfr[ni], acc[mi][ni], 0, 0, 0);
        __syncthreads();
    }
    int rowt = (lane >> 4)*4, colt = lane & 15;
    #pragma unroll
    for (int mi=0; mi<4; ++mi){
        #pragma unroll
        for (int ni=0; ni<4; ++ni){
            int col = bn + wn*64 + ni*16 + colt;
            if (col < N){
                #pragma unroll
                for (int j=0; j<4; ++j){
                    int row = bm + wm*64 + mi*16 + rowt + j;
                    float v = acc[mi][ni][j];
                    if (RESID) v += R[(size_t)row*ldr + col];
                    C[(size_t)row*ldc + col] = v;
                }
            }
        }
    }
}

// ------- conv+SiLU+gate, LDS transpose; outputs XCt/Gt f32 [d][t] + XCb bf16 [tok][d] -------
__global__ __launch_bounds__(256) void conv_t2_kernel(const float* __restrict__ XZ,
                                 const float* __restrict__ cw,
                                 const float* __restrict__ cb,
                                 float* __restrict__ XCt,
                                 float* __restrict__ Gt,
                                 unsigned short* __restrict__ XCb)
{
    __shared__ float xi[67][69];
    __shared__ float zz[64][69];
    int bid = blockIdx.x;
    int b  = bid >> 8;
    int rem = bid & 255;
    int t0 = (rem >> 3)*64;
    int d0 = (rem & 7)*68;
    int tid = threadIdx.x;
    for (int li = tid; li < 67*17; li += 256){
        int row = li / 17, q = li - row*17;
        int tg = t0 - 3 + row;
        float4 v = make_float4(0.f,0.f,0.f,0.f);
        if (tg >= 0)
            v = *(const float4*)(XZ + ((size_t)b*LL + tg)*(2*DI) + d0 + q*4);
        xi[row][q*4+0]=v.x; xi[row][q*4+1]=v.y; xi[row][q*4+2]=v.z; xi[row][q*4+3]=v.w;
    }
    for (int li = tid; li < 64*17; li += 256){
        int row = li / 17, q = li - row*17;
        float4 v = *(const float4*)(XZ + ((size_t)b*LL + t0 + row)*(2*DI) + DI + d0 + q*4);
        zz[row][q*4+0]=v.x; zz[row][q*4+1]=v.y; zz[row][q*4+2]=v.z; zz[row][q*4+3]=v.w;
    }
    __syncthreads();
    int t = tid & 63;
    int dw = tid >> 6;
    float xcreg[17];
    #pragma unroll
    for (int i=0; i<17; ++i){
        int dl = dw + i*4;
        int d = d0 + dl;
        const float* cwd = cw + d*4;
        float acc = cb[d];
        #pragma unroll
        for (int k=0;k<4;++k) acc = fmaf(xi[t+k][dl], cwd[k], acc);
        float xc = acc * sigmoidf_(acc);
        float z  = zz[t][dl];
        size_t o = ((size_t)b*DI + d)*LL + t0 + t;
        XCt[o] = xc;
        Gt[o]  = z * sigmoidf_(z);
        xcreg[i] = xc;
    }
    __syncthreads();
    #pragma unroll
    for (int i=0; i<17; ++i) zz[t][dw + i*4] = xcreg[i];
    __syncthreads();
    for (int li = tid; li < 64*17; li += 256){
        int row = li / 17, q = li - row*17;
        ushort4 v;
        v.x = f2bfu(zz[row][q*4+0]); v.y = f2bfu(zz[row][q*4+1]);
        v.z = f2bfu(zz[row][q*4+2]); v.w = f2bfu(zz[row][q*4+3]);
        *(ushort4*)&XCb[((size_t)b*LL + t0 + row)*DI + d0 + q*4] = v;
    }
}

// ------- dt_proj (K=17) + softplus, LDS-staged, coalesced output over t -------
__global__ __launch_bounds__(256) void dt_t2_kernel(const float* __restrict__ DBLb,
                          const float* __restrict__ Wdt,
                          const float* __restrict__ bdt,
                          float* __restrict__ DELt)
{
    __shared__ float dtv[64*19];
    __shared__ float wl[68*17];
    int bid = blockIdx.x;
    int b  = bid >> 8;
    int rem = bid & 255;
    int t0 = (rem >> 3)*64;
    int d0 = (rem & 7)*68;
    int tid = threadIdx.x;
    for (int li = tid; li < 64*17; li += 256){
        int row = li / 17, col = li - row*17;
        dtv[row*19 + col] = DBLb[((size_t)b*LL + t0 + row)*145 + col];
    }
    for (int li = tid; li < 68*17; li += 256)
        wl[li] = Wdt[(size_t)d0*17 + li];
    __syncthreads();
    int t = tid & 63;
    #pragma unroll 1
    for (int dl = tid >> 6; dl < 68; dl += 4){
        float s = bdt[d0 + dl];
        #pragma unroll
        for (int r=0;r<DTR;++r) s = fmaf(dtv[t*19 + r], wl[dl*17 + r], s);
        float sp = (s > 20.f) ? s : log1pf(__expf(s));
        DELt[((size_t)b*DI + d0 + dl)*LL + t0 + t] = sp;
    }
}

// ======= chunked scan, pass A: 4 channels/wave, local scan from h=0 =======
#define ASTEP(s) { float Bv = p[17+lane]; \
    h0 = fmaf(__expf(rlf(dl0,s)*Av0), h0, rlf(du0,s)*Bv); \
    h1 = fmaf(__expf(rlf(dl1,s)*Av1), h1, rlf(du1,s)*Bv); \
    h2 = fmaf(__expf(rlf(dl2,s)*Av2), h2, rlf(du2,s)*Bv); \
    h3 = fmaf(__expf(rlf(dl3,s)*Av3), h3, rlf(du3,s)*Bv); \
    p += 145; }

__global__ __launch_bounds__(256) void scan_a(const float* __restrict__ DELt,
                       const float* __restrict__ XCt,
                       const float* __restrict__ DBLb,
                       const float* __restrict__ A_log,
                       float* __restrict__ Q,
                       float* __restrict__ S)
{
    int wave = threadIdx.x >> 6, lane = threadIdx.x & 63;
    int wid = blockIdx.x*4 + wave;            // (b, c, dd) dd fastest; total BB*CH*DQ
    int dd = wid % DQ;
    int c  = (wid / DQ) % CH;
    int b  = wid / (DQ*CH);
    int d0 = dd, d1 = dd+DQ, d2 = dd+2*DQ, d3 = dd+3*DQ;
    float Av0 = -__expf(A_log[d0*DS + lane]);
    float Av1 = -__expf(A_log[d1*DS + lane]);
    float Av2 = -__expf(A_log[d2*DS + lane]);
    float Av3 = -__expf(A_log[d3*DS + lane]);
    float h0=0.f,h1=0.f,h2=0.f,h3=0.f, ds0=0.f,ds1=0.f,ds2=0.f,ds3=0.f;
    size_t rb0 = ((size_t)b*DI + d0)*LL + c*TCH;
    size_t rb1 = ((size_t)b*DI + d1)*LL + c*TCH;
    size_t rb2 = ((size_t)b*DI + d2)*LL + c*TCH;
    size_t rb3 = ((size_t)b*DI + d3)*LL + c*TCH;
    const float* pB = DBLb + ((size_t)b*LL + c*TCH)*145;
    for (int blk=0; blk<TCH/64; ++blk){
        size_t o0 = rb0 + blk*64 + lane, o1 = rb1 + blk*64 + lane;
        size_t o2 = rb2 + blk*64 + lane, o3 = rb3 + blk*64 + lane;
        float dl0 = DELt[o0], dl1 = DELt[o1], dl2 = DELt[o2], dl3 = DELt[o3];
        float du0 = dl0*XCt[o0], du1 = dl1*XCt[o1], du2 = dl2*XCt[o2], du3 = dl3*XCt[o3];
        ds0 += dl0; ds1 += dl1; ds2 += dl2; ds3 += dl3;
        const float* p = pB + (size_t)blk*64*145;
        #pragma unroll
        for (int s=0; s<64; ++s) ASTEP(s)
    }
    size_t q0 = ((size_t)b*DI + d0)*CH + c, q1 = ((size_t)b*DI + d1)*CH + c;
    size_t q2 = ((size_t)b*DI + d2)*CH + c, q3 = ((size_t)b*DI + d3)*CH + c;
    Q[q0*64 + lane] = h0; Q[q1*64 + lane] = h1;
    Q[q2*64 + lane] = h2; Q[q3*64 + lane] = h3;
    float s0 = wsum64(ds0), s1 = wsum64(ds1), s2 = wsum64(ds2), s3 = wsum64(ds3);
    if (lane == 63){ S[q0]=s0; S[q1]=s1; S[q2]=s2; S[q3]=s3; }
}

// ======= chunked scan, pass C: 4 channels/wave, inline lookback, LDS y-reduction =======
#define CSTEP(s) { float Bv = p[17+lane]; float Cv = p[81+lane]; \
    h0 = fmaf(__expf(rlf(dl0,s)*Av0), h0, rlf(du0,s)*Bv); \
    h1 = fmaf(__expf(rlf(dl1,s)*Av1), h1, rlf(du1,s)*Bv); \
    h2 = fmaf(__expf(rlf(dl2,s)*Av2), h2, rlf(du2,s)*Bv); \
    h3 = fmaf(__expf(rlf(dl3,s)*Av3), h3, rlf(du3,s)*Bv); \
    Pw[0][(s)&7][lane] = h0*Cv; Pw[1][(s)&7][lane] = h1*Cv; \
    Pw[2][(s)&7][lane] = h2*Cv; Pw[3][(s)&7][lane] = h3*Cv; \
    p += 145; }

#define FLUSH(k, yk, f) { \
    float4 xa = *(const float4*)&Pw[k][fr][fq8]; \
    float4 xb = *(const float4*)&Pw[k][fr][fq8+4]; \
    float sA = ((xa.x+xa.y)+(xa.z+xa.w)) + ((xb.x+xb.y)+(xb.z+xb.w)); \
    DPPADD(sA,0x111); DPPADD(sA,0x112); DPPADD(sA,0x114); \
    if ((lane&7)==7) Yp[k][lane>>3] = sA; \
    float gP = Yp[k][lane&7]; \
    if ((lane>>3)==(f)) yk = gP; }

__global__ __launch_bounds__(256) void scan_c(const float* __restrict__ DELt,
                       float* __restrict__ XCt,
                       const float* __restrict__ Gt,
                       const float* __restrict__ DBLb,
                       const float* __restrict__ A_log,
                       const float* __restrict__ Dskip,
                       const float* __restrict__ Q,
                       const float* __restrict__ S)
{
    __shared__ float P[4][4][8][76];
    __shared__ float Ypark[4][4][8];
    int wave = threadIdx.x >> 6, lane = threadIdx.x & 63;
    float (*Pw)[8][76] = P[wave];
    float (*Yp)[8] = Ypark[wave];
    int wid = blockIdx.x*4 + wave;
    int dd = wid % DQ;
    int c  = (wid / DQ) % CH;
    int b  = wid / (DQ*CH);
    int d0 = dd, d1 = dd+DQ, d2 = dd+2*DQ, d3 = dd+3*DQ;
    float Av0 = -__expf(A_log[d0*DS + lane]);
    float Av1 = -__expf(A_log[d1*DS + lane]);
    float Av2 = -__expf(A_log[d2*DS + lane]);
    float Av3 = -__expf(A_log[d3*DS + lane]);
    float Dd0 = Dskip[d0], Dd1 = Dskip[d1], Dd2 = Dskip[d2], Dd3 = Dskip[d3];
    // inline lookback: combine chunks 0..c-1
    size_t q0 = ((size_t)b*DI + d0)*CH, q1 = ((size_t)b*DI + d1)*CH;
    size_t q2 = ((size_t)b*DI + d2)*CH, q3 = ((size_t)b*DI + d3)*CH;
    float h0=0.f,h1=0.f,h2=0.f,h3=0.f;
    for (int j=0; j<c; ++j){
        h0 = fmaf(__expf(Av0*S[q0+j]), h0, Q[(q0+j)*64 + lane]);
        h1 = fmaf(__expf(Av1*S[q1+j]), h1, Q[(q1+j)*64 + lane]);
        h2 = fmaf(__expf(Av2*S[q2+j]), h2, Q[(q2+j)*64 + lane]);
        h3 = fmaf(__expf(Av3*S[q3+j]), h3, Q[(q3+j)*64 + lane]);
    }
    size_t rb0 = ((size_t)b*DI + d0)*LL + c*TCH;
    size_t rb1 = ((size_t)b*DI + d1)*LL + c*TCH;
    size_t rb2 = ((size_t)b*DI + d2)*LL + c*TCH;
    size_t rb3 = ((size_t)b*DI + d3)*LL + c*TCH;
    const float* pB = DBLb + ((size_t)b*LL + c*TCH)*145;
    int fr = lane >> 3, fq8 = (lane & 7)*8;
    for (int blk=0; blk<TCH/64; ++blk){
        size_t o0 = rb0 + blk*64 + lane, o1 = rb1 + blk*64 + lane;
        size_t o2 = rb2 + blk*64 + lane, o3 = rb3 + blk*64 + lane;
        float dl0 = DELt[o0], dl1 = DELt[o1], dl2 = DELt[o2], dl3 = DELt[o3];
        float ul0 = XCt[o0],  ul1 = XCt[o1],  ul2 = XCt[o2],  ul3 = XCt[o3];
        float gl0 = Gt[o0],   gl1 = Gt[o1],   gl2 = Gt[o2],   gl3 = Gt[o3];
        float du0 = dl0*ul0,  du1 = dl1*ul1,  du2 = dl2*ul2,  du3 = dl3*ul3;
        float y0=0.f,y1=0.f,y2=0.f,y3=0.f;
        const float* p = pB + (size_t)blk*64*145;
        #pragma unroll 1
        for (int f=0; f<8; ++f){
            int base = f*8;
            CSTEP(base+0) CSTEP(base+1) CSTEP(base+2) CSTEP(base+3)
            CSTEP(base+4) CSTEP(base+5) CSTEP(base+6) CSTEP(base+7)
            FLUSH(0, y0, f) FLUSH(1, y1, f) FLUSH(2, y2, f) FLUSH(3, y3, f)
        }
        XCt[o0] = (y0 + ul0*Dd0)*gl0;
        XCt[o1] = (y1 + ul1*Dd1)*gl1;
        XCt[o2] = (y2 + ul2*Dd2)*gl2;
        XCt[o3] = (y3 + ul3*Dd3)*gl3;
    }
}

// ------- y transpose: XCt f32 [b][d][t] -> Yb bf16 [tok][DI] -------
__global__ __launch_bounds__(256) void yt2yb_kernel(const float* __restrict__ Yt,
                             unsigned short* __restrict__ Yb)
{
    __shared__ float yt[64][69];
    int bid = blockIdx.x;
    int b = bid >> 8;
    int rem = bid & 255;
    int d0 = (rem >> 5)*68;
    int t0 = (rem & 31)*64;
    int tid = threadIdx.x;
    for (int li = tid; li < 68*16; li += 256){
        int dl = li >> 4, tq = (li & 15)*4;
        float4 v = *(const float4*)(Yt + ((size_t)b*DI + d0 + dl)*LL + t0 + tq);
        yt[tq+0][dl]=v.x; yt[tq+1][dl]=v.y; yt[tq+2][dl]=v.z; yt[tq+3][dl]=v.w;
    }
    __syncthreads();
    for (int li = tid; li < 64*17; li += 256){
        int row = li / 17, q = li - row*17;
        ushort4 v;
        v.x = f2bfu(yt[row][q*4+0]); v.y = f2bfu(yt[row][q*4+1]);
        v.z = f2bfu(yt[row][q*4+2]); v.w = f2bfu(yt[row][q*4+3]);
        *(ushort4*)&Yb[((size_t)b*LL + t0 + row)*DI + d0 + q*4] = v;
    }
}

// ------- weight f32 -> bf16 convert -------
__global__ __launch_bounds__(256) void wconv_kernel(const float* __restrict__ src,
                            unsigned short* __restrict__ dst,
                            int total, int kin, int kout)
{
    int idx = blockIdx.x*256 + threadIdx.x;
    if (idx >= total) return;
    int r = idx / kout, c = idx - r*kout;
    float v = (c < kin) ? src[(size_t)r*kin + c] : 0.f;
    dst[idx] = f2bfu(v);
}

// ------- head: two-stage mean-pool + regression -------
__global__ __launch_bounds__(256) void head1_kernel(const float* __restrict__ X,
                             float* __restrict__ Pt)
{
    int b = blockIdx.x >> 6, c = blockIdx.x & 63;
    int tid = threadIdx.x;
    for (int dm = tid; dm < DM; dm += 256){
        float s = 0.f;
        const float* base = X + ((size_t)b*LL + c*32)*DM + dm;
        #pragma unroll 8
        for (int tt=0; tt<32; ++tt) s += base[(size_t)tt*DM];
        Pt[(size_t)(b*64 + c)*DM + dm] = s;
    }
}

__global__ __launch_bounds__(256) void head2_kernel(const float* __restrict__ Pt,
                             const float* __restrict__ reg_w,
                             const float* __restrict__ reg_b,
                             float* __restrict__ out)
{
    __shared__ float feat[DM];
    int b = blockIdx.x, tid = threadIdx.x;
    for (int dm = tid; dm < DM; dm += 256){
        float s = 0.f;
        for (int c=0; c<64; ++c) s += Pt[(size_t)(b*64 + c)*DM + dm];
        float f = s * (1.0f/LL);
        feat[dm] = f;
        out[16 + b*DM + dm] = f;
    }
    __syncthreads();
    if (tid < NSC){
        float s = reg_b[tid];
        const float* wr = reg_w + tid*DM;
        for (int k=0;k<DM;++k) s = fmaf(feat[k], wr[k], s);
        out[b*NSC + tid] = s;
    }
}

extern "C" void kernel_launch(void* const* d_in, const int* in_sizes, int n_in,
                              void* d_out, int out_size, void* d_ws, size_t ws_size,
                              hipStream_t stream)
{
    const float* x_in  = (const float*)d_in[0];
    const float* ln_w  = (const float*)d_in[1];
    const float* ln_b  = (const float*)d_in[2];
    const float* Wi    = (const float*)d_in[3];
    const float* cw    = (const float*)d_in[4];
    const float* cb    = (const float*)d_in[5];
    const float* Wx    = (const float*)d_in[6];
    const float* Wdt   = (const float*)d_in[7];
    const float* bdt   = (const float*)d_in[8];
    const float* A_log = (const float*)d_in[9];
    const float* Dd    = (const float*)d_in[10];
    const float* Wo    = (const float*)d_in[11];
    const float* regw  = (const float*)d_in[12];
    const float* regb  = (const float*)d_in[13];
    float* out = (float*)d_out;

    float* ws   = (float*)d_ws;
    float* XZ   = ws;                          // MTOK*1088 f32 (DELt + Yb overlay)
    float* XCt  = XZ   + (size_t)MTOK*1088;    // MTOK*544 f32 (u, then y)
    float* Gt   = XCt  + (size_t)MTOK*544;     // MTOK*544 f32
    float* DBLb = Gt   + (size_t)MTOK*544;     // MTOK*145 f32
    float* Xb   = DBLb + (size_t)MTOK*145;     // MTOK*272 f32 residual
    float* SCR  = Xb   + (size_t)MTOK*272;     // MTOK*272 f32 scratch: Hb/XCb/Q/Pt overlay
    float* Sbuf = SCR  + (size_t)MTOK*272;     // BB*DI*CH
    unsigned short* WiB = (unsigned short*)(Sbuf + BB*DI*CH);   // NL*1088*272 bf16
    unsigned short* WxB = WiB + (size_t)NL*1088*DM;             // NL*145*544 bf16
    unsigned short* WoB = WxB + (size_t)NL*145*DI;              // NL*272*544 bf16

    float* DELt = XZ;
    unsigned short* Yb = (unsigned short*)(XZ + (size_t)MTOK*544);
    unsigned short* Hb  = (unsigned short*)SCR;
    unsigned short* XCb = (unsigned short*)SCR;
    float* Q  = SCR;
    float* Pt = SCR;

    (void)hipMemcpyAsync(Xb, x_in, sizeof(float)*(size_t)MTOK*DM, hipMemcpyDeviceToDevice, stream);

    wconv_kernel<<<(NL*1088*DM + 255)/256, 256, 0, stream>>>(Wi, WiB, NL*1088*DM, DM, DM);
    wconv_kernel<<<(NL*145*DI + 255)/256, 256, 0, stream>>>(Wx, WxB, NL*145*DI, DI, DI);
    wconv_kernel<<<(NL*272*DI + 255)/256, 256, 0, stream>>>(Wo, WoB, NL*272*DI, DI, DI);

    for (int l=0; l<NL; ++l){
        ln_kernel<<<MTOK/4, 256, 0, stream>>>(Xb, ln_w + l*DM, ln_b + l*DM, Hb);
        gmfma<false><<<dim3(MTOK/128, (2*DI+127)/128), 256, 0, stream>>>(
            Hb, DM, WiB + (size_t)l*2*DI*DM, DM, XZ, 2*DI, nullptr, 0, 2*DI, DM);
        conv_t2_kernel<<<BB*256, 256, 0, stream>>>(XZ, cw + l*DI*4, cb + l*DI, XCt, Gt, XCb);
        gmfma<false><<<dim3(MTOK/128, 2), 256, 0, stream>>>(
            XCb, DI, WxB + (size_t)l*145*DI, DI, DBLb, 145, nullptr, 0, 145, DI);
        dt_t2_kernel<<<BB*256, 256, 0, stream>>>(DBLb, Wdt + (size_t)l*DI*DTR, bdt + l*DI, DELt);
        scan_a<<<(BB*CH*DQ)/4, 256, 0, stream>>>(DELt, XCt, DBLb,
                                                 A_log + (size_t)l*DI*DS, Q, Sbuf);
        scan_c<<<(BB*CH*DQ)/4, 256, 0, stream>>>(DELt, XCt, Gt, DBLb,
                                                 A_log + (size_t)l*DI*DS, Dd + l*DI, Q, Sbuf);
        yt2yb_kernel<<<BB*256, 256, 0, stream>>>(XCt, Yb);
        gmfma<true><<<dim3(MTOK/128, 3), 256, 0, stream>>>(
            Yb, DI, WoB + (size_t)l*DM*DI, DI, Xb, DM, Xb, DM, DM, DI);
    }
    head1_kernel<<<BB*64, 256, 0, stream>>>(Xb, Pt);
    head2_kernel<<<BB, 256, 0, stream>>>(Pt, regw, regb, out);
}

// Round 10
// 1697.553 us; speedup vs baseline: 3.4130x; 1.0974x over previous
//
#include <hip/hip_runtime.h>
#include <hip/hip_bf16.h>
#include <math.h>

#define NL 6
#define DM 272
#define DS 64
#define DI 544
#define DTR 17
#define NSC 4
#define BB 4
#define LL 2048
#define MTOK (BB*LL)
#define TCH 128
#define CH  16
#define DQ  (DI/4)   // 136

typedef __attribute__((ext_vector_type(8))) short bf16x8;
typedef __attribute__((ext_vector_type(4))) float f32x4;

__device__ __forceinline__ float sigmoidf_(float x){ return 1.0f/(1.0f+__expf(-x)); }
__device__ __forceinline__ float rlf(float x, int s){ return __int_as_float(__builtin_amdgcn_readlane(__float_as_int(x), s)); }
__device__ __forceinline__ unsigned short f2bfu(float x){
    union { __hip_bfloat16 h; unsigned short u; } c; c.h = __float2bfloat16(x); return c.u;
}

#define DPPADD(x, ctrl) x += __int_as_float(__builtin_amdgcn_update_dpp(0, __float_as_int(x), ctrl, 0xf, 0xf, true))
__device__ __forceinline__ float wsum64(float x){
    DPPADD(x, 0x111); DPPADD(x, 0x112); DPPADD(x, 0x114); DPPADD(x, 0x118);
    DPPADD(x, 0x142); DPPADD(x, 0x143);
    return x;
}

// ---------------- LayerNorm: one wave per token, bf16 output ----------------
__global__ __launch_bounds__(256) void ln_kernel(const float* __restrict__ X,
                          const float* __restrict__ w,
                          const float* __restrict__ b,
                          unsigned short* __restrict__ Hb)
{
    int wave = threadIdx.x >> 6;
    int lane = threadIdx.x & 63;
    int tok = blockIdx.x*4 + wave;
    const float* xr = X + (size_t)tok*DM;
    float v[5];
    float s=0.f, ss=0.f;
    #pragma unroll
    for (int j=0;j<5;++j){
        int idx = lane + j*64;
        float x = (idx < DM) ? xr[idx] : 0.f;
        v[j]=x; s+=x; ss+=x*x;
    }
    #pragma unroll
    for (int off=1; off<64; off<<=1){ s += __shfl_xor(s,off); ss += __shfl_xor(ss,off); }
    float mu  = s * (1.0f/DM);
    float var = ss*(1.0f/DM) - mu*mu;
    float inv = 1.0f/sqrtf(var + 1e-5f);
    unsigned short* hr = Hb + (size_t)tok*DM;
    #pragma unroll
    for (int j=0;j<5;++j){
        int idx = lane + j*64;
        if (idx<DM) hr[idx] = f2bfu((v[j]-mu)*inv*w[idx] + b[idx]);
    }
}

// ======= bf16 MFMA GEMM: C[M,N] = A[M,K]bf16 @ W[N,K]bf16^T (+f32 residual) =======
template<bool RESID>
__global__ __launch_bounds__(256) void gmfma(const unsigned short* __restrict__ A, int lda,
                     const unsigned short* __restrict__ W, int ldw,
                     float* __restrict__ C, int ldc,
                     const float* __restrict__ R, int ldr,
                     int N, int K)
{
    __shared__ unsigned short As[128*40];
    __shared__ unsigned short Bs[128*40];
    int bm = blockIdx.x*128, bn = blockIdx.y*128;
    int tid = threadIdx.x;
    int lane = tid & 63, wave = tid >> 6;
    int wm = wave >> 1, wn = wave & 1;
    f32x4 acc[4][4] = {};
    int r16 = lane & 15, kg = (lane >> 4) * 8;
    for (int k0=0; k0<K; k0+=32){
        #pragma unroll
        for (int it=0; it<2; ++it){
            int cid = tid + it*256;
            int row = cid >> 2, kq = (cid & 3)*8;
            int kk = k0 + kq;
            uint4 za = make_uint4(0,0,0,0);
            if (kk < K) za = *(const uint4*)(A + (size_t)(bm+row)*lda + kk);
            *(uint4*)&As[row*40 + kq] = za;
            uint4 zb = make_uint4(0,0,0,0);
            int wr = bn + row;
            if (wr < N && kk < K) zb = *(const uint4*)(W + (size_t)wr*ldw + kk);
            *(uint4*)&Bs[row*40 + kq] = zb;
        }
        __syncthreads();
        bf16x8 af[4], bfr[4];
        #pragma unroll
        for (int mi=0; mi<4; ++mi)
            af[mi] = *(bf16x8*)&As[(wm*64 + mi*16 + r16)*40 + kg];
        #pragma unroll
        for (int ni=0; ni<4; ++ni)
            bfr[ni] = *(bf16x8*)&Bs[(wn*64 + ni*16 + r16)*40 + kg];
        #pragma unroll
        for (int mi=0; mi<4; ++mi)
            #pragma unroll
            for (int ni=0; ni<4; ++ni)
                acc[mi][ni] = __builtin_amdgcn_mfma_f32_16x16x32_bf16(af[mi], bfr[ni], acc[mi][ni], 0, 0, 0);
        __syncthreads();
    }
    int rowt = (lane >> 4)*4, colt = lane & 15;
    #pragma unroll
    for (int mi=0; mi<4; ++mi){
        #pragma unroll
        for (int ni=0; ni<4; ++ni){
            int col = bn + wn*64 + ni*16 + colt;
            if (col < N){
                #pragma unroll
                for (int j=0; j<4; ++j){
                    int row = bm + wm*64 + mi*16 + rowt + j;
                    float v = acc[mi][ni][j];
                    if (RESID) v += R[(size_t)row*ldr + col];
                    C[(size_t)row*ldc + col] = v;
                }
            }
        }
    }
}

// ------- conv+SiLU+gate, LDS transpose; outputs XCt/Gt f32 [d][t] + XCb bf16 [tok][d] -------
__global__ __launch_bounds__(256) void conv_t2_kernel(const float* __restrict__ XZ,
                                 const float* __restrict__ cw,
                                 const float* __restrict__ cb,
                                 float* __restrict__ XCt,
                                 float* __restrict__ Gt,
                                 unsigned short* __restrict__ XCb)
{
    __shared__ float xi[67][69];
    __shared__ float zz[64][69];
    int bid = blockIdx.x;
    int b  = bid >> 8;
    int rem = bid & 255;
    int t0 = (rem >> 3)*64;
    int d0 = (rem & 7)*68;
    int tid = threadIdx.x;
    for (int li = tid; li < 67*17; li += 256){
        int row = li / 17, q = li - row*17;
        int tg = t0 - 3 + row;
        float4 v = make_float4(0.f,0.f,0.f,0.f);
        if (tg >= 0)
            v = *(const float4*)(XZ + ((size_t)b*LL + tg)*(2*DI) + d0 + q*4);
        xi[row][q*4+0]=v.x; xi[row][q*4+1]=v.y; xi[row][q*4+2]=v.z; xi[row][q*4+3]=v.w;
    }
    for (int li = tid; li < 64*17; li += 256){
        int row = li / 17, q = li - row*17;
        float4 v = *(const float4*)(XZ + ((size_t)b*LL + t0 + row)*(2*DI) + DI + d0 + q*4);
        zz[row][q*4+0]=v.x; zz[row][q*4+1]=v.y; zz[row][q*4+2]=v.z; zz[row][q*4+3]=v.w;
    }
    __syncthreads();
    int t = tid & 63;
    int dw = tid >> 6;
    float xcreg[17];
    #pragma unroll
    for (int i=0; i<17; ++i){
        int dl = dw + i*4;
        int d = d0 + dl;
        const float* cwd = cw + d*4;
        float acc = cb[d];
        #pragma unroll
        for (int k=0;k<4;++k) acc = fmaf(xi[t+k][dl], cwd[k], acc);
        float xc = acc * sigmoidf_(acc);
        float z  = zz[t][dl];
        size_t o = ((size_t)b*DI + d)*LL + t0 + t;
        XCt[o] = xc;
        Gt[o]  = z * sigmoidf_(z);
        xcreg[i] = xc;
    }
    __syncthreads();
    #pragma unroll
    for (int i=0; i<17; ++i) zz[t][dw + i*4] = xcreg[i];
    __syncthreads();
    for (int li = tid; li < 64*17; li += 256){
        int row = li / 17, q = li - row*17;
        ushort4 v;
        v.x = f2bfu(zz[row][q*4+0]); v.y = f2bfu(zz[row][q*4+1]);
        v.z = f2bfu(zz[row][q*4+2]); v.w = f2bfu(zz[row][q*4+3]);
        *(ushort4*)&XCb[((size_t)b*LL + t0 + row)*DI + d0 + q*4] = v;
    }
}

// ------- dt_proj (K=17) + softplus, LDS-staged, coalesced output over t -------
__global__ __launch_bounds__(256) void dt_t2_kernel(const float* __restrict__ DBLb,
                          const float* __restrict__ Wdt,
                          const float* __restrict__ bdt,
                          float* __restrict__ DELt)
{
    __shared__ float dtv[64*19];
    __shared__ float wl[68*17];
    int bid = blockIdx.x;
    int b  = bid >> 8;
    int rem = bid & 255;
    int t0 = (rem >> 3)*64;
    int d0 = (rem & 7)*68;
    int tid = threadIdx.x;
    for (int li = tid; li < 64*17; li += 256){
        int row = li / 17, col = li - row*17;
        dtv[row*19 + col] = DBLb[((size_t)b*LL + t0 + row)*145 + col];
    }
    for (int li = tid; li < 68*17; li += 256)
        wl[li] = Wdt[(size_t)d0*17 + li];
    __syncthreads();
    int t = tid & 63;
    #pragma unroll 1
    for (int dl = tid >> 6; dl < 68; dl += 4){
        float s = bdt[d0 + dl];
        #pragma unroll
        for (int r=0;r<DTR;++r) s = fmaf(dtv[t*19 + r], wl[dl*17 + r], s);
        float sp = (s > 20.f) ? s : log1pf(__expf(s));
        DELt[((size_t)b*DI + d0 + dl)*LL + t0 + t] = sp;
    }
}

// ======= chunked scan, pass A: 4 channels/wave, local scan from h=0 =======
#define ASTEP(s) { float Bv = p[17+lane]; \
    h0 = fmaf(__expf(rlf(dl0,s)*Av0), h0, rlf(du0,s)*Bv); \
    h1 = fmaf(__expf(rlf(dl1,s)*Av1), h1, rlf(du1,s)*Bv); \
    h2 = fmaf(__expf(rlf(dl2,s)*Av2), h2, rlf(du2,s)*Bv); \
    h3 = fmaf(__expf(rlf(dl3,s)*Av3), h3, rlf(du3,s)*Bv); \
    p += 145; }

__global__ __launch_bounds__(256) void scan_a(const float* __restrict__ DELt,
                       const float* __restrict__ XCt,
                       const float* __restrict__ DBLb,
                       const float* __restrict__ A_log,
                       float* __restrict__ Q,
                       float* __restrict__ S)
{
    int wave = threadIdx.x >> 6, lane = threadIdx.x & 63;
    int wid = blockIdx.x*4 + wave;            // (b, c, dd) dd fastest; total BB*CH*DQ
    int dd = wid % DQ;
    int c  = (wid / DQ) % CH;
    int b  = wid / (DQ*CH);
    int d0 = dd, d1 = dd+DQ, d2 = dd+2*DQ, d3 = dd+3*DQ;
    float Av0 = -__expf(A_log[d0*DS + lane]);
    float Av1 = -__expf(A_log[d1*DS + lane]);
    float Av2 = -__expf(A_log[d2*DS + lane]);
    float Av3 = -__expf(A_log[d3*DS + lane]);
    float h0=0.f,h1=0.f,h2=0.f,h3=0.f, ds0=0.f,ds1=0.f,ds2=0.f,ds3=0.f;
    size_t rb0 = ((size_t)b*DI + d0)*LL + c*TCH;
    size_t rb1 = ((size_t)b*DI + d1)*LL + c*TCH;
    size_t rb2 = ((size_t)b*DI + d2)*LL + c*TCH;
    size_t rb3 = ((size_t)b*DI + d3)*LL + c*TCH;
    const float* pB = DBLb + ((size_t)b*LL + c*TCH)*145;
    for (int blk=0; blk<TCH/64; ++blk){
        size_t o0 = rb0 + blk*64 + lane, o1 = rb1 + blk*64 + lane;
        size_t o2 = rb2 + blk*64 + lane, o3 = rb3 + blk*64 + lane;
        float dl0 = DELt[o0], dl1 = DELt[o1], dl2 = DELt[o2], dl3 = DELt[o3];
        float du0 = dl0*XCt[o0], du1 = dl1*XCt[o1], du2 = dl2*XCt[o2], du3 = dl3*XCt[o3];
        ds0 += dl0; ds1 += dl1; ds2 += dl2; ds3 += dl3;
        const float* p = pB + (size_t)blk*64*145;
        #pragma unroll
        for (int s=0; s<64; ++s) ASTEP(s)
    }
    size_t q0 = ((size_t)b*DI + d0)*CH + c, q1 = ((size_t)b*DI + d1)*CH + c;
    size_t q2 = ((size_t)b*DI + d2)*CH + c, q3 = ((size_t)b*DI + d3)*CH + c;
    Q[q0*64 + lane] = h0; Q[q1*64 + lane] = h1;
    Q[q2*64 + lane] = h2; Q[q3*64 + lane] = h3;
    float s0 = wsum64(ds0), s1 = wsum64(ds1), s2 = wsum64(ds2), s3 = wsum64(ds3);
    if (lane == 63){ S[q0]=s0; S[q1]=s1; S[q2]=s2; S[q3]=s3; }
}

// ======= chunked scan, pass C: 2 channels/wave, inline lookback, park-buffer y-reduction =======
#define CSTEP(s) { float Bv = p[17+lane]; float Cv = p[81+lane]; \
    h0 = fmaf(__expf(rlf(dl0,s)*Av0), h0, rlf(du0,s)*Bv); \
    h1 = fmaf(__expf(rlf(dl1,s)*Av1), h1, rlf(du1,s)*Bv); \
    Pw[0][(s)&7][lane] = h0*Cv; \
    Pw[1][(s)&7][lane] = h1*Cv; \
    p += 145; }

#define FLUSH(k, yk, f) { \
    float4 xa = *(const float4*)&Pw[k][fr][fq8]; \
    float4 xb = *(const float4*)&Pw[k][fr][fq8+4]; \
    float sA = ((xa.x+xa.y)+(xa.z+xa.w)) + ((xb.x+xb.y)+(xb.z+xb.w)); \
    DPPADD(sA,0x111); DPPADD(sA,0x112); DPPADD(sA,0x114); \
    if ((lane&7)==7) Yp[k][lane>>3] = sA; \
    float gP = Yp[k][lane&7]; \
    if ((lane>>3)==(f)) yk = gP; }

__global__ __launch_bounds__(256) void scan_c(const float* __restrict__ DELt,
                       float* __restrict__ XCt,
                       const float* __restrict__ Gt,
                       const float* __restrict__ DBLb,
                       const float* __restrict__ A_log,
                       const float* __restrict__ Dskip,
                       const float* __restrict__ Q,
                       const float* __restrict__ S)
{
    __shared__ float P[4][2][8][76];
    __shared__ float Ypark[4][2][8];
    int wave = threadIdx.x >> 6, lane = threadIdx.x & 63;
    float (*Pw)[8][76] = P[wave];
    float (*Yp)[8] = Ypark[wave];
    int wid = blockIdx.x*4 + wave;            // (b, c, dd) dd fastest; total BB*CH*(DI/2)
    int dd = wid % (DI/2);
    int c  = (wid / (DI/2)) % CH;
    int b  = wid / ((DI/2)*CH);
    int d0 = dd, d1 = dd + DI/2;
    float Av0 = -__expf(A_log[d0*DS + lane]);
    float Av1 = -__expf(A_log[d1*DS + lane]);
    float Dd0 = Dskip[d0], Dd1 = Dskip[d1];
    // inline lookback: combine chunks 0..c-1
    size_t q0 = ((size_t)b*DI + d0)*CH, q1 = ((size_t)b*DI + d1)*CH;
    float h0=0.f, h1=0.f;
    for (int j=0; j<c; ++j){
        h0 = fmaf(__expf(Av0*S[q0+j]), h0, Q[(q0+j)*64 + lane]);
        h1 = fmaf(__expf(Av1*S[q1+j]), h1, Q[(q1+j)*64 + lane]);
    }
    size_t rb0 = ((size_t)b*DI + d0)*LL + c*TCH;
    size_t rb1 = ((size_t)b*DI + d1)*LL + c*TCH;
    const float* pB = DBLb + ((size_t)b*LL + c*TCH)*145;
    int fr = lane >> 3, fq8 = (lane & 7)*8;
    for (int blk=0; blk<TCH/64; ++blk){
        size_t o0 = rb0 + blk*64 + lane, o1 = rb1 + blk*64 + lane;
        float dl0 = DELt[o0], dl1 = DELt[o1];
        float ul0 = XCt[o0],  ul1 = XCt[o1];
        float gl0 = Gt[o0],   gl1 = Gt[o1];
        float du0 = dl0*ul0,  du1 = dl1*ul1;
        float y0=0.f, y1=0.f;
        const float* p = pB + (size_t)blk*64*145;
        #pragma unroll 1
        for (int f=0; f<8; ++f){
            int base = f*8;
            CSTEP(base+0) CSTEP(base+1) CSTEP(base+2) CSTEP(base+3)
            CSTEP(base+4) CSTEP(base+5) CSTEP(base+6) CSTEP(base+7)
            FLUSH(0, y0, f) FLUSH(1, y1, f)
        }
        XCt[o0] = (y0 + ul0*Dd0)*gl0;
        XCt[o1] = (y1 + ul1*Dd1)*gl1;
    }
}

// ------- y transpose: XCt f32 [b][d][t] -> Yb bf16 [tok][DI] -------
__global__ __launch_bounds__(256) void yt2yb_kernel(const float* __restrict__ Yt,
                             unsigned short* __restrict__ Yb)
{
    __shared__ float yt[64][69];
    int bid = blockIdx.x;
    int b = bid >> 8;
    int rem = bid & 255;
    int d0 = (rem >> 5)*68;
    int t0 = (rem & 31)*64;
    int tid = threadIdx.x;
    for (int li = tid; li < 68*16; li += 256){
        int dl = li >> 4, tq = (li & 15)*4;
        float4 v = *(const float4*)(Yt + ((size_t)b*DI + d0 + dl)*LL + t0 + tq);
        yt[tq+0][dl]=v.x; yt[tq+1][dl]=v.y; yt[tq+2][dl]=v.z; yt[tq+3][dl]=v.w;
    }
    __syncthreads();
    for (int li = tid; li < 64*17; li += 256){
        int row = li / 17, q = li - row*17;
        ushort4 v;
        v.x = f2bfu(yt[row][q*4+0]); v.y = f2bfu(yt[row][q*4+1]);
        v.z = f2bfu(yt[row][q*4+2]); v.w = f2bfu(yt[row][q*4+3]);
        *(ushort4*)&Yb[((size_t)b*LL + t0 + row)*DI + d0 + q*4] = v;
    }
}

// ------- weight f32 -> bf16 convert -------
__global__ __launch_bounds__(256) void wconv_kernel(const float* __restrict__ src,
                            unsigned short* __restrict__ dst,
                            int total, int kin, int kout)
{
    int idx = blockIdx.x*256 + threadIdx.x;
    if (idx >= total) return;
    int r = idx / kout, c = idx - r*kout;
    float v = (c < kin) ? src[(size_t)r*kin + c] : 0.f;
    dst[idx] = f2bfu(v);
}

// ------- head: two-stage mean-pool + regression -------
__global__ __launch_bounds__(256) void head1_kernel(const float* __restrict__ X,
                             float* __restrict__ Pt)
{
    int b = blockIdx.x >> 6, c = blockIdx.x & 63;
    int tid = threadIdx.x;
    for (int dm = tid; dm < DM; dm += 256){
        float s = 0.f;
        const float* base = X + ((size_t)b*LL + c*32)*DM + dm;
        #pragma unroll 8
        for (int tt=0; tt<32; ++tt) s += base[(size_t)tt*DM];
        Pt[(size_t)(b*64 + c)*DM + dm] = s;
    }
}

__global__ __launch_bounds__(256) void head2_kernel(const float* __restrict__ Pt,
                             const float* __restrict__ reg_w,
                             const float* __restrict__ reg_b,
                             float* __restrict__ out)
{
    __shared__ float feat[DM];
    int b = blockIdx.x, tid = threadIdx.x;
    for (int dm = tid; dm < DM; dm += 256){
        float s = 0.f;
        for (int c=0; c<64; ++c) s += Pt[(size_t)(b*64 + c)*DM + dm];
        float f = s * (1.0f/LL);
        feat[dm] = f;
        out[16 + b*DM + dm] = f;
    }
    __syncthreads();
    if (tid < NSC){
        float s = reg_b[tid];
        const float* wr = reg_w + tid*DM;
        for (int k=0;k<DM;++k) s = fmaf(feat[k], wr[k], s);
        out[b*NSC + tid] = s;
    }
}

extern "C" void kernel_launch(void* const* d_in, const int* in_sizes, int n_in,
                              void* d_out, int out_size, void* d_ws, size_t ws_size,
                              hipStream_t stream)
{
    const float* x_in  = (const float*)d_in[0];
    const float* ln_w  = (const float*)d_in[1];
    const float* ln_b  = (const float*)d_in[2];
    const float* Wi    = (const float*)d_in[3];
    const float* cw    = (const float*)d_in[4];
    const float* cb    = (const float*)d_in[5];
    const float* Wx    = (const float*)d_in[6];
    const float* Wdt   = (const float*)d_in[7];
    const float* bdt   = (const float*)d_in[8];
    const float* A_log = (const float*)d_in[9];
    const float* Dd    = (const float*)d_in[10];
    const float* Wo    = (const float*)d_in[11];
    const float* regw  = (const float*)d_in[12];
    const float* regb  = (const float*)d_in[13];
    float* out = (float*)d_out;

    float* ws   = (float*)d_ws;
    float* XZ   = ws;                          // MTOK*1088 f32 (DELt + Yb overlay)
    float* XCt  = XZ   + (size_t)MTOK*1088;    // MTOK*544 f32 (u, then y)
    float* Gt   = XCt  + (size_t)MTOK*544;     // MTOK*544 f32
    float* DBLb = Gt   + (size_t)MTOK*544;     // MTOK*145 f32
    float* Xb   = DBLb + (size_t)MTOK*145;     // MTOK*272 f32 residual
    float* SCR  = Xb   + (size_t)MTOK*272;     // MTOK*272 f32 scratch: Hb/XCb/Q/Pt overlay
    float* Sbuf = SCR  + (size_t)MTOK*272;     // BB*DI*CH floats
    unsigned short* WiB = (unsigned short*)(Sbuf + BB*DI*CH);   // NL*1088*272 bf16
    unsigned short* WxB = WiB + (size_t)NL*1088*DM;             // NL*145*544 bf16
    unsigned short* WoB = WxB + (size_t)NL*145*DI;              // NL*272*544 bf16

    float* DELt = XZ;
    unsigned short* Yb = (unsigned short*)(XZ + (size_t)MTOK*544);
    unsigned short* Hb  = (unsigned short*)SCR;
    unsigned short* XCb = (unsigned short*)SCR;
    float* Q  = SCR;                           // BB*DI*CH*64 = MTOK*272 exactly
    float* Pt = SCR;

    (void)hipMemcpyAsync(Xb, x_in, sizeof(float)*(size_t)MTOK*DM, hipMemcpyDeviceToDevice, stream);

    wconv_kernel<<<(NL*1088*DM + 255)/256, 256, 0, stream>>>(Wi, WiB, NL*1088*DM, DM, DM);
    wconv_kernel<<<(NL*145*DI + 255)/256, 256, 0, stream>>>(Wx, WxB, NL*145*DI, DI, DI);
    wconv_kernel<<<(NL*272*DI + 255)/256, 256, 0, stream>>>(Wo, WoB, NL*272*DI, DI, DI);

    for (int l=0; l<NL; ++l){
        ln_kernel<<<MTOK/4, 256, 0, stream>>>(Xb, ln_w + l*DM, ln_b + l*DM, Hb);
        gmfma<false><<<dim3(MTOK/128, (2*DI+127)/128), 256, 0, stream>>>(
            Hb, DM, WiB + (size_t)l*2*DI*DM, DM, XZ, 2*DI, nullptr, 0, 2*DI, DM);
        conv_t2_kernel<<<BB*256, 256, 0, stream>>>(XZ, cw + l*DI*4, cb + l*DI, XCt, Gt, XCb);
        gmfma<false><<<dim3(MTOK/128, 2), 256, 0, stream>>>(
            XCb, DI, WxB + (size_t)l*145*DI, DI, DBLb, 145, nullptr, 0, 145, DI);
        dt_t2_kernel<<<BB*256, 256, 0, stream>>>(DBLb, Wdt + (size_t)l*DI*DTR, bdt + l*DI, DELt);
        scan_a<<<(BB*CH*DQ)/4, 256, 0, stream>>>(DELt, XCt, DBLb,
                                                 A_log + (size_t)l*DI*DS, Q, Sbuf);
        scan_c<<<(BB*CH*(DI/2))/4, 256, 0, stream>>>(DELt, XCt, Gt, DBLb,
                                                     A_log + (size_t)l*DI*DS, Dd + l*DI, Q, Sbuf);
        yt2yb_kernel<<<BB*256, 256, 0, stream>>>(XCt, Yb);
        gmfma<true><<<dim3(MTOK/128, 3), 256, 0, stream>>>(
            Yb, DI, WoB + (size_t)l*DM*DI, DI, Xb, DM, Xb, DM, DM, DI);
    }
    head1_kernel<<<BB*64, 256, 0, stream>>>(Xb, Pt);
    head2_kernel<<<BB, 256, 0, stream>>>(Pt, regw, regb, out);
}

// Round 11
// 1571.769 us; speedup vs baseline: 3.6862x; 1.0800x over previous
//
#include <hip/hip_runtime.h>
#include <hip/hip_bf16.h>
#include <math.h>

#define NL 6
#define DM 272
#define DS 64
#define DI 544
#define DTR 17
#define NSC 4
#define BB 4
#define LL 2048
#define MTOK (BB*LL)
#define TCH 128
#define CH  16
#define DQ  (DI/4)   // 136

typedef __attribute__((ext_vector_type(8))) short bf16x8;
typedef __attribute__((ext_vector_type(4))) float f32x4;

__device__ __forceinline__ float sigmoidf_(float x){ return 1.0f/(1.0f+__expf(-x)); }
__device__ __forceinline__ unsigned short f2bfu(float x){
    union { __hip_bfloat16 h; unsigned short u; } c; c.h = __float2bfloat16(x); return c.u;
}
// raw v_exp_f32: computes 2^x in one instruction (pair with log2e-prescaled exponents)
__device__ __forceinline__ float exp2x(float x){ float r; asm("v_exp_f32 %0, %1" : "=v"(r) : "v"(x)); return r; }

#define DPPADD(x, ctrl) x += __int_as_float(__builtin_amdgcn_update_dpp(0, __float_as_int(x), ctrl, 0xf, 0xf, true))
__device__ __forceinline__ float wsum64(float x){
    DPPADD(x, 0x111); DPPADD(x, 0x112); DPPADD(x, 0x114); DPPADD(x, 0x118);
    DPPADD(x, 0x142); DPPADD(x, 0x143);
    return x;
}

// ---------------- LayerNorm: one wave per token, bf16 output ----------------
__global__ __launch_bounds__(256) void ln_kernel(const float* __restrict__ X,
                          const float* __restrict__ w,
                          const float* __restrict__ b,
                          unsigned short* __restrict__ Hb)
{
    int wave = threadIdx.x >> 6;
    int lane = threadIdx.x & 63;
    int tok = blockIdx.x*4 + wave;
    const float* xr = X + (size_t)tok*DM;
    float v[5];
    float s=0.f, ss=0.f;
    #pragma unroll
    for (int j=0;j<5;++j){
        int idx = lane + j*64;
        float x = (idx < DM) ? xr[idx] : 0.f;
        v[j]=x; s+=x; ss+=x*x;
    }
    #pragma unroll
    for (int off=1; off<64; off<<=1){ s += __shfl_xor(s,off); ss += __shfl_xor(ss,off); }
    float mu  = s * (1.0f/DM);
    float var = ss*(1.0f/DM) - mu*mu;
    float inv = 1.0f/sqrtf(var + 1e-5f);
    unsigned short* hr = Hb + (size_t)tok*DM;
    #pragma unroll
    for (int j=0;j<5;++j){
        int idx = lane + j*64;
        if (idx<DM) hr[idx] = f2bfu((v[j]-mu)*inv*w[idx] + b[idx]);
    }
}

// ======= bf16 MFMA GEMM: C[M,N] = A[M,K]bf16 @ W[N,K]bf16^T (+f32 residual) =======
template<bool RESID>
__global__ __launch_bounds__(256) void gmfma(const unsigned short* __restrict__ A, int lda,
                     const unsigned short* __restrict__ W, int ldw,
                     float* __restrict__ C, int ldc,
                     const float* __restrict__ R, int ldr,
                     int N, int K)
{
    __shared__ unsigned short As[128*40];
    __shared__ unsigned short Bs[128*40];
    int bm = blockIdx.x*128, bn = blockIdx.y*128;
    int tid = threadIdx.x;
    int lane = tid & 63, wave = tid >> 6;
    int wm = wave >> 1, wn = wave & 1;
    f32x4 acc[4][4] = {};
    int r16 = lane & 15, kg = (lane >> 4) * 8;
    for (int k0=0; k0<K; k0+=32){
        #pragma unroll
        for (int it=0; it<2; ++it){
            int cid = tid + it*256;
            int row = cid >> 2, kq = (cid & 3)*8;
            int kk = k0 + kq;
            uint4 za = make_uint4(0,0,0,0);
            if (kk < K) za = *(const uint4*)(A + (size_t)(bm+row)*lda + kk);
            *(uint4*)&As[row*40 + kq] = za;
            uint4 zb = make_uint4(0,0,0,0);
            int wr = bn + row;
            if (wr < N && kk < K) zb = *(const uint4*)(W + (size_t)wr*ldw + kk);
            *(uint4*)&Bs[row*40 + kq] = zb;
        }
        __syncthreads();
        bf16x8 af[4], bfr[4];
        #pragma unroll
        for (int mi=0; mi<4; ++mi)
            af[mi] = *(bf16x8*)&As[(wm*64 + mi*16 + r16)*40 + kg];
        #pragma unroll
        for (int ni=0; ni<4; ++ni)
            bfr[ni] = *(bf16x8*)&Bs[(wn*64 + ni*16 + r16)*40 + kg];
        #pragma unroll
        for (int mi=0; mi<4; ++mi)
            #pragma unroll
            for (int ni=0; ni<4; ++ni)
                acc[mi][ni] = __builtin_amdgcn_mfma_f32_16x16x32_bf16(af[mi], bfr[ni], acc[mi][ni], 0, 0, 0);
        __syncthreads();
    }
    int rowt = (lane >> 4)*4, colt = lane & 15;
    #pragma unroll
    for (int mi=0; mi<4; ++mi){
        #pragma unroll
        for (int ni=0; ni<4; ++ni){
            int col = bn + wn*64 + ni*16 + colt;
            if (col < N){
                #pragma unroll
                for (int j=0; j<4; ++j){
                    int row = bm + wm*64 + mi*16 + rowt + j;
                    float v = acc[mi][ni][j];
                    if (RESID) v += R[(size_t)row*ldr + col];
                    C[(size_t)row*ldc + col] = v;
                }
            }
        }
    }
}

// ------- conv+SiLU+gate, LDS transpose; outputs XCt/Gt f32 [d][t] + XCb bf16 [tok][d] -------
__global__ __launch_bounds__(256) void conv_t2_kernel(const float* __restrict__ XZ,
                                 const float* __restrict__ cw,
                                 const float* __restrict__ cb,
                                 float* __restrict__ XCt,
                                 float* __restrict__ Gt,
                                 unsigned short* __restrict__ XCb)
{
    __shared__ float xi[67][69];
    __shared__ float zz[64][69];
    int bid = blockIdx.x;
    int b  = bid >> 8;
    int rem = bid & 255;
    int t0 = (rem >> 3)*64;
    int d0 = (rem & 7)*68;
    int tid = threadIdx.x;
    for (int li = tid; li < 67*17; li += 256){
        int row = li / 17, q = li - row*17;
        int tg = t0 - 3 + row;
        float4 v = make_float4(0.f,0.f,0.f,0.f);
        if (tg >= 0)
            v = *(const float4*)(XZ + ((size_t)b*LL + tg)*(2*DI) + d0 + q*4);
        xi[row][q*4+0]=v.x; xi[row][q*4+1]=v.y; xi[row][q*4+2]=v.z; xi[row][q*4+3]=v.w;
    }
    for (int li = tid; li < 64*17; li += 256){
        int row = li / 17, q = li - row*17;
        float4 v = *(const float4*)(XZ + ((size_t)b*LL + t0 + row)*(2*DI) + DI + d0 + q*4);
        zz[row][q*4+0]=v.x; zz[row][q*4+1]=v.y; zz[row][q*4+2]=v.z; zz[row][q*4+3]=v.w;
    }
    __syncthreads();
    int t = tid & 63;
    int dw = tid >> 6;
    float xcreg[17];
    #pragma unroll
    for (int i=0; i<17; ++i){
        int dl = dw + i*4;
        int d = d0 + dl;
        const float* cwd = cw + d*4;
        float acc = cb[d];
        #pragma unroll
        for (int k=0;k<4;++k) acc = fmaf(xi[t+k][dl], cwd[k], acc);
        float xc = acc * sigmoidf_(acc);
        float z  = zz[t][dl];
        size_t o = ((size_t)b*DI + d)*LL + t0 + t;
        XCt[o] = xc;
        Gt[o]  = z * sigmoidf_(z);
        xcreg[i] = xc;
    }
    __syncthreads();
    #pragma unroll
    for (int i=0; i<17; ++i) zz[t][dw + i*4] = xcreg[i];
    __syncthreads();
    for (int li = tid; li < 64*17; li += 256){
        int row = li / 17, q = li - row*17;
        ushort4 v;
        v.x = f2bfu(zz[row][q*4+0]); v.y = f2bfu(zz[row][q*4+1]);
        v.z = f2bfu(zz[row][q*4+2]); v.w = f2bfu(zz[row][q*4+3]);
        *(ushort4*)&XCb[((size_t)b*LL + t0 + row)*DI + d0 + q*4] = v;
    }
}

// ------- dt_proj (K=17) + softplus, LDS-staged, coalesced output over t -------
__global__ __launch_bounds__(256) void dt_t2_kernel(const float* __restrict__ DBLb,
                          const float* __restrict__ Wdt,
                          const float* __restrict__ bdt,
                          float* __restrict__ DELt)
{
    __shared__ float dtv[64*19];
    __shared__ float wl[68*17];
    int bid = blockIdx.x;
    int b  = bid >> 8;
    int rem = bid & 255;
    int t0 = (rem >> 3)*64;
    int d0 = (rem & 7)*68;
    int tid = threadIdx.x;
    for (int li = tid; li < 64*17; li += 256){
        int row = li / 17, col = li - row*17;
        dtv[row*19 + col] = DBLb[((size_t)b*LL + t0 + row)*145 + col];
    }
    for (int li = tid; li < 68*17; li += 256)
        wl[li] = Wdt[(size_t)d0*17 + li];
    __syncthreads();
    int t = tid & 63;
    #pragma unroll 1
    for (int dl = tid >> 6; dl < 68; dl += 4){
        float s = bdt[d0 + dl];
        #pragma unroll
        for (int r=0;r<DTR;++r) s = fmaf(dtv[t*19 + r], wl[dl*17 + r], s);
        float sp = (s > 20.f) ? s : log1pf(__expf(s));
        DELt[((size_t)b*DI + d0 + dl)*LL + t0 + t] = sp;
    }
}

// ======= chunked scan, pass A: 4 ch/wave, LDS-broadcast scalars, exp2 =======
__global__ __launch_bounds__(256) void scan_a(const float* __restrict__ DELt,
                       const float* __restrict__ XCt,
                       const float* __restrict__ DBLb,
                       const float* __restrict__ A_log,
                       float* __restrict__ Q,
                       float* __restrict__ S)
{
    __shared__ float2 dlb[4][4][64];
    int wave = threadIdx.x >> 6, lane = threadIdx.x & 63;
    float2 (*Db)[64] = dlb[wave];
    int wid = blockIdx.x*4 + wave;            // (b, c, dd) dd fastest
    int dd = wid % DQ;
    int c  = (wid / DQ) % CH;
    int b  = wid / (DQ*CH);
    int d0 = dd, d1 = dd+DQ, d2 = dd+2*DQ, d3 = dd+3*DQ;
    const float L2E = 1.44269504f;
    float Av0 = -__expf(A_log[d0*DS + lane]) * L2E;
    float Av1 = -__expf(A_log[d1*DS + lane]) * L2E;
    float Av2 = -__expf(A_log[d2*DS + lane]) * L2E;
    float Av3 = -__expf(A_log[d3*DS + lane]) * L2E;
    float h0=0.f,h1=0.f,h2=0.f,h3=0.f, ds0=0.f,ds1=0.f,ds2=0.f,ds3=0.f;
    size_t rb0 = ((size_t)b*DI + d0)*LL + c*TCH;
    size_t rb1 = ((size_t)b*DI + d1)*LL + c*TCH;
    size_t rb2 = ((size_t)b*DI + d2)*LL + c*TCH;
    size_t rb3 = ((size_t)b*DI + d3)*LL + c*TCH;
    const float* pB = DBLb + ((size_t)b*LL + c*TCH)*145;
    for (int blk=0; blk<TCH/64; ++blk){
        size_t o0 = rb0 + blk*64 + lane, o1 = rb1 + blk*64 + lane;
        size_t o2 = rb2 + blk*64 + lane, o3 = rb3 + blk*64 + lane;
        float dl0 = DELt[o0], dl1 = DELt[o1], dl2 = DELt[o2], dl3 = DELt[o3];
        float du0 = dl0*XCt[o0], du1 = dl1*XCt[o1], du2 = dl2*XCt[o2], du3 = dl3*XCt[o3];
        ds0 += dl0; ds1 += dl1; ds2 += dl2; ds3 += dl3;
        Db[0][lane] = make_float2(dl0, du0);
        Db[1][lane] = make_float2(dl1, du1);
        Db[2][lane] = make_float2(dl2, du2);
        Db[3][lane] = make_float2(dl3, du3);
        const float* p = pB + (size_t)blk*64*145;
        #pragma unroll 1
        for (int g=0; g<8; ++g){
            const float2* q0 = &Db[0][g*8];
            const float2* q1 = &Db[1][g*8];
            const float2* q2 = &Db[2][g*8];
            const float2* q3 = &Db[3][g*8];
            #pragma unroll
            for (int i=0; i<8; ++i){
                float Bv = p[17+lane];
                float2 a0=q0[i], a1=q1[i], a2=q2[i], a3=q3[i];
                h0 = fmaf(exp2x(a0.x*Av0), h0, a0.y*Bv);
                h1 = fmaf(exp2x(a1.x*Av1), h1, a1.y*Bv);
                h2 = fmaf(exp2x(a2.x*Av2), h2, a2.y*Bv);
                h3 = fmaf(exp2x(a3.x*Av3), h3, a3.y*Bv);
                p += 145;
            }
        }
    }
    size_t q0i = ((size_t)b*DI + d0)*CH + c, q1i = ((size_t)b*DI + d1)*CH + c;
    size_t q2i = ((size_t)b*DI + d2)*CH + c, q3i = ((size_t)b*DI + d3)*CH + c;
    Q[q0i*64 + lane] = h0; Q[q1i*64 + lane] = h1;
    Q[q2i*64 + lane] = h2; Q[q3i*64 + lane] = h3;
    float s0 = wsum64(ds0), s1 = wsum64(ds1), s2 = wsum64(ds2), s3 = wsum64(ds3);
    if (lane == 63){ S[q0i]=s0; S[q1i]=s1; S[q2i]=s2; S[q3i]=s3; }
}

// ======= chunked scan, pass C: 2 ch/wave, LDS-broadcast scalars, exp2, flush-4 =======
__global__ __launch_bounds__(256) void scan_c(const float* __restrict__ DELt,
                       float* __restrict__ XCt,
                       const float* __restrict__ Gt,
                       const float* __restrict__ DBLb,
                       const float* __restrict__ A_log,
                       const float* __restrict__ Dskip,
                       const float* __restrict__ Q,
                       const float* __restrict__ S)
{
    __shared__ float P[4][2][4][76];
    __shared__ float Ypark[4][2][4];
    __shared__ float2 dlb[4][2][64];
    int wave = threadIdx.x >> 6, lane = threadIdx.x & 63;
    float (*Pr0)[76] = P[wave][0];
    float (*Pr1)[76] = P[wave][1];
    float* Yp0 = Ypark[wave][0];
    float* Yp1 = Ypark[wave][1];
    float2* Db0 = dlb[wave][0];
    float2* Db1 = dlb[wave][1];
    int wid = blockIdx.x*4 + wave;
    int dd = wid % (DI/2);
    int c  = (wid / (DI/2)) % CH;
    int b  = wid / ((DI/2)*CH);
    int d0 = dd, d1 = dd + DI/2;
    const float L2E = 1.44269504f;
    float Av0 = -__expf(A_log[d0*DS + lane]) * L2E;
    float Av1 = -__expf(A_log[d1*DS + lane]) * L2E;
    float Dd0 = Dskip[d0], Dd1 = Dskip[d1];
    // inline lookback: combine chunks 0..c-1
    size_t q0 = ((size_t)b*DI + d0)*CH, q1 = ((size_t)b*DI + d1)*CH;
    float h0=0.f, h1=0.f;
    for (int j=0; j<c; ++j){
        h0 = fmaf(exp2x(Av0*S[q0+j]), h0, Q[(q0+j)*64 + lane]);
        h1 = fmaf(exp2x(Av1*S[q1+j]), h1, Q[(q1+j)*64 + lane]);
    }
    size_t rb0 = ((size_t)b*DI + d0)*LL + c*TCH;
    size_t rb1 = ((size_t)b*DI + d1)*LL + c*TCH;
    const float* pB = DBLb + ((size_t)b*LL + c*TCH)*145;
    int fr = lane >> 4, fq = (lane & 15)*4;
    for (int blk=0; blk<TCH/64; ++blk){
        size_t o0 = rb0 + blk*64 + lane, o1 = rb1 + blk*64 + lane;
        float dl0 = DELt[o0], dl1 = DELt[o1];
        float ul0 = XCt[o0],  ul1 = XCt[o1];
        float gl0 = Gt[o0],   gl1 = Gt[o1];
        Db0[lane] = make_float2(dl0, dl0*ul0);
        Db1[lane] = make_float2(dl1, dl1*ul1);
        float y0=0.f, y1=0.f;
        const float* p = pB + (size_t)blk*64*145;
        #pragma unroll 1
        for (int f=0; f<16; ++f){
            const float2* db0 = &Db0[f*4];
            const float2* db1 = &Db1[f*4];
            #pragma unroll
            for (int i=0; i<4; ++i){
                float Bv = p[17+lane];
                float Cv = p[81+lane];
                float2 a0 = db0[i], a1 = db1[i];
                h0 = fmaf(exp2x(a0.x*Av0), h0, a0.y*Bv);
                h1 = fmaf(exp2x(a1.x*Av1), h1, a1.y*Bv);
                Pr0[i][lane] = h0*Cv;
                Pr1[i][lane] = h1*Cv;
                p += 145;
            }
            // flush 4 steps: lane sums 4 values of row (lane>>4); 16-lane DPP reduce
            float4 xa0 = *(const float4*)&Pr0[fr][fq];
            float s0 = (xa0.x+xa0.y)+(xa0.z+xa0.w);
            DPPADD(s0,0x111); DPPADD(s0,0x112); DPPADD(s0,0x114); DPPADD(s0,0x118);
            float4 xa1 = *(const float4*)&Pr1[fr][fq];
            float s1 = (xa1.x+xa1.y)+(xa1.z+xa1.w);
            DPPADD(s1,0x111); DPPADD(s1,0x112); DPPADD(s1,0x114); DPPADD(s1,0x118);
            if ((lane & 15) == 15){ Yp0[fr] = s0; Yp1[fr] = s1; }
            float g0 = Yp0[lane & 3];
            float g1 = Yp1[lane & 3];
            if ((lane >> 2) == f){ y0 = g0; y1 = g1; }
        }
        XCt[o0] = (y0 + ul0*Dd0)*gl0;
        XCt[o1] = (y1 + ul1*Dd1)*gl1;
    }
}

// ------- y transpose: XCt f32 [b][d][t] -> Yb bf16 [tok][DI] -------
__global__ __launch_bounds__(256) void yt2yb_kernel(const float* __restrict__ Yt,
                             unsigned short* __restrict__ Yb)
{
    __shared__ float yt[64][69];
    int bid = blockIdx.x;
    int b = bid >> 8;
    int rem = bid & 255;
    int d0 = (rem >> 5)*68;
    int t0 = (rem & 31)*64;
    int tid = threadIdx.x;
    for (int li = tid; li < 68*16; li += 256){
        int dl = li >> 4, tq = (li & 15)*4;
        float4 v = *(const float4*)(Yt + ((size_t)b*DI + d0 + dl)*LL + t0 + tq);
        yt[tq+0][dl]=v.x; yt[tq+1][dl]=v.y; yt[tq+2][dl]=v.z; yt[tq+3][dl]=v.w;
    }
    __syncthreads();
    for (int li = tid; li < 64*17; li += 256){
        int row = li / 17, q = li - row*17;
        ushort4 v;
        v.x = f2bfu(yt[row][q*4+0]); v.y = f2bfu(yt[row][q*4+1]);
        v.z = f2bfu(yt[row][q*4+2]); v.w = f2bfu(yt[row][q*4+3]);
        *(ushort4*)&Yb[((size_t)b*LL + t0 + row)*DI + d0 + q*4] = v;
    }
}

// ------- weight f32 -> bf16 convert -------
__global__ __launch_bounds__(256) void wconv_kernel(const float* __restrict__ src,
                            unsigned short* __restrict__ dst,
                            int total, int kin, int kout)
{
    int idx = blockIdx.x*256 + threadIdx.x;
    if (idx >= total) return;
    int r = idx / kout, c = idx - r*kout;
    float v = (c < kin) ? src[(size_t)r*kin + c] : 0.f;
    dst[idx] = f2bfu(v);
}

// ------- head: two-stage mean-pool + regression -------
__global__ __launch_bounds__(256) void head1_kernel(const float* __restrict__ X,
                             float* __restrict__ Pt)
{
    int b = blockIdx.x >> 6, c = blockIdx.x & 63;
    int tid = threadIdx.x;
    for (int dm = tid; dm < DM; dm += 256){
        float s = 0.f;
        const float* base = X + ((size_t)b*LL + c*32)*DM + dm;
        #pragma unroll 8
        for (int tt=0; tt<32; ++tt) s += base[(size_t)tt*DM];
        Pt[(size_t)(b*64 + c)*DM + dm] = s;
    }
}

__global__ __launch_bounds__(256) void head2_kernel(const float* __restrict__ Pt,
                             const float* __restrict__ reg_w,
                             const float* __restrict__ reg_b,
                             float* __restrict__ out)
{
    __shared__ float feat[DM];
    int b = blockIdx.x, tid = threadIdx.x;
    for (int dm = tid; dm < DM; dm += 256){
        float s = 0.f;
        for (int c=0; c<64; ++c) s += Pt[(size_t)(b*64 + c)*DM + dm];
        float f = s * (1.0f/LL);
        feat[dm] = f;
        out[16 + b*DM + dm] = f;
    }
    __syncthreads();
    if (tid < NSC){
        float s = reg_b[tid];
        const float* wr = reg_w + tid*DM;
        for (int k=0;k<DM;++k) s = fmaf(feat[k], wr[k], s);
        out[b*NSC + tid] = s;
    }
}

extern "C" void kernel_launch(void* const* d_in, const int* in_sizes, int n_in,
                              void* d_out, int out_size, void* d_ws, size_t ws_size,
                              hipStream_t stream)
{
    const float* x_in  = (const float*)d_in[0];
    const float* ln_w  = (const float*)d_in[1];
    const float* ln_b  = (const float*)d_in[2];
    const float* Wi    = (const float*)d_in[3];
    const float* cw    = (const float*)d_in[4];
    const float* cb    = (const float*)d_in[5];
    const float* Wx    = (const float*)d_in[6];
    const float* Wdt   = (const float*)d_in[7];
    const float* bdt   = (const float*)d_in[8];
    const float* A_log = (const float*)d_in[9];
    const float* Dd    = (const float*)d_in[10];
    const float* Wo    = (const float*)d_in[11];
    const float* regw  = (const float*)d_in[12];
    const float* regb  = (const float*)d_in[13];
    float* out = (float*)d_out;

    float* ws   = (float*)d_ws;
    float* XZ   = ws;                          // MTOK*1088 f32 (DELt + Yb overlay)
    float* XCt  = XZ   + (size_t)MTOK*1088;    // MTOK*544 f32 (u, then y)
    float* Gt   = XCt  + (size_t)MTOK*544;     // MTOK*544 f32
    float* DBLb = Gt   + (size_t)MTOK*544;     // MTOK*145 f32
    float* Xb   = DBLb + (size_t)MTOK*145;     // MTOK*272 f32 residual
    float* SCR  = Xb   + (size_t)MTOK*272;     // MTOK*272 f32 scratch: Hb/XCb/Q/Pt overlay
    float* Sbuf = SCR  + (size_t)MTOK*272;     // BB*DI*CH floats
    unsigned short* WiB = (unsigned short*)(Sbuf + BB*DI*CH);   // NL*1088*272 bf16
    unsigned short* WxB = WiB + (size_t)NL*1088*DM;             // NL*145*544 bf16
    unsigned short* WoB = WxB + (size_t)NL*145*DI;              // NL*272*544 bf16

    float* DELt = XZ;
    unsigned short* Yb = (unsigned short*)(XZ + (size_t)MTOK*544);
    unsigned short* Hb  = (unsigned short*)SCR;
    unsigned short* XCb = (unsigned short*)SCR;
    float* Q  = SCR;                           // BB*DI*CH*64 = MTOK*272 exactly
    float* Pt = SCR;

    (void)hipMemcpyAsync(Xb, x_in, sizeof(float)*(size_t)MTOK*DM, hipMemcpyDeviceToDevice, stream);

    wconv_kernel<<<(NL*1088*DM + 255)/256, 256, 0, stream>>>(Wi, WiB, NL*1088*DM, DM, DM);
    wconv_kernel<<<(NL*145*DI + 255)/256, 256, 0, stream>>>(Wx, WxB, NL*145*DI, DI, DI);
    wconv_kernel<<<(NL*272*DI + 255)/256, 256, 0, stream>>>(Wo, WoB, NL*272*DI, DI, DI);

    for (int l=0; l<NL; ++l){
        ln_kernel<<<MTOK/4, 256, 0, stream>>>(Xb, ln_w + l*DM, ln_b + l*DM, Hb);
        gmfma<false><<<dim3(MTOK/128, (2*DI+127)/128), 256, 0, stream>>>(
            Hb, DM, WiB + (size_t)l*2*DI*DM, DM, XZ, 2*DI, nullptr, 0, 2*DI, DM);
        conv_t2_kernel<<<BB*256, 256, 0, stream>>>(XZ, cw + l*DI*4, cb + l*DI, XCt, Gt, XCb);
        gmfma<false><<<dim3(MTOK/128, 2), 256, 0, stream>>>(
            XCb, DI, WxB + (size_t)l*145*DI, DI, DBLb, 145, nullptr, 0, 145, DI);
        dt_t2_kernel<<<BB*256, 256, 0, stream>>>(DBLb, Wdt + (size_t)l*DI*DTR, bdt + l*DI, DELt);
        scan_a<<<(BB*CH*DQ)/4, 256, 0, stream>>>(DELt, XCt, DBLb,
                                                 A_log + (size_t)l*DI*DS, Q, Sbuf);
        scan_c<<<(BB*CH*(DI/2))/4, 256, 0, stream>>>(DELt, XCt, Gt, DBLb,
                                                     A_log + (size_t)l*DI*DS, Dd + l*DI, Q, Sbuf);
        yt2yb_kernel<<<BB*256, 256, 0, stream>>>(XCt, Yb);
        gmfma<true><<<dim3(MTOK/128, 3), 256, 0, stream>>>(
            Yb, DI, WoB + (size_t)l*DM*DI, DI, Xb, DM, Xb, DM, DM, DI);
    }
    head1_kernel<<<BB*64, 256, 0, stream>>>(Xb, Pt);
    head2_kernel<<<BB, 256, 0, stream>>>(Pt, regw, regb, out);
}

// Round 12
// 1543.336 us; speedup vs baseline: 3.7541x; 1.0184x over previous
//
#include <hip/hip_runtime.h>
#include <hip/hip_bf16.h>
#include <math.h>

#define NL 6
#define DM 272
#define DS 64
#define DI 544
#define DTR 17
#define NSC 4
#define BB 4
#define LL 2048
#define MTOK (BB*LL)
#define TCH 128
#define CH  16
#define DQ  (DI/4)   // 136

typedef __attribute__((ext_vector_type(8))) short bf16x8;
typedef __attribute__((ext_vector_type(4))) float f32x4;

__device__ __forceinline__ float sigmoidf_(float x){ return 1.0f/(1.0f+__expf(-x)); }
__device__ __forceinline__ unsigned short f2bfu(float x){
    union { __hip_bfloat16 h; unsigned short u; } c; c.h = __float2bfloat16(x); return c.u;
}
__device__ __forceinline__ float bfu2f(unsigned short u){ return __uint_as_float(((unsigned)u)<<16); }
// raw v_exp_f32: computes 2^x (pair with log2e-prescaled exponents)
__device__ __forceinline__ float exp2x(float x){ float r; asm("v_exp_f32 %0, %1" : "=v"(r) : "v"(x)); return r; }

#define DPPADD(x, ctrl) x += __int_as_float(__builtin_amdgcn_update_dpp(0, __float_as_int(x), ctrl, 0xf, 0xf, true))
__device__ __forceinline__ float wsum64(float x){
    DPPADD(x, 0x111); DPPADD(x, 0x112); DPPADD(x, 0x114); DPPADD(x, 0x118);
    DPPADD(x, 0x142); DPPADD(x, 0x143);
    return x;
}

// ---------------- LayerNorm: one wave per token, bf16 output ----------------
__global__ __launch_bounds__(256) void ln_kernel(const float* __restrict__ X,
                          const float* __restrict__ w,
                          const float* __restrict__ b,
                          unsigned short* __restrict__ Hb)
{
    int wave = threadIdx.x >> 6;
    int lane = threadIdx.x & 63;
    int tok = blockIdx.x*4 + wave;
    const float* xr = X + (size_t)tok*DM;
    float v[5];
    float s=0.f, ss=0.f;
    #pragma unroll
    for (int j=0;j<5;++j){
        int idx = lane + j*64;
        float x = (idx < DM) ? xr[idx] : 0.f;
        v[j]=x; s+=x; ss+=x*x;
    }
    #pragma unroll
    for (int off=1; off<64; off<<=1){ s += __shfl_xor(s,off); ss += __shfl_xor(ss,off); }
    float mu  = s * (1.0f/DM);
    float var = ss*(1.0f/DM) - mu*mu;
    float inv = 1.0f/sqrtf(var + 1e-5f);
    unsigned short* hr = Hb + (size_t)tok*DM;
    #pragma unroll
    for (int j=0;j<5;++j){
        int idx = lane + j*64;
        if (idx<DM) hr[idx] = f2bfu((v[j]-mu)*inv*w[idx] + b[idx]);
    }
}

// ======= bf16 MFMA GEMM: C[M,N] = A[M,K]bf16 @ W[N,K]bf16^T; C f32 or bf16 =======
template<bool RESID, bool OUTBF16>
__global__ __launch_bounds__(256) void gmfma(const unsigned short* __restrict__ A, int lda,
                     const unsigned short* __restrict__ W, int ldw,
                     void* __restrict__ Cv, int ldc,
                     const float* __restrict__ R, int ldr,
                     int N, int K)
{
    __shared__ unsigned short As[128*40];
    __shared__ unsigned short Bs[128*40];
    int bm = blockIdx.x*128, bn = blockIdx.y*128;
    int tid = threadIdx.x;
    int lane = tid & 63, wave = tid >> 6;
    int wm = wave >> 1, wn = wave & 1;
    f32x4 acc[4][4] = {};
    int r16 = lane & 15, kg = (lane >> 4) * 8;
    for (int k0=0; k0<K; k0+=32){
        #pragma unroll
        for (int it=0; it<2; ++it){
            int cid = tid + it*256;
            int row = cid >> 2, kq = (cid & 3)*8;
            int kk = k0 + kq;
            uint4 za = make_uint4(0,0,0,0);
            if (kk < K) za = *(const uint4*)(A + (size_t)(bm+row)*lda + kk);
            *(uint4*)&As[row*40 + kq] = za;
            uint4 zb = make_uint4(0,0,0,0);
            int wr = bn + row;
            if (wr < N && kk < K) zb = *(const uint4*)(W + (size_t)wr*ldw + kk);
            *(uint4*)&Bs[row*40 + kq] = zb;
        }
        __syncthreads();
        bf16x8 af[4], bfr[4];
        #pragma unroll
        for (int mi=0; mi<4; ++mi)
            af[mi] = *(bf16x8*)&As[(wm*64 + mi*16 + r16)*40 + kg];
        #pragma unroll
        for (int ni=0; ni<4; ++ni)
            bfr[ni] = *(bf16x8*)&Bs[(wn*64 + ni*16 + r16)*40 + kg];
        #pragma unroll
        for (int mi=0; mi<4; ++mi)
            #pragma unroll
            for (int ni=0; ni<4; ++ni)
                acc[mi][ni] = __builtin_amdgcn_mfma_f32_16x16x32_bf16(af[mi], bfr[ni], acc[mi][ni], 0, 0, 0);
        __syncthreads();
    }
    int rowt = (lane >> 4)*4, colt = lane & 15;
    #pragma unroll
    for (int mi=0; mi<4; ++mi){
        #pragma unroll
        for (int ni=0; ni<4; ++ni){
            int col = bn + wn*64 + ni*16 + colt;
            if (col < N){
                #pragma unroll
                for (int j=0; j<4; ++j){
                    int row = bm + wm*64 + mi*16 + rowt + j;
                    float v = acc[mi][ni][j];
                    if (RESID) v += R[(size_t)row*ldr + col];
                    if (OUTBF16)
                        ((unsigned short*)Cv)[(size_t)row*ldc + col] = f2bfu(v);
                    else
                        ((float*)Cv)[(size_t)row*ldc + col] = v;
                }
            }
        }
    }
}

// ------- conv+SiLU+gate (bf16 in): outputs XCtb/Gtb bf16 [d][t] + XCb bf16 [tok][d] -------
__global__ __launch_bounds__(256) void conv_t2_kernel(const unsigned short* __restrict__ XZb,
                                 const float* __restrict__ cw,
                                 const float* __restrict__ cb,
                                 unsigned short* __restrict__ XCtb,
                                 unsigned short* __restrict__ Gtb,
                                 unsigned short* __restrict__ XCb)
{
    __shared__ float xi[67][69];
    __shared__ float zz[64][69];
    int bid = blockIdx.x;
    int b  = bid >> 8;
    int rem = bid & 255;
    int t0 = (rem >> 3)*64;
    int d0 = (rem & 7)*68;
    int tid = threadIdx.x;
    for (int li = tid; li < 67*17; li += 256){
        int row = li / 17, q = li - row*17;
        int tg = t0 - 3 + row;
        float4 v = make_float4(0.f,0.f,0.f,0.f);
        if (tg >= 0){
            ushort4 u4 = *(const ushort4*)(XZb + ((size_t)b*LL + tg)*(2*DI) + d0 + q*4);
            v.x = bfu2f(u4.x); v.y = bfu2f(u4.y); v.z = bfu2f(u4.z); v.w = bfu2f(u4.w);
        }
        xi[row][q*4+0]=v.x; xi[row][q*4+1]=v.y; xi[row][q*4+2]=v.z; xi[row][q*4+3]=v.w;
    }
    for (int li = tid; li < 64*17; li += 256){
        int row = li / 17, q = li - row*17;
        ushort4 u4 = *(const ushort4*)(XZb + ((size_t)b*LL + t0 + row)*(2*DI) + DI + d0 + q*4);
        zz[row][q*4+0]=bfu2f(u4.x); zz[row][q*4+1]=bfu2f(u4.y);
        zz[row][q*4+2]=bfu2f(u4.z); zz[row][q*4+3]=bfu2f(u4.w);
    }
    __syncthreads();
    int t = tid & 63;
    int dw = tid >> 6;
    float xcreg[17];
    #pragma unroll
    for (int i=0; i<17; ++i){
        int dl = dw + i*4;
        int d = d0 + dl;
        const float* cwd = cw + d*4;
        float acc = cb[d];
        #pragma unroll
        for (int k=0;k<4;++k) acc = fmaf(xi[t+k][dl], cwd[k], acc);
        float xc = acc * sigmoidf_(acc);
        float z  = zz[t][dl];
        size_t o = ((size_t)b*DI + d)*LL + t0 + t;
        XCtb[o] = f2bfu(xc);
        Gtb[o]  = f2bfu(z * sigmoidf_(z));
        xcreg[i] = xc;
    }
    __syncthreads();
    #pragma unroll
    for (int i=0; i<17; ++i) zz[t][dw + i*4] = xcreg[i];
    __syncthreads();
    for (int li = tid; li < 64*17; li += 256){
        int row = li / 17, q = li - row*17;
        ushort4 v;
        v.x = f2bfu(zz[row][q*4+0]); v.y = f2bfu(zz[row][q*4+1]);
        v.z = f2bfu(zz[row][q*4+2]); v.w = f2bfu(zz[row][q*4+3]);
        *(ushort4*)&XCb[((size_t)b*LL + t0 + row)*DI + d0 + q*4] = v;
    }
}

// ------- dt_proj (K=17) + softplus, LDS-staged, coalesced output over t -------
__global__ __launch_bounds__(256) void dt_t2_kernel(const float* __restrict__ DBLb,
                          const float* __restrict__ Wdt,
                          const float* __restrict__ bdt,
                          float* __restrict__ DELt)
{
    __shared__ float dtv[64*19];
    __shared__ float wl[68*17];
    int bid = blockIdx.x;
    int b  = bid >> 8;
    int rem = bid & 255;
    int t0 = (rem >> 3)*64;
    int d0 = (rem & 7)*68;
    int tid = threadIdx.x;
    for (int li = tid; li < 64*17; li += 256){
        int row = li / 17, col = li - row*17;
        dtv[row*19 + col] = DBLb[((size_t)b*LL + t0 + row)*145 + col];
    }
    for (int li = tid; li < 68*17; li += 256)
        wl[li] = Wdt[(size_t)d0*17 + li];
    __syncthreads();
    int t = tid & 63;
    #pragma unroll 1
    for (int dl = tid >> 6; dl < 68; dl += 4){
        float s = bdt[d0 + dl];
        #pragma unroll
        for (int r=0;r<DTR;++r) s = fmaf(dtv[t*19 + r], wl[dl*17 + r], s);
        float sp = (s > 20.f) ? s : log1pf(__expf(s));
        DELt[((size_t)b*DI + d0 + dl)*LL + t0 + t] = sp;
    }
}

// ======= chunked scan, pass A: 4 ch/wave, LDS-broadcast scalars, exp2 =======
__global__ __launch_bounds__(256) void scan_a(const float* __restrict__ DELt,
                       const unsigned short* __restrict__ XCtb,
                       const float* __restrict__ DBLb,
                       const float* __restrict__ A_log,
                       float* __restrict__ Q,
                       float* __restrict__ S)
{
    __shared__ float2 dlb[4][4][64];
    int wave = threadIdx.x >> 6, lane = threadIdx.x & 63;
    float2 (*Db)[64] = dlb[wave];
    int wid = blockIdx.x*4 + wave;            // (b, c, dd) dd fastest
    int dd = wid % DQ;
    int c  = (wid / DQ) % CH;
    int b  = wid / (DQ*CH);
    int d0 = dd, d1 = dd+DQ, d2 = dd+2*DQ, d3 = dd+3*DQ;
    const float L2E = 1.44269504f;
    float Av0 = -__expf(A_log[d0*DS + lane]) * L2E;
    float Av1 = -__expf(A_log[d1*DS + lane]) * L2E;
    float Av2 = -__expf(A_log[d2*DS + lane]) * L2E;
    float Av3 = -__expf(A_log[d3*DS + lane]) * L2E;
    float h0=0.f,h1=0.f,h2=0.f,h3=0.f, ds0=0.f,ds1=0.f,ds2=0.f,ds3=0.f;
    size_t rb0 = ((size_t)b*DI + d0)*LL + c*TCH;
    size_t rb1 = ((size_t)b*DI + d1)*LL + c*TCH;
    size_t rb2 = ((size_t)b*DI + d2)*LL + c*TCH;
    size_t rb3 = ((size_t)b*DI + d3)*LL + c*TCH;
    const float* pB = DBLb + ((size_t)b*LL + c*TCH)*145;
    for (int blk=0; blk<TCH/64; ++blk){
        size_t o0 = rb0 + blk*64 + lane, o1 = rb1 + blk*64 + lane;
        size_t o2 = rb2 + blk*64 + lane, o3 = rb3 + blk*64 + lane;
        float dl0 = DELt[o0], dl1 = DELt[o1], dl2 = DELt[o2], dl3 = DELt[o3];
        float du0 = dl0*bfu2f(XCtb[o0]), du1 = dl1*bfu2f(XCtb[o1]);
        float du2 = dl2*bfu2f(XCtb[o2]), du3 = dl3*bfu2f(XCtb[o3]);
        ds0 += dl0; ds1 += dl1; ds2 += dl2; ds3 += dl3;
        Db[0][lane] = make_float2(dl0, du0);
        Db[1][lane] = make_float2(dl1, du1);
        Db[2][lane] = make_float2(dl2, du2);
        Db[3][lane] = make_float2(dl3, du3);
        const float* p = pB + (size_t)blk*64*145;
        #pragma unroll 1
        for (int g=0; g<8; ++g){
            const float2* q0 = &Db[0][g*8];
            const float2* q1 = &Db[1][g*8];
            const float2* q2 = &Db[2][g*8];
            const float2* q3 = &Db[3][g*8];
            #pragma unroll
            for (int i=0; i<8; ++i){
                float Bv = p[17+lane];
                float2 a0=q0[i], a1=q1[i], a2=q2[i], a3=q3[i];
                h0 = fmaf(exp2x(a0.x*Av0), h0, a0.y*Bv);
                h1 = fmaf(exp2x(a1.x*Av1), h1, a1.y*Bv);
                h2 = fmaf(exp2x(a2.x*Av2), h2, a2.y*Bv);
                h3 = fmaf(exp2x(a3.x*Av3), h3, a3.y*Bv);
                p += 145;
            }
        }
    }
    size_t q0i = ((size_t)b*DI + d0)*CH + c, q1i = ((size_t)b*DI + d1)*CH + c;
    size_t q2i = ((size_t)b*DI + d2)*CH + c, q3i = ((size_t)b*DI + d3)*CH + c;
    Q[q0i*64 + lane] = h0; Q[q1i*64 + lane] = h1;
    Q[q2i*64 + lane] = h2; Q[q3i*64 + lane] = h3;
    float s0 = wsum64(ds0), s1 = wsum64(ds1), s2 = wsum64(ds2), s3 = wsum64(ds3);
    if (lane == 63){ S[q0i]=s0; S[q1i]=s1; S[q2i]=s2; S[q3i]=s3; }
}

// ======= chunked scan, pass C: 2 ch/wave, direct gated-y bf16 [tok][DI] output =======
__global__ __launch_bounds__(256) void scan_c(const float* __restrict__ DELt,
                       const unsigned short* __restrict__ XCtb,
                       const unsigned short* __restrict__ Gtb,
                       const float* __restrict__ DBLb,
                       const float* __restrict__ A_log,
                       const float* __restrict__ Dskip,
                       const float* __restrict__ Q,
                       const float* __restrict__ S,
                       unsigned short* __restrict__ Yb)
{
    __shared__ float P[4][2][4][76];
    __shared__ float Ypark[4][2][4];
    __shared__ float2 dlb[4][2][64];
    int wave = threadIdx.x >> 6, lane = threadIdx.x & 63;
    float (*Pr0)[76] = P[wave][0];
    float (*Pr1)[76] = P[wave][1];
    float* Yp0 = Ypark[wave][0];
    float* Yp1 = Ypark[wave][1];
    float2* Db0 = dlb[wave][0];
    float2* Db1 = dlb[wave][1];
    int wid = blockIdx.x*4 + wave;
    int dd = wid % (DI/2);
    int c  = (wid / (DI/2)) % CH;
    int b  = wid / ((DI/2)*CH);
    int d0 = dd, d1 = dd + DI/2;
    const float L2E = 1.44269504f;
    float Av0 = -__expf(A_log[d0*DS + lane]) * L2E;
    float Av1 = -__expf(A_log[d1*DS + lane]) * L2E;
    float Dd0 = Dskip[d0], Dd1 = Dskip[d1];
    size_t q0 = ((size_t)b*DI + d0)*CH, q1 = ((size_t)b*DI + d1)*CH;
    float h0=0.f, h1=0.f;
    for (int j=0; j<c; ++j){
        h0 = fmaf(exp2x(Av0*S[q0+j]), h0, Q[(q0+j)*64 + lane]);
        h1 = fmaf(exp2x(Av1*S[q1+j]), h1, Q[(q1+j)*64 + lane]);
    }
    size_t rb0 = ((size_t)b*DI + d0)*LL + c*TCH;
    size_t rb1 = ((size_t)b*DI + d1)*LL + c*TCH;
    const float* pB = DBLb + ((size_t)b*LL + c*TCH)*145;
    int fr = lane >> 4, fq = (lane & 15)*4;
    for (int blk=0; blk<TCH/64; ++blk){
        size_t o0 = rb0 + blk*64 + lane, o1 = rb1 + blk*64 + lane;
        float dl0 = DELt[o0], dl1 = DELt[o1];
        float ul0 = bfu2f(XCtb[o0]), ul1 = bfu2f(XCtb[o1]);
        float gl0 = bfu2f(Gtb[o0]),  gl1 = bfu2f(Gtb[o1]);
        Db0[lane] = make_float2(dl0, dl0*ul0);
        Db1[lane] = make_float2(dl1, dl1*ul1);
        float y0=0.f, y1=0.f;
        const float* p = pB + (size_t)blk*64*145;
        #pragma unroll 1
        for (int f=0; f<16; ++f){
            const float2* db0 = &Db0[f*4];
            const float2* db1 = &Db1[f*4];
            #pragma unroll
            for (int i=0; i<4; ++i){
                float Bv = p[17+lane];
                float Cv = p[81+lane];
                float2 a0 = db0[i], a1 = db1[i];
                h0 = fmaf(exp2x(a0.x*Av0), h0, a0.y*Bv);
                h1 = fmaf(exp2x(a1.x*Av1), h1, a1.y*Bv);
                Pr0[i][lane] = h0*Cv;
                Pr1[i][lane] = h1*Cv;
                p += 145;
            }
            float4 xa0 = *(const float4*)&Pr0[fr][fq];
            float s0 = (xa0.x+xa0.y)+(xa0.z+xa0.w);
            DPPADD(s0,0x111); DPPADD(s0,0x112); DPPADD(s0,0x114); DPPADD(s0,0x118);
            float4 xa1 = *(const float4*)&Pr1[fr][fq];
            float s1 = (xa1.x+xa1.y)+(xa1.z+xa1.w);
            DPPADD(s1,0x111); DPPADD(s1,0x112); DPPADD(s1,0x114); DPPADD(s1,0x118);
            if ((lane & 15) == 15){ Yp0[fr] = s0; Yp1[fr] = s1; }
            float g0 = Yp0[lane & 3];
            float g1 = Yp1[lane & 3];
            if ((lane >> 2) == f){ y0 = g0; y1 = g1; }
        }
        size_t trow = (size_t)b*LL + c*TCH + blk*64 + lane;
        Yb[trow*DI + d0] = f2bfu((y0 + ul0*Dd0)*gl0);
        Yb[trow*DI + d1] = f2bfu((y1 + ul1*Dd1)*gl1);
    }
}

// ------- weight f32 -> bf16 convert -------
__global__ __launch_bounds__(256) void wconv_kernel(const float* __restrict__ src,
                            unsigned short* __restrict__ dst,
                            int total, int kin, int kout)
{
    int idx = blockIdx.x*256 + threadIdx.x;
    if (idx >= total) return;
    int r = idx / kout, c = idx - r*kout;
    float v = (c < kin) ? src[(size_t)r*kin + c] : 0.f;
    dst[idx] = f2bfu(v);
}

// ------- head: two-stage mean-pool + regression -------
__global__ __launch_bounds__(256) void head1_kernel(const float* __restrict__ X,
                             float* __restrict__ Pt)
{
    int b = blockIdx.x >> 6, c = blockIdx.x & 63;
    int tid = threadIdx.x;
    for (int dm = tid; dm < DM; dm += 256){
        float s = 0.f;
        const float* base = X + ((size_t)b*LL + c*32)*DM + dm;
        #pragma unroll 8
        for (int tt=0; tt<32; ++tt) s += base[(size_t)tt*DM];
        Pt[(size_t)(b*64 + c)*DM + dm] = s;
    }
}

__global__ __launch_bounds__(256) void head2_kernel(const float* __restrict__ Pt,
                             const float* __restrict__ reg_w,
                             const float* __restrict__ reg_b,
                             float* __restrict__ out)
{
    __shared__ float feat[DM];
    int b = blockIdx.x, tid = threadIdx.x;
    for (int dm = tid; dm < DM; dm += 256){
        float s = 0.f;
        for (int c=0; c<64; ++c) s += Pt[(size_t)(b*64 + c)*DM + dm];
        float f = s * (1.0f/LL);
        feat[dm] = f;
        out[16 + b*DM + dm] = f;
    }
    __syncthreads();
    if (tid < NSC){
        float s = reg_b[tid];
        const float* wr = reg_w + tid*DM;
        for (int k=0;k<DM;++k) s = fmaf(feat[k], wr[k], s);
        out[b*NSC + tid] = s;
    }
}

extern "C" void kernel_launch(void* const* d_in, const int* in_sizes, int n_in,
                              void* d_out, int out_size, void* d_ws, size_t ws_size,
                              hipStream_t stream)
{
    const float* x_in  = (const float*)d_in[0];
    const float* ln_w  = (const float*)d_in[1];
    const float* ln_b  = (const float*)d_in[2];
    const float* Wi    = (const float*)d_in[3];
    const float* cw    = (const float*)d_in[4];
    const float* cb    = (const float*)d_in[5];
    const float* Wx    = (const float*)d_in[6];
    const float* Wdt   = (const float*)d_in[7];
    const float* bdt   = (const float*)d_in[8];
    const float* A_log = (const float*)d_in[9];
    const float* Dd    = (const float*)d_in[10];
    const float* Wo    = (const float*)d_in[11];
    const float* regw  = (const float*)d_in[12];
    const float* regb  = (const float*)d_in[13];
    float* out = (float*)d_out;

    // explicit byte-carved workspace (~71 MB total)
    char* base = (char*)d_ws;
    auto carve = [&](size_t bytes) -> char* {
        char* p = base; base += (bytes + 255) & ~(size_t)255; return p;
    };
    unsigned short* XZb  = (unsigned short*)carve((size_t)MTOK*1088*2);
    unsigned short* XCtb = (unsigned short*)carve((size_t)MTOK*544*2);
    unsigned short* Gtb  = (unsigned short*)carve((size_t)MTOK*544*2);
    float*          DELt = (float*)carve((size_t)MTOK*544*4);
    float*          DBLb = (float*)carve((size_t)MTOK*145*4);
    float*          Xb   = (float*)carve((size_t)MTOK*272*4);
    unsigned short* Yb   = (unsigned short*)carve((size_t)MTOK*544*2);
    char*           SCR  = carve((size_t)MTOK*272*4);   // Hb / XCb / Q / Pt overlay
    float*          Sbuf = (float*)carve((size_t)BB*DI*CH*4);
    unsigned short* WiB  = (unsigned short*)carve((size_t)NL*1088*DM*2);
    unsigned short* WxB  = (unsigned short*)carve((size_t)NL*145*DI*2);
    unsigned short* WoB  = (unsigned short*)carve((size_t)NL*272*DI*2);

    unsigned short* Hb  = (unsigned short*)SCR;   // MTOK*272 bf16
    unsigned short* XCb = (unsigned short*)SCR;   // MTOK*544 bf16 (= same bytes)
    float*          Q   = (float*)SCR;            // BB*DI*CH*64 f32 (= same bytes)
    float*          Pt  = (float*)SCR;

    (void)hipMemcpyAsync(Xb, x_in, sizeof(float)*(size_t)MTOK*DM, hipMemcpyDeviceToDevice, stream);

    wconv_kernel<<<(NL*1088*DM + 255)/256, 256, 0, stream>>>(Wi, WiB, NL*1088*DM, DM, DM);
    wconv_kernel<<<(NL*145*DI + 255)/256, 256, 0, stream>>>(Wx, WxB, NL*145*DI, DI, DI);
    wconv_kernel<<<(NL*272*DI + 255)/256, 256, 0, stream>>>(Wo, WoB, NL*272*DI, DI, DI);

    for (int l=0; l<NL; ++l){
        ln_kernel<<<MTOK/4, 256, 0, stream>>>(Xb, ln_w + l*DM, ln_b + l*DM, Hb);
        gmfma<false,true><<<dim3(MTOK/128, (2*DI+127)/128), 256, 0, stream>>>(
            Hb, DM, WiB + (size_t)l*2*DI*DM, DM, XZb, 2*DI, nullptr, 0, 2*DI, DM);
        conv_t2_kernel<<<BB*256, 256, 0, stream>>>(XZb, cw + l*DI*4, cb + l*DI, XCtb, Gtb, XCb);
        gmfma<false,false><<<dim3(MTOK/128, 2), 256, 0, stream>>>(
            XCb, DI, WxB + (size_t)l*145*DI, DI, DBLb, 145, nullptr, 0, 145, DI);
        dt_t2_kernel<<<BB*256, 256, 0, stream>>>(DBLb, Wdt + (size_t)l*DI*DTR, bdt + l*DI, DELt);
        scan_a<<<(BB*CH*DQ)/4, 256, 0, stream>>>(DELt, XCtb, DBLb,
                                                 A_log + (size_t)l*DI*DS, Q, Sbuf);
        scan_c<<<(BB*CH*(DI/2))/4, 256, 0, stream>>>(DELt, XCtb, Gtb, DBLb,
                                                     A_log + (size_t)l*DI*DS, Dd + l*DI, Q, Sbuf, Yb);
        gmfma<true,false><<<dim3(MTOK/128, 3), 256, 0, stream>>>(
            Yb, DI, WoB + (size_t)l*DM*DI, DI, Xb, DM, Xb, DM, DM, DI);
    }
    head1_kernel<<<BB*64, 256, 0, stream>>>(Xb, Pt);
    head2_kernel<<<BB, 256, 0, stream>>>(Pt, regw, regb, out);
}